// Round 1
// baseline (2702.110 us; speedup 1.0000x reference)
//
#include <hip/hip_runtime.h>
#include <math.h>

// ---------------------------------------------------------------------------
// Graph U-Net forward on MI355X. All fp32 (top-k ordering requires it on the
// down path; see analysis). Heavy stages are tiled 64x64 LDS GEMMs.
// ---------------------------------------------------------------------------

static __device__ __forceinline__ float wave_sum64(float v) {
#pragma unroll
  for (int off = 32; off; off >>= 1) v += __shfl_down(v, off);
  return v;
}

// A0 = A + I  (4096x4096)
__global__ void k_add_eye(const float* __restrict__ A, float* __restrict__ O) {
  size_t i = (size_t)blockIdx.x * 256 + threadIdx.x;
  size_t r = i >> 12, c = i & 4095;
  O[i] = A[i] + (r == c ? 1.f : 0.f);
}

__global__ void k_fill0(float* __restrict__ p, int n) {
  int stride = gridDim.x * 256;
  for (int i = blockIdx.x * 256 + threadIdx.x; i < n; i += stride) p[i] = 0.f;
}

// C[M,N] = A[M,K] @ B[K,N] (+ rowBias[m] if non-null). M,N mult of 64, K mult of 16.
__global__ __launch_bounds__(256) void k_gemm_nn(const float* __restrict__ A,
    const float* __restrict__ B, float* __restrict__ C, int M, int N, int K,
    const float* __restrict__ rowBias) {
  __shared__ float As[16][65];
  __shared__ float Bs[16][64];
  int tid = threadIdx.x;
  int tx = tid & 15, ty = tid >> 4;
  int n0 = blockIdx.x * 64, m0 = blockIdx.y * 64;
  float acc[4][4] = {};
  for (int k0 = 0; k0 < K; k0 += 16) {
    {
      int r = tid >> 2, c = (tid & 3) * 4;
      float4 av = *reinterpret_cast<const float4*>(&A[(size_t)(m0 + r) * K + k0 + c]);
      As[c][r] = av.x; As[c + 1][r] = av.y; As[c + 2][r] = av.z; As[c + 3][r] = av.w;
      int rb = tid >> 4, cb = (tid & 15) * 4;
      *reinterpret_cast<float4*>(&Bs[rb][cb]) =
          *reinterpret_cast<const float4*>(&B[(size_t)(k0 + rb) * N + n0 + cb]);
    }
    __syncthreads();
#pragma unroll
    for (int k = 0; k < 16; ++k) {
      float a[4], b[4];
#pragma unroll
      for (int i = 0; i < 4; ++i) a[i] = As[k][ty * 4 + i];
      float4 bv = *reinterpret_cast<const float4*>(&Bs[k][tx * 4]);
      b[0] = bv.x; b[1] = bv.y; b[2] = bv.z; b[3] = bv.w;
#pragma unroll
      for (int i = 0; i < 4; ++i)
#pragma unroll
        for (int j = 0; j < 4; ++j) acc[i][j] = fmaf(a[i], b[j], acc[i][j]);
    }
    __syncthreads();
  }
#pragma unroll
  for (int i = 0; i < 4; ++i) {
    int m = m0 + ty * 4 + i;
    float rb = rowBias ? rowBias[m] : 0.f;
    float4 o;
    o.x = acc[i][0] + rb; o.y = acc[i][1] + rb; o.z = acc[i][2] + rb; o.w = acc[i][3] + rb;
    *reinterpret_cast<float4*>(&C[(size_t)m * N + n0 + tx * 4]) = o;
  }
}

// src[n,h] = sum_f Xp[n,h,f]*a_src[h,f]; dst likewise. block = 64*H threads.
__global__ void k_src_dst(const float* __restrict__ Xp, const float* __restrict__ a_src,
    const float* __restrict__ a_dst, float* __restrict__ src, float* __restrict__ dst,
    int H, int F) {
  int n = blockIdx.x;
  int h = threadIdx.x >> 6, lane = threadIdx.x & 63;
  const float* x = Xp + ((size_t)n * H + h) * F;
  const float* as = a_src + h * F;
  const float* ad = a_dst + h * F;
  float ps = 0.f, pd = 0.f;
  for (int f = lane; f < F; f += 64) {
    float xv = x[f];
    ps = fmaf(xv, as[f], ps);
    pd = fmaf(xv, ad[f], pd);
  }
  ps = wave_sum64(ps);
  pd = wave_sum64(pd);
  if (lane == 0) { src[n * H + h] = ps; dst[n * H + h] = pd; }
}

// denom[i,h] = sum_j valid(i,j) * exp(lrelu(dst[i,h]+src[j,h]))
__global__ __launch_bounds__(256) void k_att_denom(const float* __restrict__ Adj,
    const float* __restrict__ src, const float* __restrict__ dst, float* __restrict__ denom,
    int N, int H) {
  int i = blockIdx.x, tid = threadIdx.x;
  float di[4];
#pragma unroll
  for (int h = 0; h < 4; ++h) di[h] = (h < H) ? dst[i * H + h] : 0.f;
  float acc[4] = {0.f, 0.f, 0.f, 0.f};
  const float* row = Adj + (size_t)i * N;
  for (int j = tid; j < N; j += 256) {
    float av = row[j];
    if (av != 0.f || j == i) {
#pragma unroll
      for (int h = 0; h < 4; ++h) {
        if (h < H) {
          float t = di[h] + src[j * H + h];
          t = t >= 0.f ? t : 0.2f * t;
          acc[h] += expf(t);
        }
      }
    }
  }
  __shared__ float red[4][4];
#pragma unroll
  for (int h = 0; h < 4; ++h) acc[h] = wave_sum64(acc[h]);
  if ((tid & 63) == 0) {
#pragma unroll
    for (int h = 0; h < 4; ++h) red[tid >> 6][h] = acc[h];
  }
  __syncthreads();
  if (tid < H) denom[i * H + tid] = red[0][tid] + red[1][tid] + red[2][tid] + red[3][tid];
}

// Out[i, h*F+f] = relu( (sum_j w(i,j,h) Xp[j,h,f]) / denom[i,h] + bias[h*F+f] )
// w generated on the fly from Adj mask + rank-1 logits. grid: (N/64, H*(F/64)).
__global__ __launch_bounds__(256) void k_gat_gemm(const float* __restrict__ Adj,
    const float* __restrict__ Xp, const float* __restrict__ src, const float* __restrict__ dst,
    const float* __restrict__ denom, const float* __restrict__ bias, float* __restrict__ Out,
    int N, int H, int F) {
  __shared__ float wT[64][65];
  __shared__ float xs[64][64];
  __shared__ float dsl[64], ssl[64], dnl[64];
  int ftiles = F >> 6;
  int h = blockIdx.y / ftiles;
  int f0 = (blockIdx.y % ftiles) << 6;
  int i0 = blockIdx.x << 6;
  int tid = threadIdx.x;
  int tx = tid & 15, ty = tid >> 4;
  if (tid < 64) {
    dsl[tid] = dst[(i0 + tid) * H + h];
    dnl[tid] = 1.f / denom[(i0 + tid) * H + h];
  }
  int r = tid >> 2, cbase = (tid & 3) << 4;
  float acc[4][4] = {};
  for (int j0 = 0; j0 < N; j0 += 64) {
    __syncthreads();
    if (tid < 64) ssl[tid] = src[(j0 + tid) * H + h];
    __syncthreads();
    {
      const float* arow = Adj + (size_t)(i0 + r) * N + j0;
      float di = dsl[r];
      int gi = i0 + r;
#pragma unroll
      for (int q = 0; q < 4; ++q) {
        float4 av = *reinterpret_cast<const float4*>(&arow[cbase + q * 4]);
        float vv[4] = {av.x, av.y, av.z, av.w};
#pragma unroll
        for (int e = 0; e < 4; ++e) {
          int c = cbase + q * 4 + e;
          float w = 0.f;
          if (vv[e] != 0.f || (j0 + c) == gi) {
            float t = di + ssl[c];
            t = t >= 0.f ? t : 0.2f * t;
            w = expf(t);
          }
          wT[c][r] = w;
        }
      }
      const float* xrow = Xp + ((size_t)(j0 + r) * H + h) * F + f0;
#pragma unroll
      for (int q = 0; q < 4; ++q) {
        *reinterpret_cast<float4*>(&xs[r][cbase + q * 4]) =
            *reinterpret_cast<const float4*>(&xrow[cbase + q * 4]);
      }
    }
    __syncthreads();
#pragma unroll 8
    for (int k = 0; k < 64; ++k) {
      float a[4], b[4];
#pragma unroll
      for (int i = 0; i < 4; ++i) a[i] = wT[k][ty * 4 + i];
      float4 bv = *reinterpret_cast<const float4*>(&xs[k][tx * 4]);
      b[0] = bv.x; b[1] = bv.y; b[2] = bv.z; b[3] = bv.w;
#pragma unroll
      for (int i = 0; i < 4; ++i)
#pragma unroll
        for (int j = 0; j < 4; ++j) acc[i][j] = fmaf(a[i], b[j], acc[i][j]);
    }
  }
  int HF = H * F;
  float4 bz = *reinterpret_cast<const float4*>(&bias[h * F + f0 + tx * 4]);
#pragma unroll
  for (int i = 0; i < 4; ++i) {
    int rl = ty * 4 + i;
    float inv = dnl[rl];
    float4 o;
    o.x = fmaxf(fmaf(acc[i][0], inv, bz.x), 0.f);
    o.y = fmaxf(fmaf(acc[i][1], inv, bz.y), 0.f);
    o.z = fmaxf(fmaf(acc[i][2], inv, bz.z), 0.f);
    o.w = fmaxf(fmaf(acc[i][3], inv, bz.w), 0.f);
    *reinterpret_cast<float4*>(&Out[(size_t)(i0 + rl) * HF + h * F + f0 + tx * 4]) = o;
  }
}

// s[row] = sigmoid(dot(X[row,:], w) + b). one wave per row; grid = N/4 blocks of 256.
__global__ __launch_bounds__(256) void k_score(const float* __restrict__ Xf,
    const float* __restrict__ wv, const float* __restrict__ bsc, float* __restrict__ s, int D) {
  int row = blockIdx.x * 4 + (threadIdx.x >> 6);
  int lane = threadIdx.x & 63;
  const float* x = Xf + (size_t)row * D;
  float p = 0.f;
  for (int f = lane; f < D; f += 64) p = fmaf(x[f], wv[f], p);
  p = wave_sum64(p);
  if (lane == 0) s[row] = 1.f / (1.f + expf(-(p + bsc[0])));
}

// single-block bitonic sort: key = (value desc, index asc); outputs top-k idx + values.
__global__ __launch_bounds__(1024) void k_topk_sort(const float* __restrict__ s, int n, int k,
    int* __restrict__ idx, float* __restrict__ vals) {
  extern __shared__ unsigned long long keys[];
  int tid = threadIdx.x;
  for (int i = tid; i < n; i += 1024) {
    unsigned u = __float_as_uint(s[i]);
    unsigned ord = (u & 0x80000000u) ? ~u : (u | 0x80000000u);
    keys[i] = ((unsigned long long)(~ord) << 32) | (unsigned)i;
  }
  __syncthreads();
  for (int size = 2; size <= n; size <<= 1) {
    for (int stride = size >> 1; stride > 0; stride >>= 1) {
      for (int i = tid; i < n; i += 1024) {
        int p = i ^ stride;
        if (p > i) {
          bool up = ((i & size) == 0);
          unsigned long long a = keys[i], b = keys[p];
          if (up ? (a > b) : (a < b)) { keys[i] = b; keys[p] = a; }
        }
      }
      __syncthreads();
    }
  }
  for (int i = tid; i < k; i += 1024) {
    int id = (int)(keys[i] & 0xffffffffu);
    idx[i] = id;
    vals[i] = s[id];
  }
}

// sv[i] = (sum_j Asrc[idx[i], idx[j]] + 1e-5)^-0.5
__global__ __launch_bounds__(256) void k_gather_rowsum(const float* __restrict__ Asrc, int lda,
    const int* __restrict__ idx, int k, float* __restrict__ sv) {
  int i = blockIdx.x;
  const float* row = Asrc + (size_t)idx[i] * lda;
  float p = 0.f;
  for (int j = threadIdx.x; j < k; j += 256) p += row[idx[j]];
  p = wave_sum64(p);
  __shared__ float red[4];
  if ((threadIdx.x & 63) == 0) red[threadIdx.x >> 6] = p;
  __syncthreads();
  if (threadIdx.x == 0) sv[i] = 1.f / sqrtf(red[0] + red[1] + red[2] + red[3] + 1e-5f);
}

__global__ void k_symnorm_write(const float* __restrict__ Asrc, int lda,
    const int* __restrict__ idx, const float* __restrict__ sv, float* __restrict__ B, int k) {
  int j = blockIdx.x * 256 + threadIdx.x;
  int i = blockIdx.y;
  B[(size_t)i * k + j] = Asrc[(size_t)idx[i] * lda + idx[j]] * sv[i] * sv[j];
}

__global__ void k_gather_mat(const float* __restrict__ Asrc, int lda,
    const int* __restrict__ idx, float* __restrict__ B, int k) {
  int j = blockIdx.x * 256 + threadIdx.x;
  int i = blockIdx.y;
  B[(size_t)i * k + j] = Asrc[(size_t)idx[i] * lda + idx[j]];
}

__global__ void k_gather_scale_rows(const float* __restrict__ Xs, int D,
    const int* __restrict__ idx, const float* __restrict__ v, float* __restrict__ Xo) {
  int f = blockIdx.x * 256 + threadIdx.x;
  int i = blockIdx.y;
  Xo[(size_t)i * D + f] = Xs[(size_t)idx[i] * D + f] * v[i];
}

__global__ void k_scatter_rows(const float* __restrict__ P, int D, const int* __restrict__ idx,
                               float* __restrict__ Xo) {
  int f = blockIdx.x * 256 + threadIdx.x;
  int i = blockIdx.y;
  Xo[(size_t)idx[i] * D + f] = P[(size_t)i * D + f];
}

// row softmax for D=256, one block per row
__global__ __launch_bounds__(256) void k_softmax256(float* __restrict__ Z) {
  int row = blockIdx.x, tid = threadIdx.x;
  float x = Z[(size_t)row * 256 + tid];
  float m = x;
#pragma unroll
  for (int off = 32; off; off >>= 1) m = fmaxf(m, __shfl_down(m, off));
  __shared__ float red[4];
  __shared__ float bm, bs;
  if ((tid & 63) == 0) red[tid >> 6] = m;
  __syncthreads();
  if (tid == 0) bm = fmaxf(fmaxf(red[0], red[1]), fmaxf(red[2], red[3]));
  __syncthreads();
  float e = expf(x - bm);
  float sm = wave_sum64(e);
  __syncthreads();
  if ((tid & 63) == 0) red[tid >> 6] = sm;
  __syncthreads();
  if (tid == 0) bs = red[0] + red[1] + red[2] + red[3];
  __syncthreads();
  Z[(size_t)row * 256 + tid] = e / bs;
}

// C = relu(G @ G^T), symmetric; only upper-tri tiles computed, mirrored via LDS.
__global__ __launch_bounds__(256) void k_syrk_relu(const float* __restrict__ G, int M, int Kd,
                                                   float* __restrict__ C) {
  int bi = blockIdx.y, bj = blockIdx.x;
  if (bj < bi) return;
  __shared__ float As[16][65], Bs[16][65];
  __shared__ float Ct[64][68];
  int tid = threadIdx.x;
  int tx = tid & 15, ty = tid >> 4;
  int i0 = bi << 6, j0 = bj << 6;
  int r = tid >> 2, c4 = (tid & 3) * 4;
  float acc[4][4] = {};
  for (int k0 = 0; k0 < Kd; k0 += 16) {
    float4 av = *reinterpret_cast<const float4*>(&G[(size_t)(i0 + r) * Kd + k0 + c4]);
    float4 bv = *reinterpret_cast<const float4*>(&G[(size_t)(j0 + r) * Kd + k0 + c4]);
    As[c4][r] = av.x; As[c4 + 1][r] = av.y; As[c4 + 2][r] = av.z; As[c4 + 3][r] = av.w;
    Bs[c4][r] = bv.x; Bs[c4 + 1][r] = bv.y; Bs[c4 + 2][r] = bv.z; Bs[c4 + 3][r] = bv.w;
    __syncthreads();
#pragma unroll
    for (int k = 0; k < 16; ++k) {
      float a[4], b[4];
#pragma unroll
      for (int i = 0; i < 4; ++i) { a[i] = As[k][ty * 4 + i]; b[i] = Bs[k][tx * 4 + i]; }
#pragma unroll
      for (int i = 0; i < 4; ++i)
#pragma unroll
        for (int j = 0; j < 4; ++j) acc[i][j] = fmaf(a[i], b[j], acc[i][j]);
    }
    __syncthreads();
  }
#pragma unroll
  for (int i = 0; i < 4; ++i) {
    float v0 = fmaxf(acc[i][0], 0.f), v1 = fmaxf(acc[i][1], 0.f);
    float v2 = fmaxf(acc[i][2], 0.f), v3 = fmaxf(acc[i][3], 0.f);
    float4 o; o.x = v0; o.y = v1; o.z = v2; o.w = v3;
    *reinterpret_cast<float4*>(&C[(size_t)(i0 + ty * 4 + i) * M + j0 + tx * 4]) = o;
    Ct[tx * 4 + 0][ty * 4 + i] = v0; Ct[tx * 4 + 1][ty * 4 + i] = v1;
    Ct[tx * 4 + 2][ty * 4 + i] = v2; Ct[tx * 4 + 3][ty * 4 + i] = v3;
  }
  if (bi != bj) {
    __syncthreads();
    int rr = tid >> 2, cb = (tid & 3) << 4;
#pragma unroll
    for (int q = 0; q < 4; ++q) {
      float4 w = *reinterpret_cast<const float4*>(&Ct[rr][cb + q * 4]);
      *reinterpret_cast<float4*>(&C[(size_t)(j0 + rr) * M + i0 + cb + q * 4]) = w;
    }
  }
}

extern "C" void kernel_launch(void* const* d_in, const int* in_sizes, int n_in,
                              void* d_out, int out_size, void* d_ws, size_t ws_size,
                              hipStream_t stream) {
  const float* A    = (const float*)d_in[0];
  const float* X    = (const float*)d_in[1];
  const float* Wd0  = (const float*)d_in[2];
  const float* asd0 = (const float*)d_in[3];
  const float* add0 = (const float*)d_in[4];
  const float* bd0  = (const float*)d_in[5];
  const float* Wd1  = (const float*)d_in[6];
  const float* asd1 = (const float*)d_in[7];
  const float* add1 = (const float*)d_in[8];
  const float* bd1  = (const float*)d_in[9];
  const float* wp0  = (const float*)d_in[10];
  const float* bp0  = (const float*)d_in[11];
  const float* wp1  = (const float*)d_in[12];
  const float* bp1  = (const float*)d_in[13];
  const float* Wb   = (const float*)d_in[14];
  const float* asb  = (const float*)d_in[15];
  const float* adb  = (const float*)d_in[16];
  const float* bb   = (const float*)d_in[17];
  const float* Wu0  = (const float*)d_in[18];
  const float* asu0 = (const float*)d_in[19];
  const float* adu0 = (const float*)d_in[20];
  const float* bu0  = (const float*)d_in[21];
  const float* Wu1  = (const float*)d_in[22];
  const float* asu1 = (const float*)d_in[23];
  const float* adu1 = (const float*)d_in[24];
  const float* bu1  = (const float*)d_in[25];
  const float* Wup  = (const float*)d_in[26];
  const float* bup  = (const float*)d_in[27];
  (void)in_sizes; (void)n_in; (void)out_size; (void)ws_size;

  float* out  = (float*)d_out;
  float* Aup  = out;                    // [8192*8192]
  float* A0   = out + 67108864ULL;      // [4096*4096]
  float* A1   = A0 + 16777216ULL;       // [2048*2048]
  float* rec0 = A1 + 4194304ULL;        // [2048*2048]
  float* rec1 = rec0 + 4194304ULL;      // [4096*4096]

  // Scratch: intermediates live inside the A_up output region (written last,
  // all scratch dead by then). Final-stage-live buffers (Xu1, ZL) use d_ws.
  float* S = Aup;
  size_t off = 0;
  auto nxt = [&](size_t n) { float* p = S + off; off += (n + 1023) & ~(size_t)1023; return p; };
  float* Xp0  = nxt(4096 * 512);
  float* X0   = nxt(4096 * 512);
  float* src0 = nxt(4096 * 4);
  float* dst0 = nxt(4096 * 4);
  float* den0 = nxt(4096 * 4);
  float* sc0  = nxt(4096);
  int*   idx0 = (int*)nxt(2048);
  float* v0   = nxt(2048);
  float* sv0  = nxt(2048);
  float* X1in = nxt(2048 * 512);
  float* Xp1  = nxt(2048 * 1024);
  float* X1   = nxt(2048 * 1024);
  float* src1 = nxt(2048 * 4);
  float* dst1 = nxt(2048 * 4);
  float* den1 = nxt(2048 * 4);
  float* sc1  = nxt(2048);
  int*   idx1 = (int*)nxt(1024);
  float* v1   = nxt(1024);
  float* A2m  = nxt(1024 * 1024);
  float* X2in = nxt(1024 * 1024);
  float* Xpb  = nxt(1024 * 1024);
  float* Xb   = nxt(1024 * 1024);
  float* srcb = nxt(1024 * 2);
  float* dstb = nxt(1024 * 2);
  float* denb = nxt(1024 * 2);
  float* Pu0  = nxt(1024 * 512);
  float* Xpu0 = nxt(2048 * 512);
  float* Xu0  = nxt(2048 * 512);
  float* su0  = nxt(2048 * 4);
  float* du0  = nxt(2048 * 4);
  float* dn0  = nxt(2048 * 4);
  float* Pu1  = nxt(2048 * 256);
  float* Xpu1 = nxt(4096 * 256);
  float* su1  = nxt(4096 * 4);
  float* du1  = nxt(4096 * 4);
  float* dn1  = nxt(4096 * 4);
  float* W   = (float*)d_ws;
  float* Xu1 = W;                 // [4096*256]
  float* ZL  = W + 1048576;       // [8192*256]

  // ---- A0 = A + I ----
  k_add_eye<<<65536, 256, 0, stream>>>(A, A0);

  // ---- down level 0: GAT(256 -> 4x128) ----
  k_gemm_nn<<<dim3(8, 64), 256, 0, stream>>>(X, Wd0, Xp0, 4096, 512, 256, nullptr);
  k_src_dst<<<4096, 256, 0, stream>>>(Xp0, asd0, add0, src0, dst0, 4, 128);
  k_att_denom<<<4096, 256, 0, stream>>>(A0, src0, dst0, den0, 4096, 4);
  k_gat_gemm<<<dim3(64, 8), 256, 0, stream>>>(A0, Xp0, src0, dst0, den0, bd0, X0, 4096, 4, 128);
  k_score<<<1024, 256, 0, stream>>>(X0, wp0, bp0, sc0, 512);
  k_topk_sort<<<1, 1024, 4096 * 8, stream>>>(sc0, 4096, 2048, idx0, v0);
  k_gather_rowsum<<<2048, 256, 0, stream>>>(A0, 4096, idx0, 2048, sv0);
  k_symnorm_write<<<dim3(8, 2048), 256, 0, stream>>>(A0, 4096, idx0, sv0, A1, 2048);
  k_gather_scale_rows<<<dim3(2, 2048), 256, 0, stream>>>(X0, 512, idx0, v0, X1in);

  // ---- down level 1: GAT(512 -> 4x256) ----
  k_gemm_nn<<<dim3(16, 32), 256, 0, stream>>>(X1in, Wd1, Xp1, 2048, 1024, 512, nullptr);
  k_src_dst<<<2048, 256, 0, stream>>>(Xp1, asd1, add1, src1, dst1, 4, 256);
  k_att_denom<<<2048, 256, 0, stream>>>(A1, src1, dst1, den1, 2048, 4);
  k_gat_gemm<<<dim3(32, 16), 256, 0, stream>>>(A1, Xp1, src1, dst1, den1, bd1, X1, 2048, 4, 256);
  k_score<<<512, 256, 0, stream>>>(X1, wp1, bp1, sc1, 1024);
  k_topk_sort<<<1, 1024, 2048 * 8, stream>>>(sc1, 2048, 1024, idx1, v1);
  k_gather_mat<<<dim3(4, 1024), 256, 0, stream>>>(A1, 2048, idx1, A2m, 1024);
  k_gather_scale_rows<<<dim3(4, 1024), 256, 0, stream>>>(X1, 1024, idx1, v1, X2in);

  // ---- bottom: GAT(1024 -> 2x512), A2 used as mask only ----
  k_gemm_nn<<<dim3(16, 16), 256, 0, stream>>>(X2in, Wb, Xpb, 1024, 1024, 1024, nullptr);
  k_src_dst<<<1024, 128, 0, stream>>>(Xpb, asb, adb, srcb, dstb, 2, 512);
  k_att_denom<<<1024, 256, 0, stream>>>(A2m, srcb, dstb, denb, 1024, 2);
  k_gat_gemm<<<dim3(16, 16), 256, 0, stream>>>(A2m, Xpb, srcb, dstb, denb, bb, Xb, 1024, 2, 512);

  // ---- up level 0: unpool -> GAT(1024 -> 4x128) over A1 ----
  k_gemm_nn<<<dim3(8, 16), 256, 0, stream>>>(Xb, Wu0, Pu0, 1024, 512, 1024, nullptr);
  k_fill0<<<1024, 256, 0, stream>>>(Xpu0, 2048 * 512);
  k_scatter_rows<<<dim3(2, 1024), 256, 0, stream>>>(Pu0, 512, idx1, Xpu0);
  k_src_dst<<<2048, 256, 0, stream>>>(Xpu0, asu0, adu0, su0, du0, 4, 128);
  k_att_denom<<<2048, 256, 0, stream>>>(A1, su0, du0, dn0, 2048, 4);
  k_gat_gemm<<<dim3(32, 8), 256, 0, stream>>>(A1, Xpu0, su0, du0, dn0, bu0, Xu0, 2048, 4, 128);
  k_syrk_relu<<<dim3(32, 32), 256, 0, stream>>>(Xu0, 2048, 512, rec0);

  // ---- up level 1: unpool -> GAT(512 -> 4x64) over A0 ----
  k_gemm_nn<<<dim3(4, 32), 256, 0, stream>>>(Xu0, Wu1, Pu1, 2048, 256, 512, nullptr);
  k_fill0<<<1024, 256, 0, stream>>>(Xpu1, 4096 * 256);
  k_scatter_rows<<<dim3(1, 2048), 256, 0, stream>>>(Pu1, 256, idx0, Xpu1);
  k_src_dst<<<4096, 256, 0, stream>>>(Xpu1, asu1, adu1, su1, du1, 4, 64);
  k_att_denom<<<4096, 256, 0, stream>>>(A0, su1, du1, dn1, 4096, 4);
  k_gat_gemm<<<dim3(64, 4), 256, 0, stream>>>(A0, Xpu1, su1, du1, dn1, bu1, Xu1, 4096, 4, 64);
  k_syrk_relu<<<dim3(64, 64), 256, 0, stream>>>(Xu1, 4096, 256, rec1);

  // ---- upsampler: Z = softmax(Wup@Xu1 + bup), A_up = relu(Z@Z^T) ----
  k_gemm_nn<<<dim3(4, 128), 256, 0, stream>>>(Wup, Xu1, ZL, 8192, 256, 4096, bup);
  k_softmax256<<<8192, 256, 0, stream>>>(ZL);
  k_syrk_relu<<<dim3(128, 128), 256, 0, stream>>>(ZL, 8192, 256, Aup);
}

// Round 2
// 2073.464 us; speedup vs baseline: 1.3032x; 1.3032x over previous
//
#include <hip/hip_runtime.h>
#include <math.h>

// ---------------------------------------------------------------------------
// Graph U-Net forward on MI355X.
// Down path (feeds top-k orderings) stays fp32 vector. Post-idx1 heavy GEMMs
// (rec0, rec1, A_up, Wup@Xu1) use bf16 MFMA (16x16x32).
// ---------------------------------------------------------------------------

typedef short bf16x8 __attribute__((ext_vector_type(8)));
typedef float f32x4 __attribute__((ext_vector_type(4)));

static __device__ __forceinline__ float wave_sum64(float v) {
#pragma unroll
  for (int off = 32; off; off >>= 1) v += __shfl_down(v, off);
  return v;
}

static __device__ __forceinline__ unsigned short f2b(float x) {
  unsigned u = __float_as_uint(x);
  unsigned r = (u + 0x7fffu + ((u >> 16) & 1u)) >> 16;
  return (unsigned short)r;
}

// A0 = A + I  (4096x4096)
__global__ void k_add_eye(const float* __restrict__ A, float* __restrict__ O) {
  size_t i = (size_t)blockIdx.x * 256 + threadIdx.x;
  size_t r = i >> 12, c = i & 4095;
  O[i] = A[i] + (r == c ? 1.f : 0.f);
}

__global__ void k_fill0(float* __restrict__ p, int n) {
  int stride = gridDim.x * 256;
  for (int i = blockIdx.x * 256 + threadIdx.x; i < n; i += stride) p[i] = 0.f;
}

__global__ void k_f32_to_bf16(const float* __restrict__ S, unsigned short* __restrict__ D,
                              int n) {
  int stride = gridDim.x * 1024;
  for (int i = (blockIdx.x * 256 + threadIdx.x) * 4; i < n; i += stride) {
    float4 v = *reinterpret_cast<const float4*>(&S[i]);
    uint2 o;
    o.x = (unsigned)f2b(v.x) | ((unsigned)f2b(v.y) << 16);
    o.y = (unsigned)f2b(v.z) | ((unsigned)f2b(v.w) << 16);
    *reinterpret_cast<uint2*>(&D[i]) = o;
  }
}

// D[c][r] = bf16(S[r][c]); S is [R][Cc] f32, D is [Cc][R] bf16. 64x64 tiles.
__global__ __launch_bounds__(256) void k_transpose_bf16(const float* __restrict__ S,
    unsigned short* __restrict__ D, int R, int Cc) {
  __shared__ unsigned short T[64][72];
  int r0 = blockIdx.y << 6, c0 = blockIdx.x << 6;
  int tid = threadIdx.x;
  int tr = tid >> 4, tc4 = (tid & 15) << 2;
#pragma unroll
  for (int q = 0; q < 4; ++q) {
    int row = tr + q * 16;
    float4 v = *reinterpret_cast<const float4*>(&S[(size_t)(r0 + row) * Cc + c0 + tc4]);
    T[tc4 + 0][row] = f2b(v.x);
    T[tc4 + 1][row] = f2b(v.y);
    T[tc4 + 2][row] = f2b(v.z);
    T[tc4 + 3][row] = f2b(v.w);
  }
  __syncthreads();
#pragma unroll
  for (int q = 0; q < 4; ++q) {
    int row = tr + q * 16;  // row in D tile = original column
    *reinterpret_cast<uint2*>(&D[(size_t)(c0 + row) * R + r0 + tc4]) =
        *reinterpret_cast<const uint2*>(&T[row][tc4]);
  }
}

// C[M,N] = A[M,K] @ B[K,N] (+ rowBias[m] if non-null). fp32 vector (down path).
__global__ __launch_bounds__(256) void k_gemm_nn(const float* __restrict__ A,
    const float* __restrict__ B, float* __restrict__ C, int M, int N, int K,
    const float* __restrict__ rowBias) {
  __shared__ float As[16][65];
  __shared__ float Bs[16][64];
  int tid = threadIdx.x;
  int tx = tid & 15, ty = tid >> 4;
  int n0 = blockIdx.x * 64, m0 = blockIdx.y * 64;
  float acc[4][4] = {};
  for (int k0 = 0; k0 < K; k0 += 16) {
    {
      int r = tid >> 2, c = (tid & 3) * 4;
      float4 av = *reinterpret_cast<const float4*>(&A[(size_t)(m0 + r) * K + k0 + c]);
      As[c][r] = av.x; As[c + 1][r] = av.y; As[c + 2][r] = av.z; As[c + 3][r] = av.w;
      int rb = tid >> 4, cb = (tid & 15) * 4;
      *reinterpret_cast<float4*>(&Bs[rb][cb]) =
          *reinterpret_cast<const float4*>(&B[(size_t)(k0 + rb) * N + n0 + cb]);
    }
    __syncthreads();
#pragma unroll
    for (int k = 0; k < 16; ++k) {
      float a[4], b[4];
#pragma unroll
      for (int i = 0; i < 4; ++i) a[i] = As[k][ty * 4 + i];
      float4 bv = *reinterpret_cast<const float4*>(&Bs[k][tx * 4]);
      b[0] = bv.x; b[1] = bv.y; b[2] = bv.z; b[3] = bv.w;
#pragma unroll
      for (int i = 0; i < 4; ++i)
#pragma unroll
        for (int j = 0; j < 4; ++j) acc[i][j] = fmaf(a[i], b[j], acc[i][j]);
    }
    __syncthreads();
  }
#pragma unroll
  for (int i = 0; i < 4; ++i) {
    int m = m0 + ty * 4 + i;
    float rb = rowBias ? rowBias[m] : 0.f;
    float4 o;
    o.x = acc[i][0] + rb; o.y = acc[i][1] + rb; o.z = acc[i][2] + rb; o.w = acc[i][3] + rb;
    *reinterpret_cast<float4*>(&C[(size_t)m * N + n0 + tx * 4]) = o;
  }
}

// ---- bf16 MFMA kernels: 128x128 block, 4 waves, per-wave 64x64 via 16x16x32 ----

// C = relu(G @ G^T). G bf16 [M][Kd] row-major, C f32 [M][M]. Full grid (M/128)^2.
__global__ __launch_bounds__(256) void k_syrk_mfma(const unsigned short* __restrict__ G,
    int M, int Kd, float* __restrict__ C) {
  __shared__ __align__(16) unsigned short Ai[128 * 40];
  __shared__ __align__(16) unsigned short Bj[128 * 40];
  int tid = threadIdx.x;
  int i0 = blockIdx.y << 7, j0 = blockIdx.x << 7;
  int srow = tid >> 1, scol = (tid & 1) << 3;
  int lane = tid & 63, w = tid >> 6;
  int wr = (w >> 1) << 6, wc = (w & 1) << 6;
  int lr = lane & 15, kb = lane >> 4;
  f32x4 acc[4][4] = {};
  const unsigned short* gA = G + (size_t)i0 * Kd;
  const unsigned short* gB = G + (size_t)j0 * Kd;
  for (int k0 = 0; k0 < Kd; k0 += 32) {
    __syncthreads();
#pragma unroll
    for (int kk = 0; kk < 32; kk += 16) {
      *reinterpret_cast<uint4*>(&Ai[srow * 40 + scol + kk]) =
          *reinterpret_cast<const uint4*>(&gA[(size_t)srow * Kd + k0 + scol + kk]);
      *reinterpret_cast<uint4*>(&Bj[srow * 40 + scol + kk]) =
          *reinterpret_cast<const uint4*>(&gB[(size_t)srow * Kd + k0 + scol + kk]);
    }
    __syncthreads();
    bf16x8 a[4], b[4];
#pragma unroll
    for (int m = 0; m < 4; ++m)
      a[m] = *reinterpret_cast<const bf16x8*>(&Ai[(wr + m * 16 + lr) * 40 + kb * 8]);
#pragma unroll
    for (int n = 0; n < 4; ++n)
      b[n] = *reinterpret_cast<const bf16x8*>(&Bj[(wc + n * 16 + lr) * 40 + kb * 8]);
#pragma unroll
    for (int m = 0; m < 4; ++m)
#pragma unroll
      for (int n = 0; n < 4; ++n)
        acc[m][n] = __builtin_amdgcn_mfma_f32_16x16x32_bf16(a[m], b[n], acc[m][n], 0, 0, 0);
  }
  int orow = i0 + wr + (lane >> 4) * 4;
  int ocol = j0 + wc + (lane & 15);
#pragma unroll
  for (int m = 0; m < 4; ++m)
#pragma unroll
    for (int n = 0; n < 4; ++n)
#pragma unroll
      for (int r = 0; r < 4; ++r)
        C[(size_t)(orow + m * 16 + r) * M + ocol + n * 16] = fmaxf(acc[m][n][r], 0.f);
}

// C[M,N] = A[M,K] @ BT[N,K]^T + bias[m]. A,BT bf16 row-major, C f32. No relu.
__global__ __launch_bounds__(256) void k_gemm_mfma_bt(const unsigned short* __restrict__ Amat,
    const unsigned short* __restrict__ BT, const float* __restrict__ bias,
    float* __restrict__ C, int M, int N, int Kd) {
  __shared__ __align__(16) unsigned short Ai[128 * 40];
  __shared__ __align__(16) unsigned short Bj[128 * 40];
  int tid = threadIdx.x;
  int m0 = blockIdx.y << 7, n0 = blockIdx.x << 7;
  int srow = tid >> 1, scol = (tid & 1) << 3;
  int lane = tid & 63, w = tid >> 6;
  int wr = (w >> 1) << 6, wc = (w & 1) << 6;
  int lr = lane & 15, kb = lane >> 4;
  f32x4 acc[4][4] = {};
  const unsigned short* gA = Amat + (size_t)m0 * Kd;
  const unsigned short* gB = BT + (size_t)n0 * Kd;
  for (int k0 = 0; k0 < Kd; k0 += 32) {
    __syncthreads();
#pragma unroll
    for (int kk = 0; kk < 32; kk += 16) {
      *reinterpret_cast<uint4*>(&Ai[srow * 40 + scol + kk]) =
          *reinterpret_cast<const uint4*>(&gA[(size_t)srow * Kd + k0 + scol + kk]);
      *reinterpret_cast<uint4*>(&Bj[srow * 40 + scol + kk]) =
          *reinterpret_cast<const uint4*>(&gB[(size_t)srow * Kd + k0 + scol + kk]);
    }
    __syncthreads();
    bf16x8 a[4], b[4];
#pragma unroll
    for (int m = 0; m < 4; ++m)
      a[m] = *reinterpret_cast<const bf16x8*>(&Ai[(wr + m * 16 + lr) * 40 + kb * 8]);
#pragma unroll
    for (int n = 0; n < 4; ++n)
      b[n] = *reinterpret_cast<const bf16x8*>(&Bj[(wc + n * 16 + lr) * 40 + kb * 8]);
#pragma unroll
    for (int m = 0; m < 4; ++m)
#pragma unroll
      for (int n = 0; n < 4; ++n)
        acc[m][n] = __builtin_amdgcn_mfma_f32_16x16x32_bf16(a[m], b[n], acc[m][n], 0, 0, 0);
  }
  int orow = m0 + wr + (lane >> 4) * 4;
  int ocol = n0 + wc + (lane & 15);
#pragma unroll
  for (int m = 0; m < 4; ++m)
#pragma unroll
    for (int n = 0; n < 4; ++n)
#pragma unroll
      for (int r = 0; r < 4; ++r)
        C[(size_t)(orow + m * 16 + r) * N + ocol + n * 16] =
            acc[m][n][r] + bias[orow + m * 16 + r];
}

// src[n,h] = sum_f Xp[n,h,f]*a_src[h,f]; dst likewise. block = 64*H threads.
__global__ void k_src_dst(const float* __restrict__ Xp, const float* __restrict__ a_src,
    const float* __restrict__ a_dst, float* __restrict__ src, float* __restrict__ dst,
    int H, int F) {
  int n = blockIdx.x;
  int h = threadIdx.x >> 6, lane = threadIdx.x & 63;
  const float* x = Xp + ((size_t)n * H + h) * F;
  const float* as = a_src + h * F;
  const float* ad = a_dst + h * F;
  float ps = 0.f, pd = 0.f;
  for (int f = lane; f < F; f += 64) {
    float xv = x[f];
    ps = fmaf(xv, as[f], ps);
    pd = fmaf(xv, ad[f], pd);
  }
  ps = wave_sum64(ps);
  pd = wave_sum64(pd);
  if (lane == 0) { src[n * H + h] = ps; dst[n * H + h] = pd; }
}

// denom[i,h] = sum_j valid(i,j) * exp(lrelu(dst[i,h]+src[j,h]))
__global__ __launch_bounds__(256) void k_att_denom(const float* __restrict__ Adj,
    const float* __restrict__ src, const float* __restrict__ dst, float* __restrict__ denom,
    int N, int H) {
  int i = blockIdx.x, tid = threadIdx.x;
  float di[4];
#pragma unroll
  for (int h = 0; h < 4; ++h) di[h] = (h < H) ? dst[i * H + h] : 0.f;
  float acc[4] = {0.f, 0.f, 0.f, 0.f};
  const float* row = Adj + (size_t)i * N;
  for (int j = tid; j < N; j += 256) {
    float av = row[j];
    if (av != 0.f || j == i) {
#pragma unroll
      for (int h = 0; h < 4; ++h) {
        if (h < H) {
          float t = di[h] + src[j * H + h];
          t = t >= 0.f ? t : 0.2f * t;
          acc[h] += expf(t);
        }
      }
    }
  }
  __shared__ float red[4][4];
#pragma unroll
  for (int h = 0; h < 4; ++h) acc[h] = wave_sum64(acc[h]);
  if ((tid & 63) == 0) {
#pragma unroll
    for (int h = 0; h < 4; ++h) red[tid >> 6][h] = acc[h];
  }
  __syncthreads();
  if (tid < H) denom[i * H + tid] = red[0][tid] + red[1][tid] + red[2][tid] + red[3][tid];
}

// Out[i, h*F+f] = relu( (sum_j w(i,j,h) Xp[j,h,f]) / denom[i,h] + bias[h*F+f] )
__global__ __launch_bounds__(256) void k_gat_gemm(const float* __restrict__ Adj,
    const float* __restrict__ Xp, const float* __restrict__ src, const float* __restrict__ dst,
    const float* __restrict__ denom, const float* __restrict__ bias, float* __restrict__ Out,
    int N, int H, int F) {
  __shared__ float wT[64][65];
  __shared__ float xs[64][64];
  __shared__ float dsl[64], ssl[64], dnl[64];
  int ftiles = F >> 6;
  int h = blockIdx.y / ftiles;
  int f0 = (blockIdx.y % ftiles) << 6;
  int i0 = blockIdx.x << 6;
  int tid = threadIdx.x;
  int tx = tid & 15, ty = tid >> 4;
  if (tid < 64) {
    dsl[tid] = dst[(i0 + tid) * H + h];
    dnl[tid] = 1.f / denom[(i0 + tid) * H + h];
  }
  int r = tid >> 2, cbase = (tid & 3) << 4;
  float acc[4][4] = {};
  for (int j0 = 0; j0 < N; j0 += 64) {
    __syncthreads();
    if (tid < 64) ssl[tid] = src[(j0 + tid) * H + h];
    __syncthreads();
    {
      const float* arow = Adj + (size_t)(i0 + r) * N + j0;
      float di = dsl[r];
      int gi = i0 + r;
#pragma unroll
      for (int q = 0; q < 4; ++q) {
        float4 av = *reinterpret_cast<const float4*>(&arow[cbase + q * 4]);
        float vv[4] = {av.x, av.y, av.z, av.w};
#pragma unroll
        for (int e = 0; e < 4; ++e) {
          int c = cbase + q * 4 + e;
          float w = 0.f;
          if (vv[e] != 0.f || (j0 + c) == gi) {
            float t = di + ssl[c];
            t = t >= 0.f ? t : 0.2f * t;
            w = expf(t);
          }
          wT[c][r] = w;
        }
      }
      const float* xrow = Xp + ((size_t)(j0 + r) * H + h) * F + f0;
#pragma unroll
      for (int q = 0; q < 4; ++q) {
        *reinterpret_cast<float4*>(&xs[r][cbase + q * 4]) =
            *reinterpret_cast<const float4*>(&xrow[cbase + q * 4]);
      }
    }
    __syncthreads();
#pragma unroll 8
    for (int k = 0; k < 64; ++k) {
      float a[4], b[4];
#pragma unroll
      for (int i = 0; i < 4; ++i) a[i] = wT[k][ty * 4 + i];
      float4 bv = *reinterpret_cast<const float4*>(&xs[k][tx * 4]);
      b[0] = bv.x; b[1] = bv.y; b[2] = bv.z; b[3] = bv.w;
#pragma unroll
      for (int i = 0; i < 4; ++i)
#pragma unroll
        for (int j = 0; j < 4; ++j) acc[i][j] = fmaf(a[i], b[j], acc[i][j]);
    }
  }
  int HF = H * F;
  float4 bz = *reinterpret_cast<const float4*>(&bias[h * F + f0 + tx * 4]);
#pragma unroll
  for (int i = 0; i < 4; ++i) {
    int rl = ty * 4 + i;
    float inv = dnl[rl];
    float4 o;
    o.x = fmaxf(fmaf(acc[i][0], inv, bz.x), 0.f);
    o.y = fmaxf(fmaf(acc[i][1], inv, bz.y), 0.f);
    o.z = fmaxf(fmaf(acc[i][2], inv, bz.z), 0.f);
    o.w = fmaxf(fmaf(acc[i][3], inv, bz.w), 0.f);
    *reinterpret_cast<float4*>(&Out[(size_t)(i0 + rl) * HF + h * F + f0 + tx * 4]) = o;
  }
}

// s[row] = sigmoid(dot(X[row,:], w) + b)
__global__ __launch_bounds__(256) void k_score(const float* __restrict__ Xf,
    const float* __restrict__ wv, const float* __restrict__ bsc, float* __restrict__ s, int D) {
  int row = blockIdx.x * 4 + (threadIdx.x >> 6);
  int lane = threadIdx.x & 63;
  const float* x = Xf + (size_t)row * D;
  float p = 0.f;
  for (int f = lane; f < D; f += 64) p = fmaf(x[f], wv[f], p);
  p = wave_sum64(p);
  if (lane == 0) s[row] = 1.f / (1.f + expf(-(p + bsc[0])));
}

// single-block bitonic sort: key = (value desc, index asc)
__global__ __launch_bounds__(1024) void k_topk_sort(const float* __restrict__ s, int n, int k,
    int* __restrict__ idx, float* __restrict__ vals) {
  extern __shared__ unsigned long long keys[];
  int tid = threadIdx.x;
  for (int i = tid; i < n; i += 1024) {
    unsigned u = __float_as_uint(s[i]);
    unsigned ord = (u & 0x80000000u) ? ~u : (u | 0x80000000u);
    keys[i] = ((unsigned long long)(~ord) << 32) | (unsigned)i;
  }
  __syncthreads();
  for (int size = 2; size <= n; size <<= 1) {
    for (int stride = size >> 1; stride > 0; stride >>= 1) {
      for (int i = tid; i < n; i += 1024) {
        int p = i ^ stride;
        if (p > i) {
          bool up = ((i & size) == 0);
          unsigned long long a = keys[i], b = keys[p];
          if (up ? (a > b) : (a < b)) { keys[i] = b; keys[p] = a; }
        }
      }
      __syncthreads();
    }
  }
  for (int i = tid; i < k; i += 1024) {
    int id = (int)(keys[i] & 0xffffffffu);
    idx[i] = id;
    vals[i] = s[id];
  }
}

__global__ __launch_bounds__(256) void k_gather_rowsum(const float* __restrict__ Asrc, int lda,
    const int* __restrict__ idx, int k, float* __restrict__ sv) {
  int i = blockIdx.x;
  const float* row = Asrc + (size_t)idx[i] * lda;
  float p = 0.f;
  for (int j = threadIdx.x; j < k; j += 256) p += row[idx[j]];
  p = wave_sum64(p);
  __shared__ float red[4];
  if ((threadIdx.x & 63) == 0) red[threadIdx.x >> 6] = p;
  __syncthreads();
  if (threadIdx.x == 0) sv[i] = 1.f / sqrtf(red[0] + red[1] + red[2] + red[3] + 1e-5f);
}

__global__ void k_symnorm_write(const float* __restrict__ Asrc, int lda,
    const int* __restrict__ idx, const float* __restrict__ sv, float* __restrict__ B, int k) {
  int j = blockIdx.x * 256 + threadIdx.x;
  int i = blockIdx.y;
  B[(size_t)i * k + j] = Asrc[(size_t)idx[i] * lda + idx[j]] * sv[i] * sv[j];
}

__global__ void k_gather_mat(const float* __restrict__ Asrc, int lda,
    const int* __restrict__ idx, float* __restrict__ B, int k) {
  int j = blockIdx.x * 256 + threadIdx.x;
  int i = blockIdx.y;
  B[(size_t)i * k + j] = Asrc[(size_t)idx[i] * lda + idx[j]];
}

__global__ void k_gather_scale_rows(const float* __restrict__ Xs, int D,
    const int* __restrict__ idx, const float* __restrict__ v, float* __restrict__ Xo) {
  int f = blockIdx.x * 256 + threadIdx.x;
  int i = blockIdx.y;
  Xo[(size_t)i * D + f] = Xs[(size_t)idx[i] * D + f] * v[i];
}

__global__ void k_scatter_rows(const float* __restrict__ P, int D, const int* __restrict__ idx,
                               float* __restrict__ Xo) {
  int f = blockIdx.x * 256 + threadIdx.x;
  int i = blockIdx.y;
  Xo[(size_t)idx[i] * D + f] = P[(size_t)i * D + f];
}

// row softmax for D=256, f32 in -> bf16 out
__global__ __launch_bounds__(256) void k_softmax256_b(const float* __restrict__ Z,
    unsigned short* __restrict__ ZB) {
  int row = blockIdx.x, tid = threadIdx.x;
  float x = Z[(size_t)row * 256 + tid];
  float m = x;
#pragma unroll
  for (int off = 32; off; off >>= 1) m = fmaxf(m, __shfl_down(m, off));
  __shared__ float red[4];
  __shared__ float bm, bs;
  if ((tid & 63) == 0) red[tid >> 6] = m;
  __syncthreads();
  if (tid == 0) bm = fmaxf(fmaxf(red[0], red[1]), fmaxf(red[2], red[3]));
  __syncthreads();
  float e = expf(x - bm);
  float sm = wave_sum64(e);
  __syncthreads();
  if ((tid & 63) == 0) red[tid >> 6] = sm;
  __syncthreads();
  if (tid == 0) bs = red[0] + red[1] + red[2] + red[3];
  __syncthreads();
  ZB[(size_t)row * 256 + tid] = f2b(e / bs);
}

extern "C" void kernel_launch(void* const* d_in, const int* in_sizes, int n_in,
                              void* d_out, int out_size, void* d_ws, size_t ws_size,
                              hipStream_t stream) {
  const float* A    = (const float*)d_in[0];
  const float* X    = (const float*)d_in[1];
  const float* Wd0  = (const float*)d_in[2];
  const float* asd0 = (const float*)d_in[3];
  const float* add0 = (const float*)d_in[4];
  const float* bd0  = (const float*)d_in[5];
  const float* Wd1  = (const float*)d_in[6];
  const float* asd1 = (const float*)d_in[7];
  const float* add1 = (const float*)d_in[8];
  const float* bd1  = (const float*)d_in[9];
  const float* wp0  = (const float*)d_in[10];
  const float* bp0  = (const float*)d_in[11];
  const float* wp1  = (const float*)d_in[12];
  const float* bp1  = (const float*)d_in[13];
  const float* Wb   = (const float*)d_in[14];
  const float* asb  = (const float*)d_in[15];
  const float* adb  = (const float*)d_in[16];
  const float* bb   = (const float*)d_in[17];
  const float* Wu0  = (const float*)d_in[18];
  const float* asu0 = (const float*)d_in[19];
  const float* adu0 = (const float*)d_in[20];
  const float* bu0  = (const float*)d_in[21];
  const float* Wu1  = (const float*)d_in[22];
  const float* asu1 = (const float*)d_in[23];
  const float* adu1 = (const float*)d_in[24];
  const float* bu1  = (const float*)d_in[25];
  const float* Wup  = (const float*)d_in[26];
  const float* bup  = (const float*)d_in[27];
  (void)in_sizes; (void)n_in; (void)out_size; (void)ws_size;

  float* out  = (float*)d_out;
  float* Aup  = out;                    // [8192*8192]
  float* A0   = out + 67108864ULL;      // [4096*4096]
  float* A1   = A0 + 16777216ULL;       // [2048*2048]
  float* rec0 = A1 + 4194304ULL;        // [2048*2048]
  float* rec1 = rec0 + 4194304ULL;      // [4096*4096]

  // Scratch in the A_up output region (all dead before A_up syrk writes).
  float* S = Aup;
  size_t off = 0;
  auto nxt = [&](size_t n) { float* p = S + off; off += (n + 1023) & ~(size_t)1023; return p; };
  float* Xp0  = nxt(4096 * 512);
  float* X0   = nxt(4096 * 512);
  float* src0 = nxt(4096 * 4);
  float* dst0 = nxt(4096 * 4);
  float* den0 = nxt(4096 * 4);
  float* sc0  = nxt(4096);
  int*   idx0 = (int*)nxt(2048);
  float* v0   = nxt(2048);
  float* sv0  = nxt(2048);
  float* X1in = nxt(2048 * 512);
  float* Xp1  = nxt(2048 * 1024);
  float* X1   = nxt(2048 * 1024);
  float* src1 = nxt(2048 * 4);
  float* dst1 = nxt(2048 * 4);
  float* den1 = nxt(2048 * 4);
  float* sc1  = nxt(2048);
  int*   idx1 = (int*)nxt(1024);
  float* v1   = nxt(1024);
  float* A2m  = nxt(1024 * 1024);
  float* X2in = nxt(1024 * 1024);
  float* Xpb  = nxt(1024 * 1024);
  float* Xb   = nxt(1024 * 1024);
  float* srcb = nxt(1024 * 2);
  float* dstb = nxt(1024 * 2);
  float* denb = nxt(1024 * 2);
  float* Pu0  = nxt(1024 * 512);
  float* Xpu0 = nxt(2048 * 512);
  float* Xu0  = nxt(2048 * 512);
  float* su0  = nxt(2048 * 4);
  float* du0  = nxt(2048 * 4);
  float* dn0  = nxt(2048 * 4);
  float* Pu1  = nxt(2048 * 256);
  float* Xpu1 = nxt(4096 * 256);
  float* su1  = nxt(4096 * 4);
  float* du1  = nxt(4096 * 4);
  float* dn1  = nxt(4096 * 4);
  unsigned short* WupB = (unsigned short*)nxt(16777216);  // 8192*4096 bf16

  // d_ws: final-stage-live small buffers (8 MB total)
  float* W = (float*)d_ws;
  float* Xu1 = W;                                               // 4096*256 f32
  unsigned short* Xu1B = (unsigned short*)(W + 1048576);        // 4096*256 bf16
  unsigned short* Xu0B = (unsigned short*)(W + 1048576 + 524288);  // 2048*512 bf16

  // rec1 output region as late scratch (dead before rec1 syrk writes)
  float* ZL = rec1;                                             // 8192*256 f32
  unsigned short* ZB = (unsigned short*)(rec1 + 2097152);       // 8192*256 bf16
  unsigned short* Xu1T = (unsigned short*)(rec1 + 2097152 + 1048576);  // 256*4096 bf16

  // ---- A0 = A + I ----
  k_add_eye<<<65536, 256, 0, stream>>>(A, A0);

  // ---- down level 0: GAT(256 -> 4x128) ----
  k_gemm_nn<<<dim3(8, 64), 256, 0, stream>>>(X, Wd0, Xp0, 4096, 512, 256, nullptr);
  k_src_dst<<<4096, 256, 0, stream>>>(Xp0, asd0, add0, src0, dst0, 4, 128);
  k_att_denom<<<4096, 256, 0, stream>>>(A0, src0, dst0, den0, 4096, 4);
  k_gat_gemm<<<dim3(64, 8), 256, 0, stream>>>(A0, Xp0, src0, dst0, den0, bd0, X0, 4096, 4, 128);
  k_score<<<1024, 256, 0, stream>>>(X0, wp0, bp0, sc0, 512);
  k_topk_sort<<<1, 1024, 4096 * 8, stream>>>(sc0, 4096, 2048, idx0, v0);
  k_gather_rowsum<<<2048, 256, 0, stream>>>(A0, 4096, idx0, 2048, sv0);
  k_symnorm_write<<<dim3(8, 2048), 256, 0, stream>>>(A0, 4096, idx0, sv0, A1, 2048);
  k_gather_scale_rows<<<dim3(2, 2048), 256, 0, stream>>>(X0, 512, idx0, v0, X1in);

  // ---- down level 1: GAT(512 -> 4x256) ----
  k_gemm_nn<<<dim3(16, 32), 256, 0, stream>>>(X1in, Wd1, Xp1, 2048, 1024, 512, nullptr);
  k_src_dst<<<2048, 256, 0, stream>>>(Xp1, asd1, add1, src1, dst1, 4, 256);
  k_att_denom<<<2048, 256, 0, stream>>>(A1, src1, dst1, den1, 2048, 4);
  k_gat_gemm<<<dim3(32, 16), 256, 0, stream>>>(A1, Xp1, src1, dst1, den1, bd1, X1, 2048, 4, 256);
  k_score<<<512, 256, 0, stream>>>(X1, wp1, bp1, sc1, 1024);
  k_topk_sort<<<1, 1024, 2048 * 8, stream>>>(sc1, 2048, 1024, idx1, v1);
  k_gather_mat<<<dim3(4, 1024), 256, 0, stream>>>(A1, 2048, idx1, A2m, 1024);
  k_gather_scale_rows<<<dim3(4, 1024), 256, 0, stream>>>(X1, 1024, idx1, v1, X2in);

  // ---- bottom: GAT(1024 -> 2x512), A2 used as mask only ----
  k_gemm_nn<<<dim3(16, 16), 256, 0, stream>>>(X2in, Wb, Xpb, 1024, 1024, 1024, nullptr);
  k_src_dst<<<1024, 128, 0, stream>>>(Xpb, asb, adb, srcb, dstb, 2, 512);
  k_att_denom<<<1024, 256, 0, stream>>>(A2m, srcb, dstb, denb, 1024, 2);
  k_gat_gemm<<<dim3(16, 16), 256, 0, stream>>>(A2m, Xpb, srcb, dstb, denb, bb, Xb, 1024, 2, 512);

  // ---- up level 0: unpool -> GAT(1024 -> 4x128) over A1 ----
  k_gemm_nn<<<dim3(8, 16), 256, 0, stream>>>(Xb, Wu0, Pu0, 1024, 512, 1024, nullptr);
  k_fill0<<<1024, 256, 0, stream>>>(Xpu0, 2048 * 512);
  k_scatter_rows<<<dim3(2, 1024), 256, 0, stream>>>(Pu0, 512, idx1, Xpu0);
  k_src_dst<<<2048, 256, 0, stream>>>(Xpu0, asu0, adu0, su0, du0, 4, 128);
  k_att_denom<<<2048, 256, 0, stream>>>(A1, su0, du0, dn0, 2048, 4);
  k_gat_gemm<<<dim3(32, 8), 256, 0, stream>>>(A1, Xpu0, su0, du0, dn0, bu0, Xu0, 2048, 4, 128);
  k_f32_to_bf16<<<1024, 256, 0, stream>>>(Xu0, Xu0B, 2048 * 512);

  // ---- up level 1: unpool -> GAT(512 -> 4x64) over A0 ----
  k_gemm_nn<<<dim3(4, 32), 256, 0, stream>>>(Xu0, Wu1, Pu1, 2048, 256, 512, nullptr);
  k_fill0<<<1024, 256, 0, stream>>>(Xpu1, 4096 * 256);
  k_scatter_rows<<<dim3(1, 2048), 256, 0, stream>>>(Pu1, 256, idx0, Xpu1);
  k_src_dst<<<4096, 256, 0, stream>>>(Xpu1, asu1, adu1, su1, du1, 4, 64);
  k_att_denom<<<4096, 256, 0, stream>>>(A0, su1, du1, dn1, 4096, 4);
  k_gat_gemm<<<dim3(64, 4), 256, 0, stream>>>(A0, Xpu1, su1, du1, dn1, bu1, Xu1, 4096, 4, 64);
  k_f32_to_bf16<<<1024, 256, 0, stream>>>(Xu1, Xu1B, 4096 * 256);
  k_transpose_bf16<<<dim3(4, 64), 256, 0, stream>>>(Xu1, Xu1T, 4096, 256);

  // ---- upsampler first (its scratch lives in rec1 region) ----
  k_f32_to_bf16<<<2048, 256, 0, stream>>>(Wup, WupB, 8192 * 4096);
  k_gemm_mfma_bt<<<dim3(2, 64), 256, 0, stream>>>(WupB, Xu1T, bup, ZL, 8192, 256, 4096);
  k_softmax256_b<<<8192, 256, 0, stream>>>(ZL, ZB);
  k_syrk_mfma<<<dim3(64, 64), 256, 0, stream>>>(ZB, 8192, 256, Aup);

  // ---- reconstructions (now free to overwrite rec1/rec0 regions) ----
  k_syrk_mfma<<<dim3(32, 32), 256, 0, stream>>>(Xu1B, 4096, 256, rec1);
  k_syrk_mfma<<<dim3(16, 16), 256, 0, stream>>>(Xu0B, 2048, 512, rec0);
}

// Round 3
// 1573.935 us; speedup vs baseline: 1.7168x; 1.3174x over previous
//
#include <hip/hip_runtime.h>
#include <math.h>

// ---------------------------------------------------------------------------
// Graph U-Net forward on MI355X.
// Down path (feeds top-k orderings) = fp32, high-intensity 8x8-blocked GAT.
// Bottom/up GATs + projections + reconstructions + upsampler = bf16 MFMA.
// ---------------------------------------------------------------------------

typedef short bf16x8 __attribute__((ext_vector_type(8)));
typedef float f32x4 __attribute__((ext_vector_type(4)));

static __device__ __forceinline__ float wave_sum64(float v) {
#pragma unroll
  for (int off = 32; off; off >>= 1) v += __shfl_down(v, off);
  return v;
}

static __device__ __forceinline__ unsigned short f2b(float x) {
  unsigned u = __float_as_uint(x);
  unsigned r = (u + 0x7fffu + ((u >> 16) & 1u)) >> 16;
  return (unsigned short)r;
}

// A0 = A + I  (4096x4096)
__global__ void k_add_eye(const float* __restrict__ A, float* __restrict__ O) {
  size_t i = (size_t)blockIdx.x * 256 + threadIdx.x;
  size_t r = i >> 12, c = i & 4095;
  O[i] = A[i] + (r == c ? 1.f : 0.f);
}

__global__ void k_fill0(float* __restrict__ p, int n) {
  int stride = gridDim.x * 256;
  for (int i = blockIdx.x * 256 + threadIdx.x; i < n; i += stride) p[i] = 0.f;
}

__global__ void k_f32_to_bf16(const float* __restrict__ S, unsigned short* __restrict__ D,
                              int n) {
  int stride = gridDim.x * 1024;
  for (int i = (blockIdx.x * 256 + threadIdx.x) * 4; i < n; i += stride) {
    float4 v = *reinterpret_cast<const float4*>(&S[i]);
    uint2 o;
    o.x = (unsigned)f2b(v.x) | ((unsigned)f2b(v.y) << 16);
    o.y = (unsigned)f2b(v.z) | ((unsigned)f2b(v.w) << 16);
    *reinterpret_cast<uint2*>(&D[i]) = o;
  }
}

// D[c][r] = bf16(S[r*ldS + c]); S has R rows, Cc cols; D is [Cc][R].
__global__ __launch_bounds__(256) void k_transpose_bf16(const float* __restrict__ S, int ldS,
    unsigned short* __restrict__ D, int R, int Cc) {
  __shared__ unsigned short T[64][72];
  int r0 = blockIdx.y << 6, c0 = blockIdx.x << 6;
  int tid = threadIdx.x;
  int tr = tid >> 4, tc4 = (tid & 15) << 2;
#pragma unroll
  for (int q = 0; q < 4; ++q) {
    int row = tr + q * 16;
    float4 v = *reinterpret_cast<const float4*>(&S[(size_t)(r0 + row) * ldS + c0 + tc4]);
    T[tc4 + 0][row] = f2b(v.x);
    T[tc4 + 1][row] = f2b(v.y);
    T[tc4 + 2][row] = f2b(v.z);
    T[tc4 + 3][row] = f2b(v.w);
  }
  __syncthreads();
#pragma unroll
  for (int q = 0; q < 4; ++q) {
    int row = tr + q * 16;
    *reinterpret_cast<uint2*>(&D[(size_t)(c0 + row) * R + r0 + tc4]) =
        *reinterpret_cast<const uint2*>(&T[row][tc4]);
  }
}

// C[M,N] = A[M,K] @ B[K,N] (+ rowBias[m]). fp32 vector (down-path projections).
__global__ __launch_bounds__(256) void k_gemm_nn(const float* __restrict__ A,
    const float* __restrict__ B, float* __restrict__ C, int M, int N, int K,
    const float* __restrict__ rowBias) {
  __shared__ float As[16][65];
  __shared__ float Bs[16][64];
  int tid = threadIdx.x;
  int tx = tid & 15, ty = tid >> 4;
  int n0 = blockIdx.x * 64, m0 = blockIdx.y * 64;
  float acc[4][4] = {};
  for (int k0 = 0; k0 < K; k0 += 16) {
    {
      int r = tid >> 2, c = (tid & 3) * 4;
      float4 av = *reinterpret_cast<const float4*>(&A[(size_t)(m0 + r) * K + k0 + c]);
      As[c][r] = av.x; As[c + 1][r] = av.y; As[c + 2][r] = av.z; As[c + 3][r] = av.w;
      int rb = tid >> 4, cb = (tid & 15) * 4;
      *reinterpret_cast<float4*>(&Bs[rb][cb]) =
          *reinterpret_cast<const float4*>(&B[(size_t)(k0 + rb) * N + n0 + cb]);
    }
    __syncthreads();
#pragma unroll
    for (int k = 0; k < 16; ++k) {
      float a[4], b[4];
#pragma unroll
      for (int i = 0; i < 4; ++i) a[i] = As[k][ty * 4 + i];
      float4 bv = *reinterpret_cast<const float4*>(&Bs[k][tx * 4]);
      b[0] = bv.x; b[1] = bv.y; b[2] = bv.z; b[3] = bv.w;
#pragma unroll
      for (int i = 0; i < 4; ++i)
#pragma unroll
        for (int j = 0; j < 4; ++j) acc[i][j] = fmaf(a[i], b[j], acc[i][j]);
    }
    __syncthreads();
  }
#pragma unroll
  for (int i = 0; i < 4; ++i) {
    int m = m0 + ty * 4 + i;
    float rb = rowBias ? rowBias[m] : 0.f;
    float4 o;
    o.x = acc[i][0] + rb; o.y = acc[i][1] + rb; o.z = acc[i][2] + rb; o.w = acc[i][3] + rb;
    *reinterpret_cast<float4*>(&C[(size_t)m * N + n0 + tx * 4]) = o;
  }
}

// ---- fp32 GAT aggregation, 128x128 tile, 8x8/thread, split-j partials ----
// grid: (h*(F/128)+ft, N/128, JC). P[chunk][N][HF] += w-tile @ Xp-tile.
__global__ __launch_bounds__(256) void k_gat_f32(const float* __restrict__ Adj, int N,
    const float* __restrict__ Xp, int HF, int F,
    const float* __restrict__ src, const float* __restrict__ dst,
    float* __restrict__ P, int jchunk) {
  __shared__ float wK[32][132];
  __shared__ float xs[32][132];
  __shared__ float dsl[128];
  int ftiles = F >> 7;
  int h = blockIdx.x / ftiles;
  int f0 = (blockIdx.x % ftiles) << 7;
  int H = HF / F;
  int i0 = blockIdx.y << 7;
  int jb0 = blockIdx.z * jchunk;
  int tid = threadIdx.x;
  if (tid < 128) dsl[tid] = dst[(i0 + tid) * H + h];
  int tx = tid & 15, ty = tid >> 4;
  int sj4 = (tid & 7) << 2;  // j offset 0..28
  int si = tid >> 3;         // 0..31 (+q*32)
  int xf4 = (tid & 31) << 2; // f 0..124
  int xj = tid >> 5;         // 0..7 (+q*8)
  float acc[8][8] = {};
  for (int jb = jb0; jb < jb0 + jchunk; jb += 32) {
    __syncthreads();
    float s4[4];
#pragma unroll
    for (int e = 0; e < 4; ++e) s4[e] = src[(jb + sj4 + e) * H + h];
#pragma unroll
    for (int q = 0; q < 4; ++q) {
      int i = si + q * 32;
      int gi = i0 + i;
      float4 av = *reinterpret_cast<const float4*>(&Adj[(size_t)gi * N + jb + sj4]);
      float di = dsl[i];
      float vv[4] = {av.x, av.y, av.z, av.w};
#pragma unroll
      for (int e = 0; e < 4; ++e) {
        float w = 0.f;
        if (vv[e] != 0.f || (jb + sj4 + e) == gi) {
          float t = di + s4[e];
          t = t >= 0.f ? t : 0.2f * t;
          w = expf(t);
        }
        wK[sj4 + e][i] = w;
      }
    }
#pragma unroll
    for (int q = 0; q < 4; ++q) {
      int j = xj + q * 8;
      *reinterpret_cast<float4*>(&xs[j][xf4]) =
          *reinterpret_cast<const float4*>(&Xp[(size_t)(jb + j) * HF + h * F + f0 + xf4]);
    }
    __syncthreads();
#pragma unroll 2
    for (int k = 0; k < 32; ++k) {
      float a[8], b[8];
      *reinterpret_cast<float4*>(&a[0]) = *reinterpret_cast<const float4*>(&wK[k][ty * 8]);
      *reinterpret_cast<float4*>(&a[4]) = *reinterpret_cast<const float4*>(&wK[k][ty * 8 + 4]);
      *reinterpret_cast<float4*>(&b[0]) = *reinterpret_cast<const float4*>(&xs[k][tx * 8]);
      *reinterpret_cast<float4*>(&b[4]) = *reinterpret_cast<const float4*>(&xs[k][tx * 8 + 4]);
#pragma unroll
      for (int i = 0; i < 8; ++i)
#pragma unroll
        for (int j = 0; j < 8; ++j) acc[i][j] = fmaf(a[i], b[j], acc[i][j]);
    }
  }
  float* Pc = P + (size_t)blockIdx.z * N * HF;
#pragma unroll
  for (int i = 0; i < 8; ++i) {
    size_t row = (size_t)(i0 + ty * 8 + i) * HF + h * F + f0 + tx * 8;
    *reinterpret_cast<float4*>(&Pc[row]) = *reinterpret_cast<const float4*>(&acc[i][0]);
    *reinterpret_cast<float4*>(&Pc[row + 4]) = *reinterpret_cast<const float4*>(&acc[i][4]);
  }
}

// ---- bf16 MFMA GAT aggregation (non-ordering layers): 256x64 tile ----
// grid: (H*(F/64), N/256, JC). XpT is [H][F][N] bf16. P partials as above.
__global__ __launch_bounds__(256) void k_gat_mfma(const float* __restrict__ Adj, int N,
    const unsigned short* __restrict__ XpT,
    const float* __restrict__ src, const float* __restrict__ dst,
    float* __restrict__ P, int HF, int F, int jchunk) {
  __shared__ __align__(16) unsigned short wL[256][40];
  __shared__ __align__(16) unsigned short xT[64][40];
  __shared__ float dsl[256];
  int ftiles = F >> 6;
  int h = blockIdx.x / ftiles;
  int f0 = (blockIdx.x % ftiles) << 6;
  int H = HF / F;
  int i0 = blockIdx.y << 8;
  int jb0 = blockIdx.z * jchunk;
  int tid = threadIdx.x;
  int lane = tid & 63, w = tid >> 6;
  int lr = lane & 15, kb = lane >> 4;
  dsl[tid] = dst[(i0 + tid) * H + h];
  int sj4 = (tid & 7) << 2;
  int si = tid >> 3;        // 0..31 (+q*32 -> 0..255)
  int xf = tid >> 2;        // 0..63
  int xj8 = (tid & 3) << 3; // 0,8,16,24
  const unsigned short* xg = XpT + ((size_t)h * F + f0 + xf) * N;
  f32x4 acc[4][4] = {};
  for (int jb = jb0; jb < jb0 + jchunk; jb += 32) {
    __syncthreads();
    float s4[4];
#pragma unroll
    for (int e = 0; e < 4; ++e) s4[e] = src[(jb + sj4 + e) * H + h];
#pragma unroll
    for (int q = 0; q < 8; ++q) {
      int i = si + q * 32;
      int gi = i0 + i;
      float4 av = *reinterpret_cast<const float4*>(&Adj[(size_t)gi * N + jb + sj4]);
      float di = dsl[i];
      float vv[4] = {av.x, av.y, av.z, av.w};
      unsigned short wb[4];
#pragma unroll
      for (int e = 0; e < 4; ++e) {
        float wv = 0.f;
        if (vv[e] != 0.f || (jb + sj4 + e) == gi) {
          float t = di + s4[e];
          t = t >= 0.f ? t : 0.2f * t;
          wv = expf(t);
        }
        wb[e] = f2b(wv);
      }
      *reinterpret_cast<uint2*>(&wL[i][sj4]) = *reinterpret_cast<const uint2*>(wb);
    }
    *reinterpret_cast<uint4*>(&xT[xf][xj8]) = *reinterpret_cast<const uint4*>(&xg[jb + xj8]);
    __syncthreads();
    bf16x8 a[4], b[4];
#pragma unroll
    for (int m = 0; m < 4; ++m)
      a[m] = *reinterpret_cast<const bf16x8*>(&wL[w * 64 + m * 16 + lr][kb * 8]);
#pragma unroll
    for (int n = 0; n < 4; ++n)
      b[n] = *reinterpret_cast<const bf16x8*>(&xT[n * 16 + lr][kb * 8]);
#pragma unroll
    for (int m = 0; m < 4; ++m)
#pragma unroll
      for (int n = 0; n < 4; ++n)
        acc[m][n] = __builtin_amdgcn_mfma_f32_16x16x32_bf16(a[m], b[n], acc[m][n], 0, 0, 0);
  }
  float* Pc = P + (size_t)blockIdx.z * N * HF;
  int orow = i0 + w * 64 + (lane >> 4) * 4;
  int ocol = h * F + f0 + (lane & 15);
#pragma unroll
  for (int m = 0; m < 4; ++m)
#pragma unroll
    for (int n = 0; n < 4; ++n)
#pragma unroll
      for (int r = 0; r < 4; ++r)
        Pc[(size_t)(orow + m * 16 + r) * HF + ocol + n * 16] = acc[m][n][r];
}

// Out = relu((sum_c P[c]) / den + bias)
__global__ void k_gat_reduce(const float* __restrict__ P, int nch, size_t chstride,
    const float* __restrict__ den, const float* __restrict__ bias, float* __restrict__ Out,
    int HF, int F, int n_total) {
  int e = (blockIdx.x * 256 + threadIdx.x) * 4;
  if (e >= n_total) return;
  float4 s = *reinterpret_cast<const float4*>(&P[e]);
  for (int c = 1; c < nch; ++c) {
    float4 v = *reinterpret_cast<const float4*>(&P[c * chstride + e]);
    s.x += v.x; s.y += v.y; s.z += v.z; s.w += v.w;
  }
  int i = e / HF;
  int hf = e - i * HF;
  int h = hf / F;
  float inv = 1.f / den[i * (HF / F) + h];
  float4 bz = *reinterpret_cast<const float4*>(&bias[hf]);
  float4 o;
  o.x = fmaxf(fmaf(s.x, inv, bz.x), 0.f);
  o.y = fmaxf(fmaf(s.y, inv, bz.y), 0.f);
  o.z = fmaxf(fmaf(s.z, inv, bz.z), 0.f);
  o.w = fmaxf(fmaf(s.w, inv, bz.w), 0.f);
  *reinterpret_cast<float4*>(&Out[e]) = o;
}

// ---- bf16 MFMA: C = relu(G @ G^T), 128x128 block ----
__global__ __launch_bounds__(256) void k_syrk_mfma(const unsigned short* __restrict__ G,
    int M, int Kd, float* __restrict__ C) {
  __shared__ __align__(16) unsigned short Ai[128 * 40];
  __shared__ __align__(16) unsigned short Bj[128 * 40];
  int tid = threadIdx.x;
  int i0 = blockIdx.y << 7, j0 = blockIdx.x << 7;
  int srow = tid >> 1, scol = (tid & 1) << 3;
  int lane = tid & 63, w = tid >> 6;
  int wr = (w >> 1) << 6, wc = (w & 1) << 6;
  int lr = lane & 15, kb = lane >> 4;
  f32x4 acc[4][4] = {};
  const unsigned short* gA = G + (size_t)i0 * Kd;
  const unsigned short* gB = G + (size_t)j0 * Kd;
  for (int k0 = 0; k0 < Kd; k0 += 32) {
    __syncthreads();
#pragma unroll
    for (int kk = 0; kk < 32; kk += 16) {
      *reinterpret_cast<uint4*>(&Ai[srow * 40 + scol + kk]) =
          *reinterpret_cast<const uint4*>(&gA[(size_t)srow * Kd + k0 + scol + kk]);
      *reinterpret_cast<uint4*>(&Bj[srow * 40 + scol + kk]) =
          *reinterpret_cast<const uint4*>(&gB[(size_t)srow * Kd + k0 + scol + kk]);
    }
    __syncthreads();
    bf16x8 a[4], b[4];
#pragma unroll
    for (int m = 0; m < 4; ++m)
      a[m] = *reinterpret_cast<const bf16x8*>(&Ai[(wr + m * 16 + lr) * 40 + kb * 8]);
#pragma unroll
    for (int n = 0; n < 4; ++n)
      b[n] = *reinterpret_cast<const bf16x8*>(&Bj[(wc + n * 16 + lr) * 40 + kb * 8]);
#pragma unroll
    for (int m = 0; m < 4; ++m)
#pragma unroll
      for (int n = 0; n < 4; ++n)
        acc[m][n] = __builtin_amdgcn_mfma_f32_16x16x32_bf16(a[m], b[n], acc[m][n], 0, 0, 0);
  }
  int orow = i0 + wr + (lane >> 4) * 4;
  int ocol = j0 + wc + (lane & 15);
#pragma unroll
  for (int m = 0; m < 4; ++m)
#pragma unroll
    for (int n = 0; n < 4; ++n)
#pragma unroll
      for (int r = 0; r < 4; ++r)
        C[(size_t)(orow + m * 16 + r) * M + ocol + n * 16] = fmaxf(acc[m][n][r], 0.f);
}

// C[M,N] = A[M,K] @ BT[N,K]^T (+ bias[m] if non-null). bf16 in, f32 out.
__global__ __launch_bounds__(256) void k_gemm_mfma_bt(const unsigned short* __restrict__ Amat,
    const unsigned short* __restrict__ BT, const float* __restrict__ bias,
    float* __restrict__ C, int M, int N, int Kd) {
  __shared__ __align__(16) unsigned short Ai[128 * 40];
  __shared__ __align__(16) unsigned short Bj[128 * 40];
  int tid = threadIdx.x;
  int m0 = blockIdx.y << 7, n0 = blockIdx.x << 7;
  int srow = tid >> 1, scol = (tid & 1) << 3;
  int lane = tid & 63, w = tid >> 6;
  int wr = (w >> 1) << 6, wc = (w & 1) << 6;
  int lr = lane & 15, kb = lane >> 4;
  f32x4 acc[4][4] = {};
  const unsigned short* gA = Amat + (size_t)m0 * Kd;
  const unsigned short* gB = BT + (size_t)n0 * Kd;
  for (int k0 = 0; k0 < Kd; k0 += 32) {
    __syncthreads();
#pragma unroll
    for (int kk = 0; kk < 32; kk += 16) {
      *reinterpret_cast<uint4*>(&Ai[srow * 40 + scol + kk]) =
          *reinterpret_cast<const uint4*>(&gA[(size_t)srow * Kd + k0 + scol + kk]);
      *reinterpret_cast<uint4*>(&Bj[srow * 40 + scol + kk]) =
          *reinterpret_cast<const uint4*>(&gB[(size_t)srow * Kd + k0 + scol + kk]);
    }
    __syncthreads();
    bf16x8 a[4], b[4];
#pragma unroll
    for (int m = 0; m < 4; ++m)
      a[m] = *reinterpret_cast<const bf16x8*>(&Ai[(wr + m * 16 + lr) * 40 + kb * 8]);
#pragma unroll
    for (int n = 0; n < 4; ++n)
      b[n] = *reinterpret_cast<const bf16x8*>(&Bj[(wc + n * 16 + lr) * 40 + kb * 8]);
#pragma unroll
    for (int m = 0; m < 4; ++m)
#pragma unroll
      for (int n = 0; n < 4; ++n)
        acc[m][n] = __builtin_amdgcn_mfma_f32_16x16x32_bf16(a[m], b[n], acc[m][n], 0, 0, 0);
  }
  int orow = m0 + wr + (lane >> 4) * 4;
  int ocol = n0 + wc + (lane & 15);
#pragma unroll
  for (int m = 0; m < 4; ++m)
#pragma unroll
    for (int n = 0; n < 4; ++n)
#pragma unroll
      for (int r = 0; r < 4; ++r) {
        float rb = bias ? bias[orow + m * 16 + r] : 0.f;
        C[(size_t)(orow + m * 16 + r) * N + ocol + n * 16] = acc[m][n][r] + rb;
      }
}

// src[n,h] = sum_f Xp[n,h,f]*a_src[h,f]; dst likewise. block = 64*H threads.
__global__ void k_src_dst(const float* __restrict__ Xp, const float* __restrict__ a_src,
    const float* __restrict__ a_dst, float* __restrict__ src, float* __restrict__ dst,
    int H, int F) {
  int n = blockIdx.x;
  int h = threadIdx.x >> 6, lane = threadIdx.x & 63;
  const float* x = Xp + ((size_t)n * H + h) * F;
  const float* as = a_src + h * F;
  const float* ad = a_dst + h * F;
  float ps = 0.f, pd = 0.f;
  for (int f = lane; f < F; f += 64) {
    float xv = x[f];
    ps = fmaf(xv, as[f], ps);
    pd = fmaf(xv, ad[f], pd);
  }
  ps = wave_sum64(ps);
  pd = wave_sum64(pd);
  if (lane == 0) { src[n * H + h] = ps; dst[n * H + h] = pd; }
}

// denom[i,h] = sum_j valid(i,j) * exp(lrelu(dst[i,h]+src[j,h]))
__global__ __launch_bounds__(256) void k_att_denom(const float* __restrict__ Adj,
    const float* __restrict__ src, const float* __restrict__ dst, float* __restrict__ denom,
    int N, int H) {
  int i = blockIdx.x, tid = threadIdx.x;
  float di[4];
#pragma unroll
  for (int h = 0; h < 4; ++h) di[h] = (h < H) ? dst[i * H + h] : 0.f;
  float acc[4] = {0.f, 0.f, 0.f, 0.f};
  const float* row = Adj + (size_t)i * N;
  for (int j = tid; j < N; j += 256) {
    float av = row[j];
    if (av != 0.f || j == i) {
#pragma unroll
      for (int h = 0; h < 4; ++h) {
        if (h < H) {
          float t = di[h] + src[j * H + h];
          t = t >= 0.f ? t : 0.2f * t;
          acc[h] += expf(t);
        }
      }
    }
  }
  __shared__ float red[4][4];
#pragma unroll
  for (int h = 0; h < 4; ++h) acc[h] = wave_sum64(acc[h]);
  if ((tid & 63) == 0) {
#pragma unroll
    for (int h = 0; h < 4; ++h) red[tid >> 6][h] = acc[h];
  }
  __syncthreads();
  if (tid < H) denom[i * H + tid] = red[0][tid] + red[1][tid] + red[2][tid] + red[3][tid];
}

// s[row] = sigmoid(dot(X[row,:], w) + b)
__global__ __launch_bounds__(256) void k_score(const float* __restrict__ Xf,
    const float* __restrict__ wv, const float* __restrict__ bsc, float* __restrict__ s, int D) {
  int row = blockIdx.x * 4 + (threadIdx.x >> 6);
  int lane = threadIdx.x & 63;
  const float* x = Xf + (size_t)row * D;
  float p = 0.f;
  for (int f = lane; f < D; f += 64) p = fmaf(x[f], wv[f], p);
  p = wave_sum64(p);
  if (lane == 0) s[row] = 1.f / (1.f + expf(-(p + bsc[0])));
}

// single-block bitonic sort: key = (value desc, index asc)
__global__ __launch_bounds__(1024) void k_topk_sort(const float* __restrict__ s, int n, int k,
    int* __restrict__ idx, float* __restrict__ vals) {
  extern __shared__ unsigned long long keys[];
  int tid = threadIdx.x;
  for (int i = tid; i < n; i += 1024) {
    unsigned u = __float_as_uint(s[i]);
    unsigned ord = (u & 0x80000000u) ? ~u : (u | 0x80000000u);
    keys[i] = ((unsigned long long)(~ord) << 32) | (unsigned)i;
  }
  __syncthreads();
  for (int size = 2; size <= n; size <<= 1) {
    for (int stride = size >> 1; stride > 0; stride >>= 1) {
      for (int i = tid; i < n; i += 1024) {
        int p = i ^ stride;
        if (p > i) {
          bool up = ((i & size) == 0);
          unsigned long long a = keys[i], b = keys[p];
          if (up ? (a > b) : (a < b)) { keys[i] = b; keys[p] = a; }
        }
      }
      __syncthreads();
    }
  }
  for (int i = tid; i < k; i += 1024) {
    int id = (int)(keys[i] & 0xffffffffu);
    idx[i] = id;
    vals[i] = s[id];
  }
}

__global__ __launch_bounds__(256) void k_gather_rowsum(const float* __restrict__ Asrc, int lda,
    const int* __restrict__ idx, int k, float* __restrict__ sv) {
  int i = blockIdx.x;
  const float* row = Asrc + (size_t)idx[i] * lda;
  float p = 0.f;
  for (int j = threadIdx.x; j < k; j += 256) p += row[idx[j]];
  p = wave_sum64(p);
  __shared__ float red[4];
  if ((threadIdx.x & 63) == 0) red[threadIdx.x >> 6] = p;
  __syncthreads();
  if (threadIdx.x == 0) sv[i] = 1.f / sqrtf(red[0] + red[1] + red[2] + red[3] + 1e-5f);
}

__global__ void k_symnorm_write(const float* __restrict__ Asrc, int lda,
    const int* __restrict__ idx, const float* __restrict__ sv, float* __restrict__ B, int k) {
  int j = blockIdx.x * 256 + threadIdx.x;
  int i = blockIdx.y;
  B[(size_t)i * k + j] = Asrc[(size_t)idx[i] * lda + idx[j]] * sv[i] * sv[j];
}

__global__ void k_gather_mat(const float* __restrict__ Asrc, int lda,
    const int* __restrict__ idx, float* __restrict__ B, int k) {
  int j = blockIdx.x * 256 + threadIdx.x;
  int i = blockIdx.y;
  B[(size_t)i * k + j] = Asrc[(size_t)idx[i] * lda + idx[j]];
}

__global__ void k_gather_scale_rows(const float* __restrict__ Xs, int D,
    const int* __restrict__ idx, const float* __restrict__ v, float* __restrict__ Xo) {
  int f = blockIdx.x * 256 + threadIdx.x;
  int i = blockIdx.y;
  Xo[(size_t)i * D + f] = Xs[(size_t)idx[i] * D + f] * v[i];
}

__global__ void k_scatter_rows(const float* __restrict__ P, int D, const int* __restrict__ idx,
                               float* __restrict__ Xo) {
  int f = blockIdx.x * 256 + threadIdx.x;
  int i = blockIdx.y;
  Xo[(size_t)idx[i] * D + f] = P[(size_t)i * D + f];
}

// row softmax for D=256, f32 in -> bf16 out
__global__ __launch_bounds__(256) void k_softmax256_b(const float* __restrict__ Z,
    unsigned short* __restrict__ ZB) {
  int row = blockIdx.x, tid = threadIdx.x;
  float x = Z[(size_t)row * 256 + tid];
  float m = x;
#pragma unroll
  for (int off = 32; off; off >>= 1) m = fmaxf(m, __shfl_down(m, off));
  __shared__ float red[4];
  __shared__ float bm, bs;
  if ((tid & 63) == 0) red[tid >> 6] = m;
  __syncthreads();
  if (tid == 0) bm = fmaxf(fmaxf(red[0], red[1]), fmaxf(red[2], red[3]));
  __syncthreads();
  float e = expf(x - bm);
  float sm = wave_sum64(e);
  __syncthreads();
  if ((tid & 63) == 0) red[tid >> 6] = sm;
  __syncthreads();
  if (tid == 0) bs = red[0] + red[1] + red[2] + red[3];
  __syncthreads();
  ZB[(size_t)row * 256 + tid] = f2b(e / bs);
}

extern "C" void kernel_launch(void* const* d_in, const int* in_sizes, int n_in,
                              void* d_out, int out_size, void* d_ws, size_t ws_size,
                              hipStream_t stream) {
  const float* A    = (const float*)d_in[0];
  const float* X    = (const float*)d_in[1];
  const float* Wd0  = (const float*)d_in[2];
  const float* asd0 = (const float*)d_in[3];
  const float* add0 = (const float*)d_in[4];
  const float* bd0  = (const float*)d_in[5];
  const float* Wd1  = (const float*)d_in[6];
  const float* asd1 = (const float*)d_in[7];
  const float* add1 = (const float*)d_in[8];
  const float* bd1  = (const float*)d_in[9];
  const float* wp0  = (const float*)d_in[10];
  const float* bp0  = (const float*)d_in[11];
  const float* wp1  = (const float*)d_in[12];
  const float* bp1  = (const float*)d_in[13];
  const float* Wb   = (const float*)d_in[14];
  const float* asb  = (const float*)d_in[15];
  const float* adb  = (const float*)d_in[16];
  const float* bb   = (const float*)d_in[17];
  const float* Wu0  = (const float*)d_in[18];
  const float* asu0 = (const float*)d_in[19];
  const float* adu0 = (const float*)d_in[20];
  const float* bu0  = (const float*)d_in[21];
  const float* Wu1  = (const float*)d_in[22];
  const float* asu1 = (const float*)d_in[23];
  const float* adu1 = (const float*)d_in[24];
  const float* bu1  = (const float*)d_in[25];
  const float* Wup  = (const float*)d_in[26];
  const float* bup  = (const float*)d_in[27];
  (void)in_sizes; (void)n_in; (void)out_size; (void)ws_size;

  float* out  = (float*)d_out;
  float* Aup  = out;                    // [8192*8192]
  float* A0   = out + 67108864ULL;      // [4096*4096]
  float* A1   = A0 + 16777216ULL;       // [2048*2048]
  float* rec0 = A1 + 4194304ULL;        // [2048*2048]
  float* rec1 = rec0 + 4194304ULL;      // [4096*4096]

  // Scratch in the A_up output region (dead before A_up syrk writes).
  float* S = Aup;
  size_t off = 0;
  auto nxt = [&](size_t n) { float* p = S + off; off += (n + 1023) & ~(size_t)1023; return p; };
  float* Xp0  = nxt(4096 * 512);
  float* X0   = nxt(4096 * 512);
  float* src0 = nxt(4096 * 4);
  float* dst0 = nxt(4096 * 4);
  float* den0 = nxt(4096 * 4);
  float* sc0  = nxt(4096);
  int*   idx0 = (int*)nxt(2048);
  float* v0   = nxt(2048);
  float* sv0  = nxt(2048);
  float* X1in = nxt(2048 * 512);
  float* Xp1  = nxt(2048 * 1024);
  float* X1   = nxt(2048 * 1024);
  float* src1 = nxt(2048 * 4);
  float* dst1 = nxt(2048 * 4);
  float* den1 = nxt(2048 * 4);
  float* sc1  = nxt(2048);
  int*   idx1 = (int*)nxt(1024);
  float* v1   = nxt(1024);
  float* A2m  = nxt(1024 * 1024);
  float* X2in = nxt(1024 * 1024);
  float* Xpb  = nxt(1024 * 1024);
  float* Xb   = nxt(1024 * 1024);
  float* srcb = nxt(1024 * 2);
  float* dstb = nxt(1024 * 2);
  float* denb = nxt(1024 * 2);
  float* Pu0  = nxt(1024 * 512);
  float* Xpu0 = nxt(2048 * 512);
  float* Xu0  = nxt(2048 * 512);
  float* su0  = nxt(2048 * 4);
  float* du0  = nxt(2048 * 4);
  float* dn0  = nxt(2048 * 4);
  float* Pu1  = nxt(2048 * 256);
  float* Xpu1 = nxt(4096 * 256);
  float* su1  = nxt(4096 * 4);
  float* du1  = nxt(4096 * 4);
  float* dn1  = nxt(4096 * 4);
  unsigned short* WupB = (unsigned short*)nxt(16777216);   // 8192*4096 bf16
  float* P = nxt(4 * 4096 * 512);                          // split-j partials (33.5 MB)
  unsigned short* XpT  = (unsigned short*)nxt(524288);     // [H][F][N] bf16, <=2 MB
  unsigned short* X2inB = (unsigned short*)nxt(524288);    // 1024*1024 bf16
  unsigned short* XbB   = (unsigned short*)nxt(524288);    // 1024*1024 bf16
  unsigned short* WbT   = (unsigned short*)nxt(524288);    // 1024*1024 bf16
  unsigned short* Wu0T  = (unsigned short*)nxt(262144);    // 512*1024 bf16
  unsigned short* Wu1T  = (unsigned short*)nxt(65536);     // 256*512 bf16

  // d_ws: final-stage-live buffers
  float* W = (float*)d_ws;
  float* Xu1 = W;                                               // 4096*256 f32
  unsigned short* Xu1B = (unsigned short*)(W + 1048576);        // 4096*256 bf16
  unsigned short* Xu0B = (unsigned short*)(W + 1048576 + 524288);  // 2048*512 bf16

  // rec1 output region as late scratch (dead before rec1 syrk writes)
  float* ZL = rec1;                                             // 8192*256 f32
  unsigned short* ZB = (unsigned short*)(rec1 + 2097152);       // 8192*256 bf16
  unsigned short* Xu1T = (unsigned short*)(rec1 + 2097152 + 1048576);  // 256*4096 bf16

  // ---- A0 = A + I ----
  k_add_eye<<<65536, 256, 0, stream>>>(A, A0);

  // ---- down level 0: GAT(256 -> 4x128), fp32 ----
  k_gemm_nn<<<dim3(8, 64), 256, 0, stream>>>(X, Wd0, Xp0, 4096, 512, 256, nullptr);
  k_src_dst<<<4096, 256, 0, stream>>>(Xp0, asd0, add0, src0, dst0, 4, 128);
  k_att_denom<<<4096, 256, 0, stream>>>(A0, src0, dst0, den0, 4096, 4);
  k_gat_f32<<<dim3(4, 32, 4), 256, 0, stream>>>(A0, 4096, Xp0, 512, 128, src0, dst0, P, 1024);
  k_gat_reduce<<<2048, 256, 0, stream>>>(P, 4, (size_t)4096 * 512, den0, bd0, X0, 512, 128,
                                         4096 * 512);
  k_score<<<1024, 256, 0, stream>>>(X0, wp0, bp0, sc0, 512);
  k_topk_sort<<<1, 1024, 4096 * 8, stream>>>(sc0, 4096, 2048, idx0, v0);
  k_gather_rowsum<<<2048, 256, 0, stream>>>(A0, 4096, idx0, 2048, sv0);
  k_symnorm_write<<<dim3(8, 2048), 256, 0, stream>>>(A0, 4096, idx0, sv0, A1, 2048);
  k_gather_scale_rows<<<dim3(2, 2048), 256, 0, stream>>>(X0, 512, idx0, v0, X1in);

  // ---- down level 1: GAT(512 -> 4x256), fp32 ----
  k_gemm_nn<<<dim3(16, 32), 256, 0, stream>>>(X1in, Wd1, Xp1, 2048, 1024, 512, nullptr);
  k_src_dst<<<2048, 256, 0, stream>>>(Xp1, asd1, add1, src1, dst1, 4, 256);
  k_att_denom<<<2048, 256, 0, stream>>>(A1, src1, dst1, den1, 2048, 4);
  k_gat_f32<<<dim3(8, 16, 4), 256, 0, stream>>>(A1, 2048, Xp1, 1024, 256, src1, dst1, P, 512);
  k_gat_reduce<<<2048, 256, 0, stream>>>(P, 4, (size_t)2048 * 1024, den1, bd1, X1, 1024, 256,
                                         2048 * 1024);
  k_score<<<512, 256, 0, stream>>>(X1, wp1, bp1, sc1, 1024);
  k_topk_sort<<<1, 1024, 2048 * 8, stream>>>(sc1, 2048, 1024, idx1, v1);
  k_gather_mat<<<dim3(4, 1024), 256, 0, stream>>>(A1, 2048, idx1, A2m, 1024);
  k_gather_scale_rows<<<dim3(4, 1024), 256, 0, stream>>>(X1, 1024, idx1, v1, X2in);

  // ---- bottom: GAT(1024 -> 2x512), bf16 MFMA ----
  k_f32_to_bf16<<<1024, 256, 0, stream>>>(X2in, X2inB, 1024 * 1024);
  k_transpose_bf16<<<dim3(16, 16), 256, 0, stream>>>(Wb, 1024, WbT, 1024, 1024);
  k_gemm_mfma_bt<<<dim3(8, 8), 256, 0, stream>>>(X2inB, WbT, nullptr, Xpb, 1024, 1024, 1024);
  k_src_dst<<<1024, 128, 0, stream>>>(Xpb, asb, adb, srcb, dstb, 2, 512);
  k_att_denom<<<1024, 256, 0, stream>>>(A2m, srcb, dstb, denb, 1024, 2);
  for (int h = 0; h < 2; ++h)
    k_transpose_bf16<<<dim3(8, 16), 256, 0, stream>>>(Xpb + h * 512, 1024,
                                                      XpT + (size_t)h * 512 * 1024, 1024, 512);
  k_gat_mfma<<<dim3(16, 4, 4), 256, 0, stream>>>(A2m, 1024, XpT, srcb, dstb, P, 1024, 512, 256);
  k_gat_reduce<<<1024, 256, 0, stream>>>(P, 4, (size_t)1024 * 1024, denb, bb, Xb, 1024, 512,
                                         1024 * 1024);

  // ---- up level 0: unpool -> GAT(1024 -> 4x128) over A1, bf16 MFMA ----
  k_f32_to_bf16<<<1024, 256, 0, stream>>>(Xb, XbB, 1024 * 1024);
  k_transpose_bf16<<<dim3(8, 16), 256, 0, stream>>>(Wu0, 512, Wu0T, 1024, 512);
  k_gemm_mfma_bt<<<dim3(4, 8), 256, 0, stream>>>(XbB, Wu0T, nullptr, Pu0, 1024, 512, 1024);
  k_fill0<<<1024, 256, 0, stream>>>(Xpu0, 2048 * 512);
  k_scatter_rows<<<dim3(2, 1024), 256, 0, stream>>>(Pu0, 512, idx1, Xpu0);
  k_src_dst<<<2048, 256, 0, stream>>>(Xpu0, asu0, adu0, su0, du0, 4, 128);
  k_att_denom<<<2048, 256, 0, stream>>>(A1, su0, du0, dn0, 2048, 4);
  for (int h = 0; h < 4; ++h)
    k_transpose_bf16<<<dim3(2, 32), 256, 0, stream>>>(Xpu0 + h * 128, 512,
                                                      XpT + (size_t)h * 128 * 2048, 2048, 128);
  k_gat_mfma<<<dim3(8, 8, 4), 256, 0, stream>>>(A1, 2048, XpT, su0, du0, P, 512, 128, 512);
  k_gat_reduce<<<1024, 256, 0, stream>>>(P, 4, (size_t)2048 * 512, dn0, bu0, Xu0, 512, 128,
                                         2048 * 512);
  k_f32_to_bf16<<<1024, 256, 0, stream>>>(Xu0, Xu0B, 2048 * 512);

  // ---- up level 1: unpool -> GAT(512 -> 4x64) over A0, bf16 MFMA ----
  k_transpose_bf16<<<dim3(4, 8), 256, 0, stream>>>(Wu1, 256, Wu1T, 512, 256);
  k_gemm_mfma_bt<<<dim3(2, 16), 256, 0, stream>>>(Xu0B, Wu1T, nullptr, Pu1, 2048, 256, 512);
  k_fill0<<<1024, 256, 0, stream>>>(Xpu1, 4096 * 256);
  k_scatter_rows<<<dim3(1, 2048), 256, 0, stream>>>(Pu1, 256, idx0, Xpu1);
  k_src_dst<<<4096, 256, 0, stream>>>(Xpu1, asu1, adu1, su1, du1, 4, 64);
  k_att_denom<<<4096, 256, 0, stream>>>(A0, su1, du1, dn1, 4096, 4);
  for (int h = 0; h < 4; ++h)
    k_transpose_bf16<<<dim3(1, 64), 256, 0, stream>>>(Xpu1 + h * 64, 256,
                                                      XpT + (size_t)h * 64 * 4096, 4096, 64);
  k_gat_mfma<<<dim3(4, 16, 4), 256, 0, stream>>>(A0, 4096, XpT, su1, du1, P, 256, 64, 1024);
  k_gat_reduce<<<1024, 256, 0, stream>>>(P, 4, (size_t)4096 * 256, dn1, bu1, Xu1, 256, 64,
                                         4096 * 256);
  k_f32_to_bf16<<<1024, 256, 0, stream>>>(Xu1, Xu1B, 4096 * 256);
  k_transpose_bf16<<<dim3(4, 64), 256, 0, stream>>>(Xu1, 256, Xu1T, 4096, 256);

  // ---- upsampler (scratch in rec1 region) ----
  k_f32_to_bf16<<<2048, 256, 0, stream>>>(Wup, WupB, 8192 * 4096);
  k_gemm_mfma_bt<<<dim3(2, 64), 256, 0, stream>>>(WupB, Xu1T, bup, ZL, 8192, 256, 4096);
  k_softmax256_b<<<8192, 256, 0, stream>>>(ZL, ZB);
  k_syrk_mfma<<<dim3(64, 64), 256, 0, stream>>>(ZB, 8192, 256, Aup);

  // ---- reconstructions ----
  k_syrk_mfma<<<dim3(32, 32), 256, 0, stream>>>(Xu1B, 4096, 256, rec1);
  k_syrk_mfma<<<dim3(16, 16), 256, 0, stream>>>(Xu0B, 2048, 512, rec0);
}

// Round 4
// 1351.245 us; speedup vs baseline: 1.9997x; 1.1648x over previous
//
#include <hip/hip_runtime.h>
#include <math.h>

// ---------------------------------------------------------------------------
// Graph U-Net forward on MI355X.
// Down path (feeds top-k orderings) = fp32, pipelined 8x8-blocked GAT.
// Bottom/up GATs + projections + reconstructions + upsampler = bf16 MFMA.
// ---------------------------------------------------------------------------

typedef short bf16x8 __attribute__((ext_vector_type(8)));
typedef float f32x4 __attribute__((ext_vector_type(4)));

static __device__ __forceinline__ float wave_sum64(float v) {
#pragma unroll
  for (int off = 32; off; off >>= 1) v += __shfl_down(v, off);
  return v;
}

static __device__ __forceinline__ unsigned short f2b(float x) {
  unsigned u = __float_as_uint(x);
  unsigned r = (u + 0x7fffu + ((u >> 16) & 1u)) >> 16;
  return (unsigned short)r;
}

// A0 = A + I  (4096x4096), float4
__global__ void k_add_eye(const float* __restrict__ A, float* __restrict__ O) {
  size_t i = ((size_t)blockIdx.x * 256 + threadIdx.x) * 4;
  size_t r = i >> 12, c = i & 4095;
  float4 v = *reinterpret_cast<const float4*>(&A[i]);
  if (r >= c && r < c + 4) ((float*)&v)[r - c] += 1.f;
  *reinterpret_cast<float4*>(&O[i]) = v;
}

__global__ void k_fill0(float* __restrict__ p, int n) {
  int stride = gridDim.x * 256;
  for (int i = blockIdx.x * 256 + threadIdx.x; i < n; i += stride) p[i] = 0.f;
}

__global__ void k_f32_to_bf16(const float* __restrict__ S, unsigned short* __restrict__ D,
                              int n) {
  int stride = gridDim.x * 1024;
  for (int i = (blockIdx.x * 256 + threadIdx.x) * 4; i < n; i += stride) {
    float4 v = *reinterpret_cast<const float4*>(&S[i]);
    uint2 o;
    o.x = (unsigned)f2b(v.x) | ((unsigned)f2b(v.y) << 16);
    o.y = (unsigned)f2b(v.z) | ((unsigned)f2b(v.w) << 16);
    *reinterpret_cast<uint2*>(&D[i]) = o;
  }
}

// D[c][r] = bf16(S[r*ldS + c]); S has R rows, Cc cols; D is [Cc][R].
__global__ __launch_bounds__(256) void k_transpose_bf16(const float* __restrict__ S, int ldS,
    unsigned short* __restrict__ D, int R, int Cc) {
  __shared__ unsigned short T[64][72];
  int r0 = blockIdx.y << 6, c0 = blockIdx.x << 6;
  int tid = threadIdx.x;
  int tr = tid >> 4, tc4 = (tid & 15) << 2;
#pragma unroll
  for (int q = 0; q < 4; ++q) {
    int row = tr + q * 16;
    float4 v = *reinterpret_cast<const float4*>(&S[(size_t)(r0 + row) * ldS + c0 + tc4]);
    T[tc4 + 0][row] = f2b(v.x);
    T[tc4 + 1][row] = f2b(v.y);
    T[tc4 + 2][row] = f2b(v.z);
    T[tc4 + 3][row] = f2b(v.w);
  }
  __syncthreads();
#pragma unroll
  for (int q = 0; q < 4; ++q) {
    int row = tr + q * 16;
    *reinterpret_cast<uint2*>(&D[(size_t)(c0 + row) * R + r0 + tc4]) =
        *reinterpret_cast<const uint2*>(&T[row][tc4]);
  }
}

// C[M,N] = A[M,K] @ B[K,N] (+ rowBias[m]). fp32 vector (down-path projections).
__global__ __launch_bounds__(256) void k_gemm_nn(const float* __restrict__ A,
    const float* __restrict__ B, float* __restrict__ C, int M, int N, int K,
    const float* __restrict__ rowBias) {
  __shared__ float As[16][65];
  __shared__ float Bs[16][64];
  int tid = threadIdx.x;
  int tx = tid & 15, ty = tid >> 4;
  int n0 = blockIdx.x * 64, m0 = blockIdx.y * 64;
  float acc[4][4] = {};
  for (int k0 = 0; k0 < K; k0 += 16) {
    {
      int r = tid >> 2, c = (tid & 3) * 4;
      float4 av = *reinterpret_cast<const float4*>(&A[(size_t)(m0 + r) * K + k0 + c]);
      As[c][r] = av.x; As[c + 1][r] = av.y; As[c + 2][r] = av.z; As[c + 3][r] = av.w;
      int rb = tid >> 4, cb = (tid & 15) * 4;
      *reinterpret_cast<float4*>(&Bs[rb][cb]) =
          *reinterpret_cast<const float4*>(&B[(size_t)(k0 + rb) * N + n0 + cb]);
    }
    __syncthreads();
#pragma unroll
    for (int k = 0; k < 16; ++k) {
      float a[4], b[4];
#pragma unroll
      for (int i = 0; i < 4; ++i) a[i] = As[k][ty * 4 + i];
      float4 bv = *reinterpret_cast<const float4*>(&Bs[k][tx * 4]);
      b[0] = bv.x; b[1] = bv.y; b[2] = bv.z; b[3] = bv.w;
#pragma unroll
      for (int i = 0; i < 4; ++i)
#pragma unroll
        for (int j = 0; j < 4; ++j) acc[i][j] = fmaf(a[i], b[j], acc[i][j]);
    }
    __syncthreads();
  }
#pragma unroll
  for (int i = 0; i < 4; ++i) {
    int m = m0 + ty * 4 + i;
    float rb = rowBias ? rowBias[m] : 0.f;
    float4 o;
    o.x = acc[i][0] + rb; o.y = acc[i][1] + rb; o.z = acc[i][2] + rb; o.w = acc[i][3] + rb;
    *reinterpret_cast<float4*>(&C[(size_t)m * N + n0 + tx * 4]) = o;
  }
}

// ---- fp32 GAT aggregation v2: 128x128 tile, 8x8/thread, reg-prefetch pipeline ----
// grid: (h*ftiles+ft, N/128, JC). P[chunk][N][HF] partials.
__global__ __launch_bounds__(256) void k_gat_f32(const float* __restrict__ Adj, int N,
    const float* __restrict__ Xp, int HF, int F,
    const float* __restrict__ src, const float* __restrict__ dst,
    float* __restrict__ P, int jchunk) {
  __shared__ float wK[32][132];
  __shared__ float xs[32][132];
  int ftiles = F >> 7;
  int h = blockIdx.x / ftiles;
  int f0 = (blockIdx.x % ftiles) << 7;
  int H = HF / F;
  int i0 = blockIdx.y << 7;
  int jb0 = blockIdx.z * jchunk;
  int tid = threadIdx.x;
  int tx = tid & 15, ty = tid >> 4;
  int sj4 = (tid & 7) << 2;   // 0..28
  int si  = tid >> 3;         // 0..31
  int xf4 = (tid & 31) << 2;  // 0..124
  int xj  = tid >> 5;         // 0..7
  int hf0 = h * F + f0;
  float di[4];
#pragma unroll
  for (int q = 0; q < 4; ++q) di[q] = dst[(i0 + si + q * 32) * H + h];
  float4 aw[4];
  float4 xv[4];
  float s4[4];
  {
#pragma unroll
    for (int e = 0; e < 4; ++e) s4[e] = src[(jb0 + sj4 + e) * H + h];
#pragma unroll
    for (int q = 0; q < 4; ++q)
      aw[q] = *reinterpret_cast<const float4*>(&Adj[(size_t)(i0 + si + q * 32) * N + jb0 + sj4]);
#pragma unroll
    for (int q = 0; q < 4; ++q)
      xv[q] = *reinterpret_cast<const float4*>(&Xp[(size_t)(jb0 + xj + q * 8) * HF + hf0 + xf4]);
  }
  float acc[8][8] = {};
  int ntiles = jchunk >> 5;
  for (int t = 0; t < ntiles; ++t) {
    int jb = jb0 + (t << 5);
    // adj regs -> w regs (in place)
#pragma unroll
    for (int q = 0; q < 4; ++q) {
      int gi = i0 + si + q * 32;
      float dq = di[q];
      float* a = (float*)&aw[q];
#pragma unroll
      for (int e = 0; e < 4; ++e) {
        float w = 0.f;
        if (a[e] != 0.f || (jb + sj4 + e) == gi) {
          float tt = dq + s4[e];
          tt = tt >= 0.f ? tt : 0.2f * tt;
          w = __expf(tt);
        }
        a[e] = w;
      }
    }
    __syncthreads();
#pragma unroll
    for (int q = 0; q < 4; ++q) {
      const float* a = (const float*)&aw[q];
#pragma unroll
      for (int e = 0; e < 4; ++e) wK[sj4 + e][si + q * 32] = a[e];
      *reinterpret_cast<float4*>(&xs[xj + q * 8][xf4]) = xv[q];
    }
    __syncthreads();
    if (t + 1 < ntiles) {
      int jn = jb + 32;
#pragma unroll
      for (int e = 0; e < 4; ++e) s4[e] = src[(jn + sj4 + e) * H + h];
#pragma unroll
      for (int q = 0; q < 4; ++q)
        aw[q] = *reinterpret_cast<const float4*>(&Adj[(size_t)(i0 + si + q * 32) * N + jn + sj4]);
#pragma unroll
      for (int q = 0; q < 4; ++q)
        xv[q] = *reinterpret_cast<const float4*>(&Xp[(size_t)(jn + xj + q * 8) * HF + hf0 + xf4]);
    }
#pragma unroll 2
    for (int k = 0; k < 32; ++k) {
      float a[8], b[8];
      *reinterpret_cast<float4*>(&a[0]) = *reinterpret_cast<const float4*>(&wK[k][ty * 8]);
      *reinterpret_cast<float4*>(&a[4]) = *reinterpret_cast<const float4*>(&wK[k][ty * 8 + 4]);
      *reinterpret_cast<float4*>(&b[0]) = *reinterpret_cast<const float4*>(&xs[k][tx * 4]);
      *reinterpret_cast<float4*>(&b[4]) = *reinterpret_cast<const float4*>(&xs[k][64 + tx * 4]);
#pragma unroll
      for (int i = 0; i < 8; ++i)
#pragma unroll
        for (int j = 0; j < 8; ++j) acc[i][j] = fmaf(a[i], b[j], acc[i][j]);
    }
  }
  float* Pc = P + (size_t)blockIdx.z * N * HF;
#pragma unroll
  for (int i = 0; i < 8; ++i) {
    size_t row = (size_t)(i0 + ty * 8 + i) * HF + hf0;
    *reinterpret_cast<float4*>(&Pc[row + tx * 4]) = *reinterpret_cast<const float4*>(&acc[i][0]);
    *reinterpret_cast<float4*>(&Pc[row + 64 + tx * 4]) =
        *reinterpret_cast<const float4*>(&acc[i][4]);
  }
}

// ---- bf16 MFMA GAT aggregation (non-ordering layers): 256x64 tile ----
__global__ __launch_bounds__(256) void k_gat_mfma(const float* __restrict__ Adj, int N,
    const unsigned short* __restrict__ XpT,
    const float* __restrict__ src, const float* __restrict__ dst,
    float* __restrict__ P, int HF, int F, int jchunk) {
  __shared__ __align__(16) unsigned short wL[256][40];
  __shared__ __align__(16) unsigned short xT[64][40];
  __shared__ float dsl[256];
  int ftiles = F >> 6;
  int h = blockIdx.x / ftiles;
  int f0 = (blockIdx.x % ftiles) << 6;
  int H = HF / F;
  int i0 = blockIdx.y << 8;
  int jb0 = blockIdx.z * jchunk;
  int tid = threadIdx.x;
  int lane = tid & 63, w = tid >> 6;
  int lr = lane & 15, kb = lane >> 4;
  dsl[tid] = dst[(i0 + tid) * H + h];
  int sj4 = (tid & 7) << 2;
  int si = tid >> 3;
  int xf = tid >> 2;
  int xj8 = (tid & 3) << 3;
  const unsigned short* xg = XpT + ((size_t)h * F + f0 + xf) * N;
  f32x4 acc[4][4] = {};
  for (int jb = jb0; jb < jb0 + jchunk; jb += 32) {
    __syncthreads();
    float s4[4];
#pragma unroll
    for (int e = 0; e < 4; ++e) s4[e] = src[(jb + sj4 + e) * H + h];
#pragma unroll
    for (int q = 0; q < 8; ++q) {
      int i = si + q * 32;
      int gi = i0 + i;
      float4 av = *reinterpret_cast<const float4*>(&Adj[(size_t)gi * N + jb + sj4]);
      float di = dsl[i];
      float vv[4] = {av.x, av.y, av.z, av.w};
      unsigned short wb[4];
#pragma unroll
      for (int e = 0; e < 4; ++e) {
        float wv = 0.f;
        if (vv[e] != 0.f || (jb + sj4 + e) == gi) {
          float t = di + s4[e];
          t = t >= 0.f ? t : 0.2f * t;
          wv = __expf(t);
        }
        wb[e] = f2b(wv);
      }
      *reinterpret_cast<uint2*>(&wL[i][sj4]) = *reinterpret_cast<const uint2*>(wb);
    }
    *reinterpret_cast<uint4*>(&xT[xf][xj8]) = *reinterpret_cast<const uint4*>(&xg[jb + xj8]);
    __syncthreads();
    bf16x8 a[4], b[4];
#pragma unroll
    for (int m = 0; m < 4; ++m)
      a[m] = *reinterpret_cast<const bf16x8*>(&wL[w * 64 + m * 16 + lr][kb * 8]);
#pragma unroll
    for (int n = 0; n < 4; ++n)
      b[n] = *reinterpret_cast<const bf16x8*>(&xT[n * 16 + lr][kb * 8]);
#pragma unroll
    for (int m = 0; m < 4; ++m)
#pragma unroll
      for (int n = 0; n < 4; ++n)
        acc[m][n] = __builtin_amdgcn_mfma_f32_16x16x32_bf16(a[m], b[n], acc[m][n], 0, 0, 0);
  }
  float* Pc = P + (size_t)blockIdx.z * N * HF;
  int orow = i0 + w * 64 + (lane >> 4) * 4;
  int ocol = h * F + f0 + (lane & 15);
#pragma unroll
  for (int m = 0; m < 4; ++m)
#pragma unroll
    for (int n = 0; n < 4; ++n)
#pragma unroll
      for (int r = 0; r < 4; ++r)
        Pc[(size_t)(orow + m * 16 + r) * HF + ocol + n * 16] = acc[m][n][r];
}

// Out = relu((sum_c P[c]) / den + bias)
__global__ void k_gat_reduce(const float* __restrict__ P, int nch, size_t chstride,
    const float* __restrict__ den, const float* __restrict__ bias, float* __restrict__ Out,
    int HF, int F, int n_total) {
  int e = (blockIdx.x * 256 + threadIdx.x) * 4;
  if (e >= n_total) return;
  float4 s = *reinterpret_cast<const float4*>(&P[e]);
  for (int c = 1; c < nch; ++c) {
    float4 v = *reinterpret_cast<const float4*>(&P[c * chstride + e]);
    s.x += v.x; s.y += v.y; s.z += v.z; s.w += v.w;
  }
  int i = e / HF;
  int hf = e - i * HF;
  int h = hf / F;
  float inv = 1.f / den[i * (HF / F) + h];
  float4 bz = *reinterpret_cast<const float4*>(&bias[hf]);
  float4 o;
  o.x = fmaxf(fmaf(s.x, inv, bz.x), 0.f);
  o.y = fmaxf(fmaf(s.y, inv, bz.y), 0.f);
  o.z = fmaxf(fmaf(s.z, inv, bz.z), 0.f);
  o.w = fmaxf(fmaf(s.w, inv, bz.w), 0.f);
  *reinterpret_cast<float4*>(&Out[e]) = o;
}

// ---- bf16 MFMA: C = relu(G @ G^T), 128x128 block ----
__global__ __launch_bounds__(256) void k_syrk_mfma(const unsigned short* __restrict__ G,
    int M, int Kd, float* __restrict__ C) {
  __shared__ __align__(16) unsigned short Ai[128 * 40];
  __shared__ __align__(16) unsigned short Bj[128 * 40];
  int tid = threadIdx.x;
  int i0 = blockIdx.y << 7, j0 = blockIdx.x << 7;
  int srow = tid >> 1, scol = (tid & 1) << 3;
  int lane = tid & 63, w = tid >> 6;
  int wr = (w >> 1) << 6, wc = (w & 1) << 6;
  int lr = lane & 15, kb = lane >> 4;
  f32x4 acc[4][4] = {};
  const unsigned short* gA = G + (size_t)i0 * Kd;
  const unsigned short* gB = G + (size_t)j0 * Kd;
  for (int k0 = 0; k0 < Kd; k0 += 32) {
    __syncthreads();
#pragma unroll
    for (int kk = 0; kk < 32; kk += 16) {
      *reinterpret_cast<uint4*>(&Ai[srow * 40 + scol + kk]) =
          *reinterpret_cast<const uint4*>(&gA[(size_t)srow * Kd + k0 + scol + kk]);
      *reinterpret_cast<uint4*>(&Bj[srow * 40 + scol + kk]) =
          *reinterpret_cast<const uint4*>(&gB[(size_t)srow * Kd + k0 + scol + kk]);
    }
    __syncthreads();
    bf16x8 a[4], b[4];
#pragma unroll
    for (int m = 0; m < 4; ++m)
      a[m] = *reinterpret_cast<const bf16x8*>(&Ai[(wr + m * 16 + lr) * 40 + kb * 8]);
#pragma unroll
    for (int n = 0; n < 4; ++n)
      b[n] = *reinterpret_cast<const bf16x8*>(&Bj[(wc + n * 16 + lr) * 40 + kb * 8]);
#pragma unroll
    for (int m = 0; m < 4; ++m)
#pragma unroll
      for (int n = 0; n < 4; ++n)
        acc[m][n] = __builtin_amdgcn_mfma_f32_16x16x32_bf16(a[m], b[n], acc[m][n], 0, 0, 0);
  }
  int orow = i0 + wr + (lane >> 4) * 4;
  int ocol = j0 + wc + (lane & 15);
#pragma unroll
  for (int m = 0; m < 4; ++m)
#pragma unroll
    for (int n = 0; n < 4; ++n)
#pragma unroll
      for (int r = 0; r < 4; ++r)
        C[(size_t)(orow + m * 16 + r) * M + ocol + n * 16] = fmaxf(acc[m][n][r], 0.f);
}

// C[M,N] = A[M,K] @ BT[N,K]^T (+ bias[m] if non-null). bf16 in, f32 out.
__global__ __launch_bounds__(256) void k_gemm_mfma_bt(const unsigned short* __restrict__ Amat,
    const unsigned short* __restrict__ BT, const float* __restrict__ bias,
    float* __restrict__ C, int M, int N, int Kd) {
  __shared__ __align__(16) unsigned short Ai[128 * 40];
  __shared__ __align__(16) unsigned short Bj[128 * 40];
  int tid = threadIdx.x;
  int m0 = blockIdx.y << 7, n0 = blockIdx.x << 7;
  int srow = tid >> 1, scol = (tid & 1) << 3;
  int lane = tid & 63, w = tid >> 6;
  int wr = (w >> 1) << 6, wc = (w & 1) << 6;
  int lr = lane & 15, kb = lane >> 4;
  f32x4 acc[4][4] = {};
  const unsigned short* gA = Amat + (size_t)m0 * Kd;
  const unsigned short* gB = BT + (size_t)n0 * Kd;
  for (int k0 = 0; k0 < Kd; k0 += 32) {
    __syncthreads();
#pragma unroll
    for (int kk = 0; kk < 32; kk += 16) {
      *reinterpret_cast<uint4*>(&Ai[srow * 40 + scol + kk]) =
          *reinterpret_cast<const uint4*>(&gA[(size_t)srow * Kd + k0 + scol + kk]);
      *reinterpret_cast<uint4*>(&Bj[srow * 40 + scol + kk]) =
          *reinterpret_cast<const uint4*>(&gB[(size_t)srow * Kd + k0 + scol + kk]);
    }
    __syncthreads();
    bf16x8 a[4], b[4];
#pragma unroll
    for (int m = 0; m < 4; ++m)
      a[m] = *reinterpret_cast<const bf16x8*>(&Ai[(wr + m * 16 + lr) * 40 + kb * 8]);
#pragma unroll
    for (int n = 0; n < 4; ++n)
      b[n] = *reinterpret_cast<const bf16x8*>(&Bj[(wc + n * 16 + lr) * 40 + kb * 8]);
#pragma unroll
    for (int m = 0; m < 4; ++m)
#pragma unroll
      for (int n = 0; n < 4; ++n)
        acc[m][n] = __builtin_amdgcn_mfma_f32_16x16x32_bf16(a[m], b[n], acc[m][n], 0, 0, 0);
  }
  int orow = m0 + wr + (lane >> 4) * 4;
  int ocol = n0 + wc + (lane & 15);
#pragma unroll
  for (int m = 0; m < 4; ++m)
#pragma unroll
    for (int n = 0; n < 4; ++n)
#pragma unroll
      for (int r = 0; r < 4; ++r) {
        float rb = bias ? bias[orow + m * 16 + r] : 0.f;
        C[(size_t)(orow + m * 16 + r) * N + ocol + n * 16] = acc[m][n][r] + rb;
      }
}

// ---- upsampler GEMM: Pz[kc] = Wup(f32,staged->bf16) @ Xu1T^T, 128x256 tile, split-k ----
// grid (KC, M/128), 512 threads (8 waves: wr=w>>2, wc=w&3).
__global__ __launch_bounds__(512) void k_gemm_aup(const float* __restrict__ Wg,
    const unsigned short* __restrict__ BT, float* __restrict__ Pz, int Mtot, int Ktot,
    int kc_len) {
  __shared__ __align__(16) unsigned short Ai[128 * 40];
  __shared__ __align__(16) unsigned short Bj[256 * 40];
  int tid = threadIdx.x;
  int m0 = blockIdx.y << 7;
  int k0base = blockIdx.x * kc_len;
  int lane = tid & 63, w = tid >> 6;
  int wr = (w >> 2) << 6, wc = (w & 3) << 6;
  int lr = lane & 15, kb = lane >> 4;
  int ar = tid >> 2, ac8 = (tid & 3) << 3;
  int br = tid >> 1, bc16 = (tid & 1) << 4;
  f32x4 acc[4][4] = {};
  for (int kk = 0; kk < kc_len; kk += 32) {
    int k0 = k0base + kk;
    __syncthreads();
    {
      const float* arow = &Wg[(size_t)(m0 + ar) * Ktot + k0 + ac8];
      float4 v0 = *reinterpret_cast<const float4*>(arow);
      float4 v1 = *reinterpret_cast<const float4*>(arow + 4);
      unsigned short t8[8] = {f2b(v0.x), f2b(v0.y), f2b(v0.z), f2b(v0.w),
                              f2b(v1.x), f2b(v1.y), f2b(v1.z), f2b(v1.w)};
      *reinterpret_cast<uint4*>(&Ai[ar * 40 + ac8]) = *reinterpret_cast<const uint4*>(t8);
      const unsigned short* brow = &BT[(size_t)br * Ktot + k0 + bc16];
      *reinterpret_cast<uint4*>(&Bj[br * 40 + bc16]) = *reinterpret_cast<const uint4*>(brow);
      *reinterpret_cast<uint4*>(&Bj[br * 40 + bc16 + 8]) =
          *reinterpret_cast<const uint4*>(brow + 8);
    }
    __syncthreads();
    bf16x8 a[4], b[4];
#pragma unroll
    for (int m = 0; m < 4; ++m)
      a[m] = *reinterpret_cast<const bf16x8*>(&Ai[(wr + m * 16 + lr) * 40 + kb * 8]);
#pragma unroll
    for (int n = 0; n < 4; ++n)
      b[n] = *reinterpret_cast<const bf16x8*>(&Bj[(wc + n * 16 + lr) * 40 + kb * 8]);
#pragma unroll
    for (int m = 0; m < 4; ++m)
#pragma unroll
      for (int n = 0; n < 4; ++n)
        acc[m][n] = __builtin_amdgcn_mfma_f32_16x16x32_bf16(a[m], b[n], acc[m][n], 0, 0, 0);
  }
  float* outp = Pz + (size_t)blockIdx.x * Mtot * 256;
  int orow = m0 + wr + (lane >> 4) * 4;
  int ocol = wc + (lane & 15);
#pragma unroll
  for (int m = 0; m < 4; ++m)
#pragma unroll
    for (int n = 0; n < 4; ++n)
#pragma unroll
      for (int r = 0; r < 4; ++r)
        outp[(size_t)(orow + m * 16 + r) * 256 + ocol + n * 16] = acc[m][n][r];
}

// row softmax over 256 cols of (sum_c Pz[c] + bias[row]) -> bf16
__global__ __launch_bounds__(256) void k_softmax_fuse(const float* __restrict__ Pz, int nch,
    size_t chstride, const float* __restrict__ bias, unsigned short* __restrict__ ZB) {
  int row = blockIdx.x, tid = threadIdx.x;
  size_t e = (size_t)row * 256 + tid;
  float x = bias[row];
  for (int c = 0; c < nch; ++c) x += Pz[c * chstride + e];
  float m = x;
#pragma unroll
  for (int off = 32; off; off >>= 1) m = fmaxf(m, __shfl_down(m, off));
  __shared__ float red[4];
  __shared__ float bm, bs;
  if ((tid & 63) == 0) red[tid >> 6] = m;
  __syncthreads();
  if (tid == 0) bm = fmaxf(fmaxf(red[0], red[1]), fmaxf(red[2], red[3]));
  __syncthreads();
  float ev = expf(x - bm);
  float sm = wave_sum64(ev);
  __syncthreads();
  if ((tid & 63) == 0) red[tid >> 6] = sm;
  __syncthreads();
  if (tid == 0) bs = red[0] + red[1] + red[2] + red[3];
  __syncthreads();
  ZB[e] = f2b(ev / bs);
}

// src[n,h] = sum_f Xp[n,h,f]*a_src[h,f]; dst likewise.
__global__ void k_src_dst(const float* __restrict__ Xp, const float* __restrict__ a_src,
    const float* __restrict__ a_dst, float* __restrict__ src, float* __restrict__ dst,
    int H, int F) {
  int n = blockIdx.x;
  int h = threadIdx.x >> 6, lane = threadIdx.x & 63;
  const float* x = Xp + ((size_t)n * H + h) * F;
  const float* as = a_src + h * F;
  const float* ad = a_dst + h * F;
  float ps = 0.f, pd = 0.f;
  for (int f = lane; f < F; f += 64) {
    float xv = x[f];
    ps = fmaf(xv, as[f], ps);
    pd = fmaf(xv, ad[f], pd);
  }
  ps = wave_sum64(ps);
  pd = wave_sum64(pd);
  if (lane == 0) { src[n * H + h] = ps; dst[n * H + h] = pd; }
}

// denom[i,h] = sum_j valid(i,j) * exp(lrelu(dst[i,h]+src[j,h]))
__global__ __launch_bounds__(256) void k_att_denom(const float* __restrict__ Adj,
    const float* __restrict__ src, const float* __restrict__ dst, float* __restrict__ denom,
    int N, int H) {
  int i = blockIdx.x, tid = threadIdx.x;
  float di[4];
#pragma unroll
  for (int h = 0; h < 4; ++h) di[h] = (h < H) ? dst[i * H + h] : 0.f;
  float acc[4] = {0.f, 0.f, 0.f, 0.f};
  const float* row = Adj + (size_t)i * N;
  for (int j = tid; j < N; j += 256) {
    float av = row[j];
    if (av != 0.f || j == i) {
#pragma unroll
      for (int h = 0; h < 4; ++h) {
        if (h < H) {
          float t = di[h] + src[j * H + h];
          t = t >= 0.f ? t : 0.2f * t;
          acc[h] += __expf(t);
        }
      }
    }
  }
  __shared__ float red[4][4];
#pragma unroll
  for (int h = 0; h < 4; ++h) acc[h] = wave_sum64(acc[h]);
  if ((tid & 63) == 0) {
#pragma unroll
    for (int h = 0; h < 4; ++h) red[tid >> 6][h] = acc[h];
  }
  __syncthreads();
  if (tid < H) denom[i * H + tid] = red[0][tid] + red[1][tid] + red[2][tid] + red[3][tid];
}

// s[row] = sigmoid(dot(X[row,:], w) + b)
__global__ __launch_bounds__(256) void k_score(const float* __restrict__ Xf,
    const float* __restrict__ wv, const float* __restrict__ bsc, float* __restrict__ s, int D) {
  int row = blockIdx.x * 4 + (threadIdx.x >> 6);
  int lane = threadIdx.x & 63;
  const float* x = Xf + (size_t)row * D;
  float p = 0.f;
  for (int f = lane; f < D; f += 64) p = fmaf(x[f], wv[f], p);
  p = wave_sum64(p);
  if (lane == 0) s[row] = 1.f / (1.f + expf(-(p + bsc[0])));
}

// top-k by exact rank counting. grid = n/256, dyn LDS = n*8 bytes.
// key: (value desc, index asc) total order; rank = #{keys > mine}.
__global__ __launch_bounds__(256) void k_topk_rank(const float* __restrict__ s, int n, int k,
    int* __restrict__ idx, float* __restrict__ vals) {
  extern __shared__ unsigned long long keys[];
  int tid = threadIdx.x;
  for (int j = tid; j < n; j += 256) {
    unsigned u = __float_as_uint(s[j]);
    unsigned ord = (u & 0x80000000u) ? ~u : (u | 0x80000000u);
    keys[j] = ((unsigned long long)ord << 32) | (unsigned)(~j);
  }
  __syncthreads();
  int i = blockIdx.x * 256 + tid;
  unsigned long long mykey = keys[i];
  int rank = 0;
#pragma unroll 4
  for (int j = 0; j < n; ++j) rank += (keys[j] > mykey);
  if (rank < k) { idx[rank] = i; vals[rank] = s[i]; }
}

__global__ __launch_bounds__(256) void k_gather_rowsum(const float* __restrict__ Asrc, int lda,
    const int* __restrict__ idx, int k, float* __restrict__ sv) {
  int i = blockIdx.x;
  const float* row = Asrc + (size_t)idx[i] * lda;
  float p = 0.f;
  for (int j = threadIdx.x; j < k; j += 256) p += row[idx[j]];
  p = wave_sum64(p);
  __shared__ float red[4];
  if ((threadIdx.x & 63) == 0) red[threadIdx.x >> 6] = p;
  __syncthreads();
  if (threadIdx.x == 0) sv[i] = 1.f / sqrtf(red[0] + red[1] + red[2] + red[3] + 1e-5f);
}

__global__ void k_symnorm_write(const float* __restrict__ Asrc, int lda,
    const int* __restrict__ idx, const float* __restrict__ sv, float* __restrict__ B, int k) {
  int j = blockIdx.x * 256 + threadIdx.x;
  int i = blockIdx.y;
  B[(size_t)i * k + j] = Asrc[(size_t)idx[i] * lda + idx[j]] * sv[i] * sv[j];
}

__global__ void k_gather_mat(const float* __restrict__ Asrc, int lda,
    const int* __restrict__ idx, float* __restrict__ B, int k) {
  int j = blockIdx.x * 256 + threadIdx.x;
  int i = blockIdx.y;
  B[(size_t)i * k + j] = Asrc[(size_t)idx[i] * lda + idx[j]];
}

__global__ void k_gather_scale_rows(const float* __restrict__ Xs, int D,
    const int* __restrict__ idx, const float* __restrict__ v, float* __restrict__ Xo) {
  int f = blockIdx.x * 256 + threadIdx.x;
  int i = blockIdx.y;
  Xo[(size_t)i * D + f] = Xs[(size_t)idx[i] * D + f] * v[i];
}

__global__ void k_scatter_rows(const float* __restrict__ P, int D, const int* __restrict__ idx,
                               float* __restrict__ Xo) {
  int f = blockIdx.x * 256 + threadIdx.x;
  int i = blockIdx.y;
  Xo[(size_t)idx[i] * D + f] = P[(size_t)i * D + f];
}

extern "C" void kernel_launch(void* const* d_in, const int* in_sizes, int n_in,
                              void* d_out, int out_size, void* d_ws, size_t ws_size,
                              hipStream_t stream) {
  const float* A    = (const float*)d_in[0];
  const float* X    = (const float*)d_in[1];
  const float* Wd0  = (const float*)d_in[2];
  const float* asd0 = (const float*)d_in[3];
  const float* add0 = (const float*)d_in[4];
  const float* bd0  = (const float*)d_in[5];
  const float* Wd1  = (const float*)d_in[6];
  const float* asd1 = (const float*)d_in[7];
  const float* add1 = (const float*)d_in[8];
  const float* bd1  = (const float*)d_in[9];
  const float* wp0  = (const float*)d_in[10];
  const float* bp0  = (const float*)d_in[11];
  const float* wp1  = (const float*)d_in[12];
  const float* bp1  = (const float*)d_in[13];
  const float* Wb   = (const float*)d_in[14];
  const float* asb  = (const float*)d_in[15];
  const float* adb  = (const float*)d_in[16];
  const float* bb   = (const float*)d_in[17];
  const float* Wu0  = (const float*)d_in[18];
  const float* asu0 = (const float*)d_in[19];
  const float* adu0 = (const float*)d_in[20];
  const float* bu0  = (const float*)d_in[21];
  const float* Wu1  = (const float*)d_in[22];
  const float* asu1 = (const float*)d_in[23];
  const float* adu1 = (const float*)d_in[24];
  const float* bu1  = (const float*)d_in[25];
  const float* Wup  = (const float*)d_in[26];
  const float* bup  = (const float*)d_in[27];
  (void)in_sizes; (void)n_in; (void)out_size; (void)ws_size;

  float* out  = (float*)d_out;
  float* Aup  = out;                    // [8192*8192]
  float* A0   = out + 67108864ULL;      // [4096*4096]
  float* A1   = A0 + 16777216ULL;       // [2048*2048]
  float* rec0 = A1 + 4194304ULL;        // [2048*2048]
  float* rec1 = rec0 + 4194304ULL;      // [4096*4096]

  // Scratch in the A_up output region (dead before A_up syrk writes).
  float* S = Aup;
  size_t off = 0;
  auto nxt = [&](size_t n) { float* p = S + off; off += (n + 1023) & ~(size_t)1023; return p; };
  float* Xp0  = nxt(4096 * 512);
  float* X0   = nxt(4096 * 512);
  float* src0 = nxt(4096 * 4);
  float* dst0 = nxt(4096 * 4);
  float* den0 = nxt(4096 * 4);
  float* sc0  = nxt(4096);
  int*   idx0 = (int*)nxt(2048);
  float* v0   = nxt(2048);
  float* sv0  = nxt(2048);
  float* X1in = nxt(2048 * 512);
  float* Xp1  = nxt(2048 * 1024);
  float* X1   = nxt(2048 * 1024);
  float* src1 = nxt(2048 * 4);
  float* dst1 = nxt(2048 * 4);
  float* den1 = nxt(2048 * 4);
  float* sc1  = nxt(2048);
  int*   idx1 = (int*)nxt(1024);
  float* v1   = nxt(1024);
  float* A2m  = nxt(1024 * 1024);
  float* X2in = nxt(1024 * 1024);
  float* Xpb  = nxt(1024 * 1024);
  float* Xb   = nxt(1024 * 1024);
  float* srcb = nxt(1024 * 2);
  float* dstb = nxt(1024 * 2);
  float* denb = nxt(1024 * 2);
  float* Pu0  = nxt(1024 * 512);
  float* Xpu0 = nxt(2048 * 512);
  float* Xu0  = nxt(2048 * 512);
  float* su0  = nxt(2048 * 4);
  float* du0  = nxt(2048 * 4);
  float* dn0  = nxt(2048 * 4);
  float* Pu1  = nxt(2048 * 256);
  float* Xpu1 = nxt(4096 * 256);
  float* su1  = nxt(4096 * 4);
  float* du1  = nxt(4096 * 4);
  float* dn1  = nxt(4096 * 4);
  float* P    = nxt((size_t)8 * 4096 * 512);               // split-j partials (67 MB)
  unsigned short* XpT  = (unsigned short*)nxt(524288);     // [H][F][N] bf16
  unsigned short* X2inB = (unsigned short*)nxt(524288);
  unsigned short* XbB   = (unsigned short*)nxt(524288);
  unsigned short* WbT   = (unsigned short*)nxt(524288);
  unsigned short* Wu0T  = (unsigned short*)nxt(262144);
  unsigned short* Wu1T  = (unsigned short*)nxt(65536);

  // d_ws: final-stage-live buffers
  float* W = (float*)d_ws;
  float* Xu1 = W;                                               // 4096*256 f32
  unsigned short* Xu1B = (unsigned short*)(W + 1048576);        // 4096*256 bf16
  unsigned short* Xu0B = (unsigned short*)(W + 1048576 + 524288);  // 2048*512 bf16

  // rec1 output region as late scratch (dead before rec1 syrk writes)
  float* Pz = rec1;                                             // 4 x 8192*256 f32 (32 MB)
  unsigned short* ZB = (unsigned short*)(rec1 + 4 * 2097152);   // 8192*256 bf16
  unsigned short* Xu1T = (unsigned short*)(rec1 + 4 * 2097152 + 1048576);  // 256*4096 bf16

  // ---- A0 = A + I ----
  k_add_eye<<<16384, 256, 0, stream>>>(A, A0);

  // ---- down level 0: GAT(256 -> 4x128), fp32 ----
  k_gemm_nn<<<dim3(8, 64), 256, 0, stream>>>(X, Wd0, Xp0, 4096, 512, 256, nullptr);
  k_src_dst<<<4096, 256, 0, stream>>>(Xp0, asd0, add0, src0, dst0, 4, 128);
  k_att_denom<<<4096, 256, 0, stream>>>(A0, src0, dst0, den0, 4096, 4);
  k_gat_f32<<<dim3(4, 32, 8), 256, 0, stream>>>(A0, 4096, Xp0, 512, 128, src0, dst0, P, 512);
  k_gat_reduce<<<2048, 256, 0, stream>>>(P, 8, (size_t)4096 * 512, den0, bd0, X0, 512, 128,
                                         4096 * 512);
  k_score<<<1024, 256, 0, stream>>>(X0, wp0, bp0, sc0, 512);
  k_topk_rank<<<16, 256, 4096 * 8, stream>>>(sc0, 4096, 2048, idx0, v0);
  k_gather_rowsum<<<2048, 256, 0, stream>>>(A0, 4096, idx0, 2048, sv0);
  k_symnorm_write<<<dim3(8, 2048), 256, 0, stream>>>(A0, 4096, idx0, sv0, A1, 2048);
  k_gather_scale_rows<<<dim3(2, 2048), 256, 0, stream>>>(X0, 512, idx0, v0, X1in);

  // ---- down level 1: GAT(512 -> 4x256), fp32 ----
  k_gemm_nn<<<dim3(16, 32), 256, 0, stream>>>(X1in, Wd1, Xp1, 2048, 1024, 512, nullptr);
  k_src_dst<<<2048, 256, 0, stream>>>(Xp1, asd1, add1, src1, dst1, 4, 256);
  k_att_denom<<<2048, 256, 0, stream>>>(A1, src1, dst1, den1, 2048, 4);
  k_gat_f32<<<dim3(8, 16, 8), 256, 0, stream>>>(A1, 2048, Xp1, 1024, 256, src1, dst1, P, 256);
  k_gat_reduce<<<2048, 256, 0, stream>>>(P, 8, (size_t)2048 * 1024, den1, bd1, X1, 1024, 256,
                                         2048 * 1024);
  k_score<<<512, 256, 0, stream>>>(X1, wp1, bp1, sc1, 1024);
  k_topk_rank<<<8, 256, 2048 * 8, stream>>>(sc1, 2048, 1024, idx1, v1);
  k_gather_mat<<<dim3(4, 1024), 256, 0, stream>>>(A1, 2048, idx1, A2m, 1024);
  k_gather_scale_rows<<<dim3(4, 1024), 256, 0, stream>>>(X1, 1024, idx1, v1, X2in);

  // ---- bottom: GAT(1024 -> 2x512), bf16 MFMA ----
  k_f32_to_bf16<<<1024, 256, 0, stream>>>(X2in, X2inB, 1024 * 1024);
  k_transpose_bf16<<<dim3(16, 16), 256, 0, stream>>>(Wb, 1024, WbT, 1024, 1024);
  k_gemm_mfma_bt<<<dim3(8, 8), 256, 0, stream>>>(X2inB, WbT, nullptr, Xpb, 1024, 1024, 1024);
  k_src_dst<<<1024, 128, 0, stream>>>(Xpb, asb, adb, srcb, dstb, 2, 512);
  k_att_denom<<<1024, 256, 0, stream>>>(A2m, srcb, dstb, denb, 1024, 2);
  for (int h = 0; h < 2; ++h)
    k_transpose_bf16<<<dim3(8, 16), 256, 0, stream>>>(Xpb + h * 512, 1024,
                                                      XpT + (size_t)h * 512 * 1024, 1024, 512);
  k_gat_mfma<<<dim3(16, 4, 8), 256, 0, stream>>>(A2m, 1024, XpT, srcb, dstb, P, 1024, 512, 128);
  k_gat_reduce<<<1024, 256, 0, stream>>>(P, 8, (size_t)1024 * 1024, denb, bb, Xb, 1024, 512,
                                         1024 * 1024);

  // ---- up level 0: unpool -> GAT(1024 -> 4x128) over A1, bf16 MFMA ----
  k_f32_to_bf16<<<1024, 256, 0, stream>>>(Xb, XbB, 1024 * 1024);
  k_transpose_bf16<<<dim3(8, 16), 256, 0, stream>>>(Wu0, 512, Wu0T, 1024, 512);
  k_gemm_mfma_bt<<<dim3(4, 8), 256, 0, stream>>>(XbB, Wu0T, nullptr, Pu0, 1024, 512, 1024);
  k_fill0<<<1024, 256, 0, stream>>>(Xpu0, 2048 * 512);
  k_scatter_rows<<<dim3(2, 1024), 256, 0, stream>>>(Pu0, 512, idx1, Xpu0);
  k_src_dst<<<2048, 256, 0, stream>>>(Xpu0, asu0, adu0, su0, du0, 4, 128);
  k_att_denom<<<2048, 256, 0, stream>>>(A1, su0, du0, dn0, 2048, 4);
  for (int h = 0; h < 4; ++h)
    k_transpose_bf16<<<dim3(2, 32), 256, 0, stream>>>(Xpu0 + h * 128, 512,
                                                      XpT + (size_t)h * 128 * 2048, 2048, 128);
  k_gat_mfma<<<dim3(8, 8, 8), 256, 0, stream>>>(A1, 2048, XpT, su0, du0, P, 512, 128, 256);
  k_gat_reduce<<<1024, 256, 0, stream>>>(P, 8, (size_t)2048 * 512, dn0, bu0, Xu0, 512, 128,
                                         2048 * 512);
  k_f32_to_bf16<<<1024, 256, 0, stream>>>(Xu0, Xu0B, 2048 * 512);

  // ---- up level 1: unpool -> GAT(512 -> 4x64) over A0, bf16 MFMA ----
  k_transpose_bf16<<<dim3(4, 8), 256, 0, stream>>>(Wu1, 256, Wu1T, 512, 256);
  k_gemm_mfma_bt<<<dim3(2, 16), 256, 0, stream>>>(Xu0B, Wu1T, nullptr, Pu1, 2048, 256, 512);
  k_fill0<<<1024, 256, 0, stream>>>(Xpu1, 4096 * 256);
  k_scatter_rows<<<dim3(1, 2048), 256, 0, stream>>>(Pu1, 256, idx0, Xpu1);
  k_src_dst<<<4096, 256, 0, stream>>>(Xpu1, asu1, adu1, su1, du1, 4, 64);
  k_att_denom<<<4096, 256, 0, stream>>>(A0, su1, du1, dn1, 4096, 4);
  for (int h = 0; h < 4; ++h)
    k_transpose_bf16<<<dim3(1, 64), 256, 0, stream>>>(Xpu1 + h * 64, 256,
                                                      XpT + (size_t)h * 64 * 4096, 4096, 64);
  k_gat_mfma<<<dim3(4, 16, 8), 256, 0, stream>>>(A0, 4096, XpT, su1, du1, P, 256, 64, 512);
  k_gat_reduce<<<1024, 256, 0, stream>>>(P, 8, (size_t)4096 * 256, dn1, bu1, Xu1, 256, 64,
                                         4096 * 256);
  k_f32_to_bf16<<<1024, 256, 0, stream>>>(Xu1, Xu1B, 4096 * 256);
  k_transpose_bf16<<<dim3(4, 64), 256, 0, stream>>>(Xu1, 256, Xu1T, 4096, 256);

  // ---- upsampler: split-k GEMM (fused f32->bf16 A staging) + fused softmax ----
  k_gemm_aup<<<dim3(4, 64), 512, 0, stream>>>(Wup, Xu1T, Pz, 8192, 4096, 1024);
  k_softmax_fuse<<<8192, 256, 0, stream>>>(Pz, 4, (size_t)8192 * 256, bup, ZB);
  k_syrk_mfma<<<dim3(64, 64), 256, 0, stream>>>(ZB, 8192, 256, Aup);

  // ---- reconstructions ----
  k_syrk_mfma<<<dim3(32, 32), 256, 0, stream>>>(Xu1B, 4096, 256, rec1);
  k_syrk_mfma<<<dim3(16, 16), 256, 0, stream>>>(Xu0B, 2048, 512, rec0);
}

// Round 5
// 1292.559 us; speedup vs baseline: 2.0905x; 1.0454x over previous
//
#include <hip/hip_runtime.h>
#include <math.h>

// ---------------------------------------------------------------------------
// Graph U-Net forward on MI355X.
// Down-path GAT aggregations (feed top-k orderings) use bf16x6 split MFMA
// (3-way bf16 decomposition, ~3e-8 relative error -- below fp32-reorder noise).
// Bottom/up GATs + projections + reconstructions + upsampler = plain bf16 MFMA.
// ---------------------------------------------------------------------------

typedef short bf16x8 __attribute__((ext_vector_type(8)));
typedef float f32x4 __attribute__((ext_vector_type(4)));

static __device__ __forceinline__ float wave_sum64(float v) {
#pragma unroll
  for (int off = 32; off; off >>= 1) v += __shfl_down(v, off);
  return v;
}

static __device__ __forceinline__ unsigned short f2b(float x) {
  unsigned u = __float_as_uint(x);
  unsigned r = (u + 0x7fffu + ((u >> 16) & 1u)) >> 16;
  return (unsigned short)r;
}

static __device__ __forceinline__ float b2f(unsigned short h) {
  return __uint_as_float(((unsigned)h) << 16);
}

// A0 = A + I  (4096x4096), float4
__global__ void k_add_eye(const float* __restrict__ A, float* __restrict__ O) {
  size_t i = ((size_t)blockIdx.x * 256 + threadIdx.x) * 4;
  size_t r = i >> 12, c = i & 4095;
  float4 v = *reinterpret_cast<const float4*>(&A[i]);
  if (r >= c && r < c + 4) ((float*)&v)[r - c] += 1.f;
  *reinterpret_cast<float4*>(&O[i]) = v;
}

__global__ void k_fill0(float* __restrict__ p, int n) {
  int stride = gridDim.x * 256;
  for (int i = blockIdx.x * 256 + threadIdx.x; i < n; i += stride) p[i] = 0.f;
}

__global__ void k_f32_to_bf16(const float* __restrict__ S, unsigned short* __restrict__ D,
                              int n) {
  int stride = gridDim.x * 1024;
  for (int i = (blockIdx.x * 256 + threadIdx.x) * 4; i < n; i += stride) {
    float4 v = *reinterpret_cast<const float4*>(&S[i]);
    uint2 o;
    o.x = (unsigned)f2b(v.x) | ((unsigned)f2b(v.y) << 16);
    o.y = (unsigned)f2b(v.z) | ((unsigned)f2b(v.w) << 16);
    *reinterpret_cast<uint2*>(&D[i]) = o;
  }
}

// D[c][r] = bf16(S[r*ldS + c]); S has R rows, Cc cols; D is [Cc][R].
__global__ __launch_bounds__(256) void k_transpose_bf16(const float* __restrict__ S, int ldS,
    unsigned short* __restrict__ D, int R, int Cc) {
  __shared__ unsigned short T[64][72];
  int r0 = blockIdx.y << 6, c0 = blockIdx.x << 6;
  int tid = threadIdx.x;
  int tr = tid >> 4, tc4 = (tid & 15) << 2;
#pragma unroll
  for (int q = 0; q < 4; ++q) {
    int row = tr + q * 16;
    float4 v = *reinterpret_cast<const float4*>(&S[(size_t)(r0 + row) * ldS + c0 + tc4]);
    T[tc4 + 0][row] = f2b(v.x);
    T[tc4 + 1][row] = f2b(v.y);
    T[tc4 + 2][row] = f2b(v.z);
    T[tc4 + 3][row] = f2b(v.w);
  }
  __syncthreads();
#pragma unroll
  for (int q = 0; q < 4; ++q) {
    int row = tr + q * 16;
    *reinterpret_cast<uint2*>(&D[(size_t)(c0 + row) * R + r0 + tc4]) =
        *reinterpret_cast<const uint2*>(&T[row][tc4]);
  }
}

// 3-way bf16 split + transpose: D[p*PS + (h*F + c)*R + r] = split_p(S[r*ldS + h*F + c]).
__global__ __launch_bounds__(256) void k_transpose_split(const float* __restrict__ S, int ldS,
    int F, unsigned short* __restrict__ D, int R, size_t PS) {
  __shared__ unsigned short T[3][64][72];
  int h = blockIdx.z;
  int c0 = blockIdx.x << 6, r0 = blockIdx.y << 6;
  int tid = threadIdx.x;
  int tr = tid >> 4, tc4 = (tid & 15) << 2;
#pragma unroll
  for (int q = 0; q < 4; ++q) {
    int row = tr + q * 16;
    float4 v = *reinterpret_cast<const float4*>(&S[(size_t)(r0 + row) * ldS + h * F + c0 + tc4]);
    float xv[4] = {v.x, v.y, v.z, v.w};
#pragma unroll
    for (int e = 0; e < 4; ++e) {
      float x = xv[e];
      unsigned short h1 = f2b(x);
      float r1 = x - b2f(h1);
      unsigned short h2 = f2b(r1);
      float r2 = r1 - b2f(h2);
      unsigned short h3 = f2b(r2);
      T[0][tc4 + e][row] = h1;
      T[1][tc4 + e][row] = h2;
      T[2][tc4 + e][row] = h3;
    }
  }
  __syncthreads();
#pragma unroll
  for (int p = 0; p < 3; ++p)
#pragma unroll
    for (int q = 0; q < 4; ++q) {
      int row = tr + q * 16;
      *reinterpret_cast<uint2*>(&D[p * PS + (size_t)(h * F + c0 + row) * R + r0 + tc4]) =
          *reinterpret_cast<const uint2*>(&T[p][row][tc4]);
    }
}

// C[M,N] = A[M,K] @ B[K,N] (+ rowBias[m]). fp32 vector (down-path projections).
__global__ __launch_bounds__(256) void k_gemm_nn(const float* __restrict__ A,
    const float* __restrict__ B, float* __restrict__ C, int M, int N, int K,
    const float* __restrict__ rowBias) {
  __shared__ float As[16][65];
  __shared__ float Bs[16][64];
  int tid = threadIdx.x;
  int tx = tid & 15, ty = tid >> 4;
  int n0 = blockIdx.x * 64, m0 = blockIdx.y * 64;
  float acc[4][4] = {};
  for (int k0 = 0; k0 < K; k0 += 16) {
    {
      int r = tid >> 2, c = (tid & 3) * 4;
      float4 av = *reinterpret_cast<const float4*>(&A[(size_t)(m0 + r) * K + k0 + c]);
      As[c][r] = av.x; As[c + 1][r] = av.y; As[c + 2][r] = av.z; As[c + 3][r] = av.w;
      int rb = tid >> 4, cb = (tid & 15) * 4;
      *reinterpret_cast<float4*>(&Bs[rb][cb]) =
          *reinterpret_cast<const float4*>(&B[(size_t)(k0 + rb) * N + n0 + cb]);
    }
    __syncthreads();
#pragma unroll
    for (int k = 0; k < 16; ++k) {
      float a[4], b[4];
#pragma unroll
      for (int i = 0; i < 4; ++i) a[i] = As[k][ty * 4 + i];
      float4 bv = *reinterpret_cast<const float4*>(&Bs[k][tx * 4]);
      b[0] = bv.x; b[1] = bv.y; b[2] = bv.z; b[3] = bv.w;
#pragma unroll
      for (int i = 0; i < 4; ++i)
#pragma unroll
        for (int j = 0; j < 4; ++j) acc[i][j] = fmaf(a[i], b[j], acc[i][j]);
    }
    __syncthreads();
  }
#pragma unroll
  for (int i = 0; i < 4; ++i) {
    int m = m0 + ty * 4 + i;
    float rb = rowBias ? rowBias[m] : 0.f;
    float4 o;
    o.x = acc[i][0] + rb; o.y = acc[i][1] + rb; o.z = acc[i][2] + rb; o.w = acc[i][3] + rb;
    *reinterpret_cast<float4*>(&C[(size_t)m * N + n0 + tx * 4]) = o;
  }
}

// ---- bf16x6 split-MFMA GAT aggregation (ordering-critical, ~3e-8 rel err) ----
// 128i x 64f block, 4 waves (each 32i x 64f). XpS = 3 planes [H][F][N] bf16.
// grid: (h*(F/64)+ft, N/128, JC). P[chunk][N][HF] partials.
__global__ __launch_bounds__(256, 3) void k_gat_x6(const float* __restrict__ Adj, int N,
    const unsigned short* __restrict__ XpS, size_t PS,
    const float* __restrict__ src, const float* __restrict__ dst,
    float* __restrict__ P, int HF, int F, int jchunk) {
  __shared__ __align__(16) unsigned short wB[3][128 * 40];
  __shared__ __align__(16) unsigned short xB[3][64 * 40];
  int ftiles = F >> 6;
  int h = blockIdx.x / ftiles;
  int f0 = (blockIdx.x % ftiles) << 6;
  int H = HF / F;
  int i0 = blockIdx.y << 7;
  int jb0 = blockIdx.z * jchunk;
  int tid = threadIdx.x;
  int lane = tid & 63, w = tid >> 6;
  int lr = lane & 15, kb = lane >> 4;
  int wr = w << 5;  // wave i-offset
  int sj4 = (tid & 7) << 2, si = tid >> 3;
  int xf = tid >> 2, xj8 = (tid & 3) << 3;
  float di[4];
#pragma unroll
  for (int q = 0; q < 4; ++q) di[q] = dst[(i0 + si + q * 32) * H + h];
  const unsigned short* xg = XpS + ((size_t)h * F + f0 + xf) * N;

  float4 aw[4];
  float s4[4];
  uint4 xv[3];
  {
#pragma unroll
    for (int e = 0; e < 4; ++e) s4[e] = src[(jb0 + sj4 + e) * H + h];
#pragma unroll
    for (int q = 0; q < 4; ++q)
      aw[q] = *reinterpret_cast<const float4*>(&Adj[(size_t)(i0 + si + q * 32) * N + jb0 + sj4]);
#pragma unroll
    for (int p = 0; p < 3; ++p)
      xv[p] = *reinterpret_cast<const uint4*>(&xg[p * PS + jb0 + xj8]);
  }

  f32x4 acc[2][4] = {};
  int ntiles = jchunk >> 5;
  for (int t = 0; t < ntiles; ++t) {
    int jb = jb0 + (t << 5);
    // compute 3-way split of w from prefetched regs
    uint2 wp[4][3];
#pragma unroll
    for (int q = 0; q < 4; ++q) {
      int gi = i0 + si + q * 32;
      float dq = di[q];
      const float* a = (const float*)&aw[q];
      unsigned short h1[4], h2[4], h3[4];
#pragma unroll
      for (int e = 0; e < 4; ++e) {
        float wv = 0.f;
        if (a[e] != 0.f || (jb + sj4 + e) == gi) {
          float tt = dq + s4[e];
          tt = tt >= 0.f ? tt : 0.2f * tt;
          wv = __expf(tt);
        }
        h1[e] = f2b(wv);
        float r1 = wv - b2f(h1[e]);
        h2[e] = f2b(r1);
        float r2 = r1 - b2f(h2[e]);
        h3[e] = f2b(r2);
      }
      wp[q][0].x = (unsigned)h1[0] | ((unsigned)h1[1] << 16);
      wp[q][0].y = (unsigned)h1[2] | ((unsigned)h1[3] << 16);
      wp[q][1].x = (unsigned)h2[0] | ((unsigned)h2[1] << 16);
      wp[q][1].y = (unsigned)h2[2] | ((unsigned)h2[3] << 16);
      wp[q][2].x = (unsigned)h3[0] | ((unsigned)h3[1] << 16);
      wp[q][2].y = (unsigned)h3[2] | ((unsigned)h3[3] << 16);
    }
    __syncthreads();
#pragma unroll
    for (int q = 0; q < 4; ++q)
#pragma unroll
      for (int p = 0; p < 3; ++p)
        *reinterpret_cast<uint2*>(&wB[p][(si + q * 32) * 40 + sj4]) = wp[q][p];
#pragma unroll
    for (int p = 0; p < 3; ++p)
      *reinterpret_cast<uint4*>(&xB[p][xf * 40 + xj8]) = xv[p];
    __syncthreads();
    if (t + 1 < ntiles) {
      int jn = jb + 32;
#pragma unroll
      for (int e = 0; e < 4; ++e) s4[e] = src[(jn + sj4 + e) * H + h];
#pragma unroll
      for (int q = 0; q < 4; ++q)
        aw[q] = *reinterpret_cast<const float4*>(&Adj[(size_t)(i0 + si + q * 32) * N + jn + sj4]);
#pragma unroll
      for (int p = 0; p < 3; ++p)
        xv[p] = *reinterpret_cast<const uint4*>(&xg[p * PS + jn + xj8]);
    }
    bf16x8 a[2][3], b[4][3];
#pragma unroll
    for (int m = 0; m < 2; ++m)
#pragma unroll
      for (int p = 0; p < 3; ++p)
        a[m][p] = *reinterpret_cast<const bf16x8*>(&wB[p][(wr + m * 16 + lr) * 40 + kb * 8]);
#pragma unroll
    for (int n = 0; n < 4; ++n)
#pragma unroll
      for (int p = 0; p < 3; ++p)
        b[n][p] = *reinterpret_cast<const bf16x8*>(&xB[p][(n * 16 + lr) * 40 + kb * 8]);
#pragma unroll
    for (int m = 0; m < 2; ++m)
#pragma unroll
      for (int n = 0; n < 4; ++n) {
        acc[m][n] = __builtin_amdgcn_mfma_f32_16x16x32_bf16(a[m][0], b[n][0], acc[m][n], 0, 0, 0);
        acc[m][n] = __builtin_amdgcn_mfma_f32_16x16x32_bf16(a[m][0], b[n][1], acc[m][n], 0, 0, 0);
        acc[m][n] = __builtin_amdgcn_mfma_f32_16x16x32_bf16(a[m][1], b[n][0], acc[m][n], 0, 0, 0);
        acc[m][n] = __builtin_amdgcn_mfma_f32_16x16x32_bf16(a[m][0], b[n][2], acc[m][n], 0, 0, 0);
        acc[m][n] = __builtin_amdgcn_mfma_f32_16x16x32_bf16(a[m][2], b[n][0], acc[m][n], 0, 0, 0);
        acc[m][n] = __builtin_amdgcn_mfma_f32_16x16x32_bf16(a[m][1], b[n][1], acc[m][n], 0, 0, 0);
      }
  }
  float* Pc = P + (size_t)blockIdx.z * N * HF;
  int orow0 = i0 + wr + (lane >> 4) * 4;
  int ocol = h * F + f0 + (lane & 15);
#pragma unroll
  for (int m = 0; m < 2; ++m)
#pragma unroll
    for (int n = 0; n < 4; ++n)
#pragma unroll
      for (int r = 0; r < 4; ++r)
        Pc[(size_t)(orow0 + m * 16 + r) * HF + ocol + n * 16] = acc[m][n][r];
}

// ---- bf16 MFMA GAT aggregation (non-ordering layers): 256x64 tile ----
__global__ __launch_bounds__(256) void k_gat_mfma(const float* __restrict__ Adj, int N,
    const unsigned short* __restrict__ XpT,
    const float* __restrict__ src, const float* __restrict__ dst,
    float* __restrict__ P, int HF, int F, int jchunk) {
  __shared__ __align__(16) unsigned short wL[256][40];
  __shared__ __align__(16) unsigned short xT[64][40];
  __shared__ float dsl[256];
  int ftiles = F >> 6;
  int h = blockIdx.x / ftiles;
  int f0 = (blockIdx.x % ftiles) << 6;
  int H = HF / F;
  int i0 = blockIdx.y << 8;
  int jb0 = blockIdx.z * jchunk;
  int tid = threadIdx.x;
  int lane = tid & 63, w = tid >> 6;
  int lr = lane & 15, kb = lane >> 4;
  dsl[tid] = dst[(i0 + tid) * H + h];
  int sj4 = (tid & 7) << 2;
  int si = tid >> 3;
  int xf = tid >> 2;
  int xj8 = (tid & 3) << 3;
  const unsigned short* xg = XpT + ((size_t)h * F + f0 + xf) * N;
  f32x4 acc[4][4] = {};
  for (int jb = jb0; jb < jb0 + jchunk; jb += 32) {
    __syncthreads();
    float s4[4];
#pragma unroll
    for (int e = 0; e < 4; ++e) s4[e] = src[(jb + sj4 + e) * H + h];
#pragma unroll
    for (int q = 0; q < 8; ++q) {
      int i = si + q * 32;
      int gi = i0 + i;
      float4 av = *reinterpret_cast<const float4*>(&Adj[(size_t)gi * N + jb + sj4]);
      float di = dsl[i];
      float vv[4] = {av.x, av.y, av.z, av.w};
      unsigned short wb[4];
#pragma unroll
      for (int e = 0; e < 4; ++e) {
        float wv = 0.f;
        if (vv[e] != 0.f || (jb + sj4 + e) == gi) {
          float t = di + s4[e];
          t = t >= 0.f ? t : 0.2f * t;
          wv = __expf(t);
        }
        wb[e] = f2b(wv);
      }
      *reinterpret_cast<uint2*>(&wL[i][sj4]) = *reinterpret_cast<const uint2*>(wb);
    }
    *reinterpret_cast<uint4*>(&xT[xf][xj8]) = *reinterpret_cast<const uint4*>(&xg[jb + xj8]);
    __syncthreads();
    bf16x8 a[4], b[4];
#pragma unroll
    for (int m = 0; m < 4; ++m)
      a[m] = *reinterpret_cast<const bf16x8*>(&wL[w * 64 + m * 16 + lr][kb * 8]);
#pragma unroll
    for (int n = 0; n < 4; ++n)
      b[n] = *reinterpret_cast<const bf16x8*>(&xT[n * 16 + lr][kb * 8]);
#pragma unroll
    for (int m = 0; m < 4; ++m)
#pragma unroll
      for (int n = 0; n < 4; ++n)
        acc[m][n] = __builtin_amdgcn_mfma_f32_16x16x32_bf16(a[m], b[n], acc[m][n], 0, 0, 0);
  }
  float* Pc = P + (size_t)blockIdx.z * N * HF;
  int orow = i0 + w * 64 + (lane >> 4) * 4;
  int ocol = h * F + f0 + (lane & 15);
#pragma unroll
  for (int m = 0; m < 4; ++m)
#pragma unroll
    for (int n = 0; n < 4; ++n)
#pragma unroll
      for (int r = 0; r < 4; ++r)
        Pc[(size_t)(orow + m * 16 + r) * HF + ocol + n * 16] = acc[m][n][r];
}

// Out = relu((sum_c P[c]) / den + bias)
__global__ void k_gat_reduce(const float* __restrict__ P, int nch, size_t chstride,
    const float* __restrict__ den, const float* __restrict__ bias, float* __restrict__ Out,
    int HF, int F, int n_total) {
  int e = (blockIdx.x * 256 + threadIdx.x) * 4;
  if (e >= n_total) return;
  float4 s = *reinterpret_cast<const float4*>(&P[e]);
  for (int c = 1; c < nch; ++c) {
    float4 v = *reinterpret_cast<const float4*>(&P[c * chstride + e]);
    s.x += v.x; s.y += v.y; s.z += v.z; s.w += v.w;
  }
  int i = e / HF;
  int hf = e - i * HF;
  int h = hf / F;
  float inv = 1.f / den[i * (HF / F) + h];
  float4 bz = *reinterpret_cast<const float4*>(&bias[hf]);
  float4 o;
  o.x = fmaxf(fmaf(s.x, inv, bz.x), 0.f);
  o.y = fmaxf(fmaf(s.y, inv, bz.y), 0.f);
  o.z = fmaxf(fmaf(s.z, inv, bz.z), 0.f);
  o.w = fmaxf(fmaf(s.w, inv, bz.w), 0.f);
  *reinterpret_cast<float4*>(&Out[e]) = o;
}

// ---- bf16 MFMA: C = relu(G @ G^T), 128x128 block ----
__global__ __launch_bounds__(256) void k_syrk_mfma(const unsigned short* __restrict__ G,
    int M, int Kd, float* __restrict__ C) {
  __shared__ __align__(16) unsigned short Ai[128 * 40];
  __shared__ __align__(16) unsigned short Bj[128 * 40];
  int tid = threadIdx.x;
  int i0 = blockIdx.y << 7, j0 = blockIdx.x << 7;
  int srow = tid >> 1, scol = (tid & 1) << 3;
  int lane = tid & 63, w = tid >> 6;
  int wr = (w >> 1) << 6, wc = (w & 1) << 6;
  int lr = lane & 15, kb = lane >> 4;
  f32x4 acc[4][4] = {};
  const unsigned short* gA = G + (size_t)i0 * Kd;
  const unsigned short* gB = G + (size_t)j0 * Kd;
  for (int k0 = 0; k0 < Kd; k0 += 32) {
    __syncthreads();
#pragma unroll
    for (int kk = 0; kk < 32; kk += 16) {
      *reinterpret_cast<uint4*>(&Ai[srow * 40 + scol + kk]) =
          *reinterpret_cast<const uint4*>(&gA[(size_t)srow * Kd + k0 + scol + kk]);
      *reinterpret_cast<uint4*>(&Bj[srow * 40 + scol + kk]) =
          *reinterpret_cast<const uint4*>(&gB[(size_t)srow * Kd + k0 + scol + kk]);
    }
    __syncthreads();
    bf16x8 a[4], b[4];
#pragma unroll
    for (int m = 0; m < 4; ++m)
      a[m] = *reinterpret_cast<const bf16x8*>(&Ai[(wr + m * 16 + lr) * 40 + kb * 8]);
#pragma unroll
    for (int n = 0; n < 4; ++n)
      b[n] = *reinterpret_cast<const bf16x8*>(&Bj[(wc + n * 16 + lr) * 40 + kb * 8]);
#pragma unroll
    for (int m = 0; m < 4; ++m)
#pragma unroll
      for (int n = 0; n < 4; ++n)
        acc[m][n] = __builtin_amdgcn_mfma_f32_16x16x32_bf16(a[m], b[n], acc[m][n], 0, 0, 0);
  }
  int orow = i0 + wr + (lane >> 4) * 4;
  int ocol = j0 + wc + (lane & 15);
#pragma unroll
  for (int m = 0; m < 4; ++m)
#pragma unroll
    for (int n = 0; n < 4; ++n)
#pragma unroll
      for (int r = 0; r < 4; ++r)
        C[(size_t)(orow + m * 16 + r) * M + ocol + n * 16] = fmaxf(acc[m][n][r], 0.f);
}

// C[M,N] = A[M,K] @ BT[N,K]^T (+ bias[m] if non-null). bf16 in, f32 out.
__global__ __launch_bounds__(256) void k_gemm_mfma_bt(const unsigned short* __restrict__ Amat,
    const unsigned short* __restrict__ BT, const float* __restrict__ bias,
    float* __restrict__ C, int M, int N, int Kd) {
  __shared__ __align__(16) unsigned short Ai[128 * 40];
  __shared__ __align__(16) unsigned short Bj[128 * 40];
  int tid = threadIdx.x;
  int m0 = blockIdx.y << 7, n0 = blockIdx.x << 7;
  int srow = tid >> 1, scol = (tid & 1) << 3;
  int lane = tid & 63, w = tid >> 6;
  int wr = (w >> 1) << 6, wc = (w & 1) << 6;
  int lr = lane & 15, kb = lane >> 4;
  f32x4 acc[4][4] = {};
  const unsigned short* gA = Amat + (size_t)m0 * Kd;
  const unsigned short* gB = BT + (size_t)n0 * Kd;
  for (int k0 = 0; k0 < Kd; k0 += 32) {
    __syncthreads();
#pragma unroll
    for (int kk = 0; kk < 32; kk += 16) {
      *reinterpret_cast<uint4*>(&Ai[srow * 40 + scol + kk]) =
          *reinterpret_cast<const uint4*>(&gA[(size_t)srow * Kd + k0 + scol + kk]);
      *reinterpret_cast<uint4*>(&Bj[srow * 40 + scol + kk]) =
          *reinterpret_cast<const uint4*>(&gB[(size_t)srow * Kd + k0 + scol + kk]);
    }
    __syncthreads();
    bf16x8 a[4], b[4];
#pragma unroll
    for (int m = 0; m < 4; ++m)
      a[m] = *reinterpret_cast<const bf16x8*>(&Ai[(wr + m * 16 + lr) * 40 + kb * 8]);
#pragma unroll
    for (int n = 0; n < 4; ++n)
      b[n] = *reinterpret_cast<const bf16x8*>(&Bj[(wc + n * 16 + lr) * 40 + kb * 8]);
#pragma unroll
    for (int m = 0; m < 4; ++m)
#pragma unroll
      for (int n = 0; n < 4; ++n)
        acc[m][n] = __builtin_amdgcn_mfma_f32_16x16x32_bf16(a[m], b[n], acc[m][n], 0, 0, 0);
  }
  int orow = m0 + wr + (lane >> 4) * 4;
  int ocol = n0 + wc + (lane & 15);
#pragma unroll
  for (int m = 0; m < 4; ++m)
#pragma unroll
    for (int n = 0; n < 4; ++n)
#pragma unroll
      for (int r = 0; r < 4; ++r) {
        float rb = bias ? bias[orow + m * 16 + r] : 0.f;
        C[(size_t)(orow + m * 16 + r) * N + ocol + n * 16] = acc[m][n][r] + rb;
      }
}

// ---- upsampler GEMM: Pz[kc] = Wup(f32,staged->bf16) @ Xu1T^T, 128x256 tile, split-k ----
__global__ __launch_bounds__(512) void k_gemm_aup(const float* __restrict__ Wg,
    const unsigned short* __restrict__ BT, float* __restrict__ Pz, int Mtot, int Ktot,
    int kc_len) {
  __shared__ __align__(16) unsigned short Ai[128 * 40];
  __shared__ __align__(16) unsigned short Bj[256 * 40];
  int tid = threadIdx.x;
  int m0 = blockIdx.y << 7;
  int k0base = blockIdx.x * kc_len;
  int lane = tid & 63, w = tid >> 6;
  int wr = (w >> 2) << 6, wc = (w & 3) << 6;
  int lr = lane & 15, kb = lane >> 4;
  int ar = tid >> 2, ac8 = (tid & 3) << 3;
  int br = tid >> 1, bc16 = (tid & 1) << 4;
  f32x4 acc[4][4] = {};
  for (int kk = 0; kk < kc_len; kk += 32) {
    int k0 = k0base + kk;
    __syncthreads();
    {
      const float* arow = &Wg[(size_t)(m0 + ar) * Ktot + k0 + ac8];
      float4 v0 = *reinterpret_cast<const float4*>(arow);
      float4 v1 = *reinterpret_cast<const float4*>(arow + 4);
      unsigned short t8[8] = {f2b(v0.x), f2b(v0.y), f2b(v0.z), f2b(v0.w),
                              f2b(v1.x), f2b(v1.y), f2b(v1.z), f2b(v1.w)};
      *reinterpret_cast<uint4*>(&Ai[ar * 40 + ac8]) = *reinterpret_cast<const uint4*>(t8);
      const unsigned short* brow = &BT[(size_t)br * Ktot + k0 + bc16];
      *reinterpret_cast<uint4*>(&Bj[br * 40 + bc16]) = *reinterpret_cast<const uint4*>(brow);
      *reinterpret_cast<uint4*>(&Bj[br * 40 + bc16 + 8]) =
          *reinterpret_cast<const uint4*>(brow + 8);
    }
    __syncthreads();
    bf16x8 a[4], b[4];
#pragma unroll
    for (int m = 0; m < 4; ++m)
      a[m] = *reinterpret_cast<const bf16x8*>(&Ai[(wr + m * 16 + lr) * 40 + kb * 8]);
#pragma unroll
    for (int n = 0; n < 4; ++n)
      b[n] = *reinterpret_cast<const bf16x8*>(&Bj[(wc + n * 16 + lr) * 40 + kb * 8]);
#pragma unroll
    for (int m = 0; m < 4; ++m)
#pragma unroll
      for (int n = 0; n < 4; ++n)
        acc[m][n] = __builtin_amdgcn_mfma_f32_16x16x32_bf16(a[m], b[n], acc[m][n], 0, 0, 0);
  }
  float* outp = Pz + (size_t)blockIdx.x * Mtot * 256;
  int orow = m0 + wr + (lane >> 4) * 4;
  int ocol = wc + (lane & 15);
#pragma unroll
  for (int m = 0; m < 4; ++m)
#pragma unroll
    for (int n = 0; n < 4; ++n)
#pragma unroll
      for (int r = 0; r < 4; ++r)
        outp[(size_t)(orow + m * 16 + r) * 256 + ocol + n * 16] = acc[m][n][r];
}

// row softmax over 256 cols of (sum_c Pz[c] + bias[row]) -> bf16
__global__ __launch_bounds__(256) void k_softmax_fuse(const float* __restrict__ Pz, int nch,
    size_t chstride, const float* __restrict__ bias, unsigned short* __restrict__ ZB) {
  int row = blockIdx.x, tid = threadIdx.x;
  size_t e = (size_t)row * 256 + tid;
  float x = bias[row];
  for (int c = 0; c < nch; ++c) x += Pz[c * chstride + e];
  float m = x;
#pragma unroll
  for (int off = 32; off; off >>= 1) m = fmaxf(m, __shfl_down(m, off));
  __shared__ float red[4];
  __shared__ float bm, bs;
  if ((tid & 63) == 0) red[tid >> 6] = m;
  __syncthreads();
  if (tid == 0) bm = fmaxf(fmaxf(red[0], red[1]), fmaxf(red[2], red[3]));
  __syncthreads();
  float ev = expf(x - bm);
  float sm = wave_sum64(ev);
  __syncthreads();
  if ((tid & 63) == 0) red[tid >> 6] = sm;
  __syncthreads();
  if (tid == 0) bs = red[0] + red[1] + red[2] + red[3];
  __syncthreads();
  ZB[e] = f2b(ev / bs);
}

// src[n,h] = sum_f Xp[n,h,f]*a_src[h,f]; dst likewise.
__global__ void k_src_dst(const float* __restrict__ Xp, const float* __restrict__ a_src,
    const float* __restrict__ a_dst, float* __restrict__ src, float* __restrict__ dst,
    int H, int F) {
  int n = blockIdx.x;
  int h = threadIdx.x >> 6, lane = threadIdx.x & 63;
  const float* x = Xp + ((size_t)n * H + h) * F;
  const float* as = a_src + h * F;
  const float* ad = a_dst + h * F;
  float ps = 0.f, pd = 0.f;
  for (int f = lane; f < F; f += 64) {
    float xv = x[f];
    ps = fmaf(xv, as[f], ps);
    pd = fmaf(xv, ad[f], pd);
  }
  ps = wave_sum64(ps);
  pd = wave_sum64(pd);
  if (lane == 0) { src[n * H + h] = ps; dst[n * H + h] = pd; }
}

// denom[i,h] = sum_j valid(i,j) * exp(lrelu(dst[i,h]+src[j,h]))
__global__ __launch_bounds__(256) void k_att_denom(const float* __restrict__ Adj,
    const float* __restrict__ src, const float* __restrict__ dst, float* __restrict__ denom,
    int N, int H) {
  int i = blockIdx.x, tid = threadIdx.x;
  float di[4];
#pragma unroll
  for (int h = 0; h < 4; ++h) di[h] = (h < H) ? dst[i * H + h] : 0.f;
  float acc[4] = {0.f, 0.f, 0.f, 0.f};
  const float* row = Adj + (size_t)i * N;
  for (int j = tid; j < N; j += 256) {
    float av = row[j];
    if (av != 0.f || j == i) {
#pragma unroll
      for (int h = 0; h < 4; ++h) {
        if (h < H) {
          float t = di[h] + src[j * H + h];
          t = t >= 0.f ? t : 0.2f * t;
          acc[h] += __expf(t);
        }
      }
    }
  }
  __shared__ float red[4][4];
#pragma unroll
  for (int h = 0; h < 4; ++h) acc[h] = wave_sum64(acc[h]);
  if ((tid & 63) == 0) {
#pragma unroll
    for (int h = 0; h < 4; ++h) red[tid >> 6][h] = acc[h];
  }
  __syncthreads();
  if (tid < H) denom[i * H + tid] = red[0][tid] + red[1][tid] + red[2][tid] + red[3][tid];
}

// s[row] = sigmoid(dot(X[row,:], w) + b)
__global__ __launch_bounds__(256) void k_score(const float* __restrict__ Xf,
    const float* __restrict__ wv, const float* __restrict__ bsc, float* __restrict__ s, int D) {
  int row = blockIdx.x * 4 + (threadIdx.x >> 6);
  int lane = threadIdx.x & 63;
  const float* x = Xf + (size_t)row * D;
  float p = 0.f;
  for (int f = lane; f < D; f += 64) p = fmaf(x[f], wv[f], p);
  p = wave_sum64(p);
  if (lane == 0) s[row] = 1.f / (1.f + expf(-(p + bsc[0])));
}

// top-k by exact rank counting. grid = n/256, dyn LDS = n*8 bytes.
__global__ __launch_bounds__(256) void k_topk_rank(const float* __restrict__ s, int n, int k,
    int* __restrict__ idx, float* __restrict__ vals) {
  extern __shared__ unsigned long long keys[];
  int tid = threadIdx.x;
  for (int j = tid; j < n; j += 256) {
    unsigned u = __float_as_uint(s[j]);
    unsigned ord = (u & 0x80000000u) ? ~u : (u | 0x80000000u);
    keys[j] = ((unsigned long long)ord << 32) | (unsigned)(~j);
  }
  __syncthreads();
  int i = blockIdx.x * 256 + tid;
  unsigned long long mykey = keys[i];
  int rank = 0;
#pragma unroll 4
  for (int j = 0; j < n; ++j) rank += (keys[j] > mykey);
  if (rank < k) { idx[rank] = i; vals[rank] = s[i]; }
}

__global__ __launch_bounds__(256) void k_gather_rowsum(const float* __restrict__ Asrc, int lda,
    const int* __restrict__ idx, int k, float* __restrict__ sv) {
  int i = blockIdx.x;
  const float* row = Asrc + (size_t)idx[i] * lda;
  float p = 0.f;
  for (int j = threadIdx.x; j < k; j += 256) p += row[idx[j]];
  p = wave_sum64(p);
  __shared__ float red[4];
  if ((threadIdx.x & 63) == 0) red[threadIdx.x >> 6] = p;
  __syncthreads();
  if (threadIdx.x == 0) sv[i] = 1.f / sqrtf(red[0] + red[1] + red[2] + red[3] + 1e-5f);
}

__global__ void k_symnorm_write(const float* __restrict__ Asrc, int lda,
    const int* __restrict__ idx, const float* __restrict__ sv, float* __restrict__ B, int k) {
  int j = blockIdx.x * 256 + threadIdx.x;
  int i = blockIdx.y;
  B[(size_t)i * k + j] = Asrc[(size_t)idx[i] * lda + idx[j]] * sv[i] * sv[j];
}

__global__ void k_gather_mat(const float* __restrict__ Asrc, int lda,
    const int* __restrict__ idx, float* __restrict__ B, int k) {
  int j = blockIdx.x * 256 + threadIdx.x;
  int i = blockIdx.y;
  B[(size_t)i * k + j] = Asrc[(size_t)idx[i] * lda + idx[j]];
}

__global__ void k_gather_scale_rows(const float* __restrict__ Xs, int D,
    const int* __restrict__ idx, const float* __restrict__ v, float* __restrict__ Xo) {
  int f = blockIdx.x * 256 + threadIdx.x;
  int i = blockIdx.y;
  Xo[(size_t)i * D + f] = Xs[(size_t)idx[i] * D + f] * v[i];
}

__global__ void k_scatter_rows(const float* __restrict__ P, int D, const int* __restrict__ idx,
                               float* __restrict__ Xo) {
  int f = blockIdx.x * 256 + threadIdx.x;
  int i = blockIdx.y;
  Xo[(size_t)idx[i] * D + f] = P[(size_t)i * D + f];
}

extern "C" void kernel_launch(void* const* d_in, const int* in_sizes, int n_in,
                              void* d_out, int out_size, void* d_ws, size_t ws_size,
                              hipStream_t stream) {
  const float* A    = (const float*)d_in[0];
  const float* X    = (const float*)d_in[1];
  const float* Wd0  = (const float*)d_in[2];
  const float* asd0 = (const float*)d_in[3];
  const float* add0 = (const float*)d_in[4];
  const float* bd0  = (const float*)d_in[5];
  const float* Wd1  = (const float*)d_in[6];
  const float* asd1 = (const float*)d_in[7];
  const float* add1 = (const float*)d_in[8];
  const float* bd1  = (const float*)d_in[9];
  const float* wp0  = (const float*)d_in[10];
  const float* bp0  = (const float*)d_in[11];
  const float* wp1  = (const float*)d_in[12];
  const float* bp1  = (const float*)d_in[13];
  const float* Wb   = (const float*)d_in[14];
  const float* asb  = (const float*)d_in[15];
  const float* adb  = (const float*)d_in[16];
  const float* bb   = (const float*)d_in[17];
  const float* Wu0  = (const float*)d_in[18];
  const float* asu0 = (const float*)d_in[19];
  const float* adu0 = (const float*)d_in[20];
  const float* bu0  = (const float*)d_in[21];
  const float* Wu1  = (const float*)d_in[22];
  const float* asu1 = (const float*)d_in[23];
  const float* adu1 = (const float*)d_in[24];
  const float* bu1  = (const float*)d_in[25];
  const float* Wup  = (const float*)d_in[26];
  const float* bup  = (const float*)d_in[27];
  (void)in_sizes; (void)n_in; (void)out_size; (void)ws_size;

  float* out  = (float*)d_out;
  float* Aup  = out;                    // [8192*8192]
  float* A0   = out + 67108864ULL;      // [4096*4096]
  float* A1   = A0 + 16777216ULL;       // [2048*2048]
  float* rec0 = A1 + 4194304ULL;        // [2048*2048]
  float* rec1 = rec0 + 4194304ULL;      // [4096*4096]

  // Scratch in the A_up output region (dead before A_up syrk writes).
  float* S = Aup;
  size_t off = 0;
  auto nxt = [&](size_t n) { float* p = S + off; off += (n + 1023) & ~(size_t)1023; return p; };
  float* Xp0  = nxt(4096 * 512);
  float* X0   = nxt(4096 * 512);
  float* src0 = nxt(4096 * 4);
  float* dst0 = nxt(4096 * 4);
  float* den0 = nxt(4096 * 4);
  float* sc0  = nxt(4096);
  int*   idx0 = (int*)nxt(2048);
  float* v0   = nxt(2048);
  float* sv0  = nxt(2048);
  float* X1in = nxt(2048 * 512);
  float* Xp1  = nxt(2048 * 1024);
  float* X1   = nxt(2048 * 1024);
  float* src1 = nxt(2048 * 4);
  float* dst1 = nxt(2048 * 4);
  float* den1 = nxt(2048 * 4);
  float* sc1  = nxt(2048);
  int*   idx1 = (int*)nxt(1024);
  float* v1   = nxt(1024);
  float* A2m  = nxt(1024 * 1024);
  float* X2in = nxt(1024 * 1024);
  float* Xpb  = nxt(1024 * 1024);
  float* Xb   = nxt(1024 * 1024);
  float* srcb = nxt(1024 * 2);
  float* dstb = nxt(1024 * 2);
  float* denb = nxt(1024 * 2);
  float* Pu0  = nxt(1024 * 512);
  float* Xpu0 = nxt(2048 * 512);
  float* Xu0  = nxt(2048 * 512);
  float* su0  = nxt(2048 * 4);
  float* du0  = nxt(2048 * 4);
  float* dn0  = nxt(2048 * 4);
  float* Pu1  = nxt(2048 * 256);
  float* Xpu1 = nxt(4096 * 256);
  float* su1  = nxt(4096 * 4);
  float* du1  = nxt(4096 * 4);
  float* dn1  = nxt(4096 * 4);
  float* P    = nxt((size_t)8 * 4096 * 512);               // split-j partials
  unsigned short* XpS  = (unsigned short*)nxt(3200000);    // 3 planes [H][F][N] bf16 (12.6MB)
  unsigned short* XpT  = (unsigned short*)nxt(524288);     // [H][F][N] bf16 (single plane)
  unsigned short* X2inB = (unsigned short*)nxt(524288);
  unsigned short* XbB   = (unsigned short*)nxt(524288);
  unsigned short* WbT   = (unsigned short*)nxt(524288);
  unsigned short* Wu0T  = (unsigned short*)nxt(262144);
  unsigned short* Wu1T  = (unsigned short*)nxt(65536);

  // d_ws: final-stage-live buffers
  float* W = (float*)d_ws;
  float* Xu1 = W;                                               // 4096*256 f32
  unsigned short* Xu1B = (unsigned short*)(W + 1048576);        // 4096*256 bf16
  unsigned short* Xu0B = (unsigned short*)(W + 1048576 + 524288);  // 2048*512 bf16

  // rec1 output region as late scratch (dead before rec1 syrk writes)
  float* Pz = rec1;                                             // 4 x 8192*256 f32 (32 MB)
  unsigned short* ZB = (unsigned short*)(rec1 + 4 * 2097152);   // 8192*256 bf16
  unsigned short* Xu1T = (unsigned short*)(rec1 + 4 * 2097152 + 1048576);  // 256*4096 bf16

  const size_t PS0 = (size_t)4 * 128 * 4096;  // plane stride GAT0
  const size_t PS1 = (size_t)4 * 256 * 2048;  // plane stride GAT1

  // ---- A0 = A + I ----
  k_add_eye<<<16384, 256, 0, stream>>>(A, A0);

  // ---- down level 0: GAT(256 -> 4x128), bf16x6 split MFMA ----
  k_gemm_nn<<<dim3(8, 64), 256, 0, stream>>>(X, Wd0, Xp0, 4096, 512, 256, nullptr);
  k_src_dst<<<4096, 256, 0, stream>>>(Xp0, asd0, add0, src0, dst0, 4, 128);
  k_att_denom<<<4096, 256, 0, stream>>>(A0, src0, dst0, den0, 4096, 4);
  k_transpose_split<<<dim3(2, 64, 4), 256, 0, stream>>>(Xp0, 512, 128, XpS, 4096, PS0);
  k_gat_x6<<<dim3(8, 32, 4), 256, 0, stream>>>(A0, 4096, XpS, PS0, src0, dst0, P, 512, 128,
                                               1024);
  k_gat_reduce<<<2048, 256, 0, stream>>>(P, 4, (size_t)4096 * 512, den0, bd0, X0, 512, 128,
                                         4096 * 512);
  k_score<<<1024, 256, 0, stream>>>(X0, wp0, bp0, sc0, 512);
  k_topk_rank<<<16, 256, 4096 * 8, stream>>>(sc0, 4096, 2048, idx0, v0);
  k_gather_rowsum<<<2048, 256, 0, stream>>>(A0, 4096, idx0, 2048, sv0);
  k_symnorm_write<<<dim3(8, 2048), 256, 0, stream>>>(A0, 4096, idx0, sv0, A1, 2048);
  k_gather_scale_rows<<<dim3(2, 2048), 256, 0, stream>>>(X0, 512, idx0, v0, X1in);

  // ---- down level 1: GAT(512 -> 4x256), bf16x6 split MFMA ----
  k_gemm_nn<<<dim3(16, 32), 256, 0, stream>>>(X1in, Wd1, Xp1, 2048, 1024, 512, nullptr);
  k_src_dst<<<2048, 256, 0, stream>>>(Xp1, asd1, add1, src1, dst1, 4, 256);
  k_att_denom<<<2048, 256, 0, stream>>>(A1, src1, dst1, den1, 2048, 4);
  k_transpose_split<<<dim3(4, 32, 4), 256, 0, stream>>>(Xp1, 1024, 256, XpS, 2048, PS1);
  k_gat_x6<<<dim3(16, 16, 4), 256, 0, stream>>>(A1, 2048, XpS, PS1, src1, dst1, P, 1024, 256,
                                                512);
  k_gat_reduce<<<2048, 256, 0, stream>>>(P, 4, (size_t)2048 * 1024, den1, bd1, X1, 1024, 256,
                                         2048 * 1024);
  k_score<<<512, 256, 0, stream>>>(X1, wp1, bp1, sc1, 1024);
  k_topk_rank<<<8, 256, 2048 * 8, stream>>>(sc1, 2048, 1024, idx1, v1);
  k_gather_mat<<<dim3(4, 1024), 256, 0, stream>>>(A1, 2048, idx1, A2m, 1024);
  k_gather_scale_rows<<<dim3(4, 1024), 256, 0, stream>>>(X1, 1024, idx1, v1, X2in);

  // ---- bottom: GAT(1024 -> 2x512), bf16 MFMA ----
  k_f32_to_bf16<<<1024, 256, 0, stream>>>(X2in, X2inB, 1024 * 1024);
  k_transpose_bf16<<<dim3(16, 16), 256, 0, stream>>>(Wb, 1024, WbT, 1024, 1024);
  k_gemm_mfma_bt<<<dim3(8, 8), 256, 0, stream>>>(X2inB, WbT, nullptr, Xpb, 1024, 1024, 1024);
  k_src_dst<<<1024, 128, 0, stream>>>(Xpb, asb, adb, srcb, dstb, 2, 512);
  k_att_denom<<<1024, 256, 0, stream>>>(A2m, srcb, dstb, denb, 1024, 2);
  for (int h = 0; h < 2; ++h)
    k_transpose_bf16<<<dim3(8, 16), 256, 0, stream>>>(Xpb + h * 512, 1024,
                                                      XpT + (size_t)h * 512 * 1024, 1024, 512);
  k_gat_mfma<<<dim3(16, 4, 8), 256, 0, stream>>>(A2m, 1024, XpT, srcb, dstb, P, 1024, 512, 128);
  k_gat_reduce<<<1024, 256, 0, stream>>>(P, 8, (size_t)1024 * 1024, denb, bb, Xb, 1024, 512,
                                         1024 * 1024);

  // ---- up level 0: unpool -> GAT(1024 -> 4x128) over A1, bf16 MFMA ----
  k_f32_to_bf16<<<1024, 256, 0, stream>>>(Xb, XbB, 1024 * 1024);
  k_transpose_bf16<<<dim3(8, 16), 256, 0, stream>>>(Wu0, 512, Wu0T, 1024, 512);
  k_gemm_mfma_bt<<<dim3(4, 8), 256, 0, stream>>>(XbB, Wu0T, nullptr, Pu0, 1024, 512, 1024);
  k_fill0<<<1024, 256, 0, stream>>>(Xpu0, 2048 * 512);
  k_scatter_rows<<<dim3(2, 1024), 256, 0, stream>>>(Pu0, 512, idx1, Xpu0);
  k_src_dst<<<2048, 256, 0, stream>>>(Xpu0, asu0, adu0, su0, du0, 4, 128);
  k_att_denom<<<2048, 256, 0, stream>>>(A1, su0, du0, dn0, 2048, 4);
  for (int h = 0; h < 4; ++h)
    k_transpose_bf16<<<dim3(2, 32), 256, 0, stream>>>(Xpu0 + h * 128, 512,
                                                      XpT + (size_t)h * 128 * 2048, 2048, 128);
  k_gat_mfma<<<dim3(8, 8, 8), 256, 0, stream>>>(A1, 2048, XpT, su0, du0, P, 512, 128, 256);
  k_gat_reduce<<<1024, 256, 0, stream>>>(P, 8, (size_t)2048 * 512, dn0, bu0, Xu0, 512, 128,
                                         2048 * 512);
  k_f32_to_bf16<<<1024, 256, 0, stream>>>(Xu0, Xu0B, 2048 * 512);

  // ---- up level 1: unpool -> GAT(512 -> 4x64) over A0, bf16 MFMA ----
  k_transpose_bf16<<<dim3(4, 8), 256, 0, stream>>>(Wu1, 256, Wu1T, 512, 256);
  k_gemm_mfma_bt<<<dim3(2, 16), 256, 0, stream>>>(Xu0B, Wu1T, nullptr, Pu1, 2048, 256, 512);
  k_fill0<<<1024, 256, 0, stream>>>(Xpu1, 4096 * 256);
  k_scatter_rows<<<dim3(1, 2048), 256, 0, stream>>>(Pu1, 256, idx0, Xpu1);
  k_src_dst<<<4096, 256, 0, stream>>>(Xpu1, asu1, adu1, su1, du1, 4, 64);
  k_att_denom<<<4096, 256, 0, stream>>>(A0, su1, du1, dn1, 4096, 4);
  for (int h = 0; h < 4; ++h)
    k_transpose_bf16<<<dim3(1, 64), 256, 0, stream>>>(Xpu1 + h * 64, 256,
                                                      XpT + (size_t)h * 64 * 4096, 4096, 64);
  k_gat_mfma<<<dim3(4, 16, 8), 256, 0, stream>>>(A0, 4096, XpT, su1, du1, P, 256, 64, 512);
  k_gat_reduce<<<1024, 256, 0, stream>>>(P, 8, (size_t)4096 * 256, dn1, bu1, Xu1, 256, 64,
                                         4096 * 256);
  k_f32_to_bf16<<<1024, 256, 0, stream>>>(Xu1, Xu1B, 4096 * 256);
  k_transpose_bf16<<<dim3(4, 64), 256, 0, stream>>>(Xu1, 256, Xu1T, 4096, 256);

  // ---- upsampler: split-k GEMM (fused f32->bf16 A staging) + fused softmax ----
  k_gemm_aup<<<dim3(4, 64), 512, 0, stream>>>(Wup, Xu1T, Pz, 8192, 4096, 1024);
  k_softmax_fuse<<<8192, 256, 0, stream>>>(Pz, 4, (size_t)8192 * 256, bup, ZB);
  k_syrk_mfma<<<dim3(64, 64), 256, 0, stream>>>(ZB, 8192, 256, Aup);

  // ---- reconstructions ----
  k_syrk_mfma<<<dim3(32, 32), 256, 0, stream>>>(Xu1B, 4096, 256, rec1);
  k_syrk_mfma<<<dim3(16, 16), 256, 0, stream>>>(Xu0B, 2048, 512, rec0);
}

// Round 6
// 1242.445 us; speedup vs baseline: 2.1748x; 1.0403x over previous
//
#include <hip/hip_runtime.h>
#include <math.h>

// ---------------------------------------------------------------------------
// Graph U-Net forward on MI355X.
// Ordering-critical math (down path) = bf16x6 split MFMA (~3e-8 rel err).
// Non-ordering layers = plain bf16 MFMA. All gathers coalesced via transpose.
// ---------------------------------------------------------------------------

typedef short bf16x8 __attribute__((ext_vector_type(8)));
typedef float f32x4 __attribute__((ext_vector_type(4)));

static __device__ __forceinline__ float wave_sum64(float v) {
#pragma unroll
  for (int off = 32; off; off >>= 1) v += __shfl_down(v, off);
  return v;
}

static __device__ __forceinline__ unsigned short f2b(float x) {
  unsigned u = __float_as_uint(x);
  unsigned r = (u + 0x7fffu + ((u >> 16) & 1u)) >> 16;
  return (unsigned short)r;
}

static __device__ __forceinline__ float b2f(unsigned short h) {
  return __uint_as_float(((unsigned)h) << 16);
}

// A0 = A + I  (4096x4096), float4
__global__ void k_add_eye(const float* __restrict__ A, float* __restrict__ O) {
  size_t i = ((size_t)blockIdx.x * 256 + threadIdx.x) * 4;
  size_t r = i >> 12, c = i & 4095;
  float4 v = *reinterpret_cast<const float4*>(&A[i]);
  if (r >= c && r < c + 4) ((float*)&v)[r - c] += 1.f;
  *reinterpret_cast<float4*>(&O[i]) = v;
}

__global__ void k_fill0(float* __restrict__ p, int n) {
  int stride = gridDim.x * 256;
  for (int i = blockIdx.x * 256 + threadIdx.x; i < n; i += stride) p[i] = 0.f;
}

__global__ void k_scatter_ones(const int* __restrict__ idx, float* __restrict__ m, int k) {
  int i = blockIdx.x * 256 + threadIdx.x;
  if (i < k) m[idx[i]] = 1.f;
}

__global__ void k_f32_to_bf16(const float* __restrict__ S, unsigned short* __restrict__ D,
                              int n) {
  int stride = gridDim.x * 1024;
  for (int i = (blockIdx.x * 256 + threadIdx.x) * 4; i < n; i += stride) {
    float4 v = *reinterpret_cast<const float4*>(&S[i]);
    uint2 o;
    o.x = (unsigned)f2b(v.x) | ((unsigned)f2b(v.y) << 16);
    o.y = (unsigned)f2b(v.z) | ((unsigned)f2b(v.w) << 16);
    *reinterpret_cast<uint2*>(&D[i]) = o;
  }
}

// row-major 3-plane bf16 split: D[p*PS + i] = split_p(S[i])
__global__ void k_split3(const float* __restrict__ S, unsigned short* __restrict__ D,
                         size_t PS, int n) {
  int stride = gridDim.x * 1024;
  for (int i = (blockIdx.x * 256 + threadIdx.x) * 4; i < n; i += stride) {
    float4 v = *reinterpret_cast<const float4*>(&S[i]);
    float xv[4] = {v.x, v.y, v.z, v.w};
    unsigned short o1[4], o2[4], o3[4];
#pragma unroll
    for (int e = 0; e < 4; ++e) {
      float x = xv[e];
      unsigned short a = f2b(x);
      float r1 = x - b2f(a);
      unsigned short b = f2b(r1);
      float r2 = r1 - b2f(b);
      o1[e] = a; o2[e] = b; o3[e] = f2b(r2);
    }
    *reinterpret_cast<uint2*>(&D[i]) = *reinterpret_cast<const uint2*>(o1);
    *reinterpret_cast<uint2*>(&D[PS + i]) = *reinterpret_cast<const uint2*>(o2);
    *reinterpret_cast<uint2*>(&D[2 * PS + i]) = *reinterpret_cast<const uint2*>(o3);
  }
}

// D[c][r] = bf16(S[r*ldS + c]); S has R rows, Cc cols; D is [Cc][R].
__global__ __launch_bounds__(256) void k_transpose_bf16(const float* __restrict__ S, int ldS,
    unsigned short* __restrict__ D, int R, int Cc) {
  __shared__ unsigned short T[64][72];
  int r0 = blockIdx.y << 6, c0 = blockIdx.x << 6;
  int tid = threadIdx.x;
  int tr = tid >> 4, tc4 = (tid & 15) << 2;
#pragma unroll
  for (int q = 0; q < 4; ++q) {
    int row = tr + q * 16;
    float4 v = *reinterpret_cast<const float4*>(&S[(size_t)(r0 + row) * ldS + c0 + tc4]);
    T[tc4 + 0][row] = f2b(v.x);
    T[tc4 + 1][row] = f2b(v.y);
    T[tc4 + 2][row] = f2b(v.z);
    T[tc4 + 3][row] = f2b(v.w);
  }
  __syncthreads();
#pragma unroll
  for (int q = 0; q < 4; ++q) {
    int row = tr + q * 16;
    *reinterpret_cast<uint2*>(&D[(size_t)(c0 + row) * R + r0 + tc4]) =
        *reinterpret_cast<const uint2*>(&T[row][tc4]);
  }
}

// 3-way bf16 split + transpose: D[p*PS + (h*F + c)*R + r] = split_p(S[r*ldS + h*F + c]).
__global__ __launch_bounds__(256) void k_transpose_split(const float* __restrict__ S, int ldS,
    int F, unsigned short* __restrict__ D, int R, size_t PS) {
  __shared__ unsigned short T[3][64][72];
  int h = blockIdx.z;
  int c0 = blockIdx.x << 6, r0 = blockIdx.y << 6;
  int tid = threadIdx.x;
  int tr = tid >> 4, tc4 = (tid & 15) << 2;
#pragma unroll
  for (int q = 0; q < 4; ++q) {
    int row = tr + q * 16;
    float4 v = *reinterpret_cast<const float4*>(&S[(size_t)(r0 + row) * ldS + h * F + c0 + tc4]);
    float xv[4] = {v.x, v.y, v.z, v.w};
#pragma unroll
    for (int e = 0; e < 4; ++e) {
      float x = xv[e];
      unsigned short h1 = f2b(x);
      float r1 = x - b2f(h1);
      unsigned short h2 = f2b(r1);
      float r2 = r1 - b2f(h2);
      T[0][tc4 + e][row] = h1;
      T[1][tc4 + e][row] = h2;
      T[2][tc4 + e][row] = f2b(r2);
    }
  }
  __syncthreads();
#pragma unroll
  for (int p = 0; p < 3; ++p)
#pragma unroll
    for (int q = 0; q < 4; ++q) {
      int row = tr + q * 16;
      *reinterpret_cast<uint2*>(&D[p * PS + (size_t)(h * F + c0 + row) * R + r0 + tc4]) =
          *reinterpret_cast<const uint2*>(&T[p][row][tc4]);
    }
}

// ---- bf16x6 GEMM: C[M,N] = A @ BT^T from 3-plane splits. 128x128 block. ----
__global__ __launch_bounds__(256, 2) void k_gemm_x6_bt(const unsigned short* __restrict__ As,
    size_t APS, const unsigned short* __restrict__ BTs, size_t BPS, float* __restrict__ C,
    int M, int N, int K) {
  __shared__ __align__(16) unsigned short Ai[3][128 * 40];
  __shared__ __align__(16) unsigned short Bj[3][128 * 40];
  int tid = threadIdx.x;
  int m0 = blockIdx.y << 7, n0 = blockIdx.x << 7;
  int lane = tid & 63, w = tid >> 6;
  int lr = lane & 15, kb = lane >> 4;
  int wr = (w >> 1) << 6, wc = (w & 1) << 6;
  int sr = tid >> 1, sc = (tid & 1) << 4;
  f32x4 acc[4][4] = {};
  for (int k0 = 0; k0 < K; k0 += 32) {
    __syncthreads();
#pragma unroll
    for (int p = 0; p < 3; ++p) {
      const unsigned short* ga = &As[p * APS + (size_t)(m0 + sr) * K + k0 + sc];
      *reinterpret_cast<uint4*>(&Ai[p][sr * 40 + sc]) = *reinterpret_cast<const uint4*>(ga);
      *reinterpret_cast<uint4*>(&Ai[p][sr * 40 + sc + 8]) =
          *reinterpret_cast<const uint4*>(ga + 8);
      const unsigned short* gb = &BTs[p * BPS + (size_t)(n0 + sr) * K + k0 + sc];
      *reinterpret_cast<uint4*>(&Bj[p][sr * 40 + sc]) = *reinterpret_cast<const uint4*>(gb);
      *reinterpret_cast<uint4*>(&Bj[p][sr * 40 + sc + 8]) =
          *reinterpret_cast<const uint4*>(gb + 8);
    }
    __syncthreads();
    bf16x8 af[4][3], bf_[4][3];
#pragma unroll
    for (int m = 0; m < 4; ++m)
#pragma unroll
      for (int p = 0; p < 3; ++p)
        af[m][p] = *reinterpret_cast<const bf16x8*>(&Ai[p][(wr + m * 16 + lr) * 40 + kb * 8]);
#pragma unroll
    for (int n = 0; n < 4; ++n)
#pragma unroll
      for (int p = 0; p < 3; ++p)
        bf_[n][p] = *reinterpret_cast<const bf16x8*>(&Bj[p][(wc + n * 16 + lr) * 40 + kb * 8]);
#pragma unroll
    for (int m = 0; m < 4; ++m)
#pragma unroll
      for (int n = 0; n < 4; ++n) {
        acc[m][n] = __builtin_amdgcn_mfma_f32_16x16x32_bf16(af[m][0], bf_[n][0], acc[m][n], 0, 0, 0);
        acc[m][n] = __builtin_amdgcn_mfma_f32_16x16x32_bf16(af[m][0], bf_[n][1], acc[m][n], 0, 0, 0);
        acc[m][n] = __builtin_amdgcn_mfma_f32_16x16x32_bf16(af[m][1], bf_[n][0], acc[m][n], 0, 0, 0);
        acc[m][n] = __builtin_amdgcn_mfma_f32_16x16x32_bf16(af[m][0], bf_[n][2], acc[m][n], 0, 0, 0);
        acc[m][n] = __builtin_amdgcn_mfma_f32_16x16x32_bf16(af[m][2], bf_[n][0], acc[m][n], 0, 0, 0);
        acc[m][n] = __builtin_amdgcn_mfma_f32_16x16x32_bf16(af[m][1], bf_[n][1], acc[m][n], 0, 0, 0);
      }
  }
  int orow = m0 + wr + (lane >> 4) * 4;
  int ocol = n0 + wc + lr;
#pragma unroll
  for (int m = 0; m < 4; ++m)
#pragma unroll
    for (int n = 0; n < 4; ++n)
#pragma unroll
      for (int r = 0; r < 4; ++r)
        C[(size_t)(orow + m * 16 + r) * N + ocol + n * 16] = acc[m][n][r];
}

// ---- bf16x6 split-MFMA GAT aggregation v2: 128i x 128f block, wave = 64x64 ----
// grid: (h*(F/128)+ft, N/128, JC). P[chunk][N][HF] partials.
__global__ __launch_bounds__(256, 2) void k_gat_x6(const float* __restrict__ Adj, int N,
    const unsigned short* __restrict__ XpS, size_t PS,
    const float* __restrict__ src, const float* __restrict__ dst,
    float* __restrict__ P, int HF, int F, int jchunk) {
  __shared__ __align__(16) unsigned short wB[3][128 * 40];
  __shared__ __align__(16) unsigned short xB[3][128 * 40];
  int ftiles = F >> 7;
  int h = blockIdx.x / ftiles;
  int f0 = (blockIdx.x % ftiles) << 7;
  int H = HF / F;
  int i0 = blockIdx.y << 7;
  int jb0 = blockIdx.z * jchunk;
  int tid = threadIdx.x;
  int lane = tid & 63, w = tid >> 6;
  int lr = lane & 15, kb = lane >> 4;
  int wr = (w >> 1) << 6, wf = (w & 1) << 6;
  int sj4 = (tid & 7) << 2, si = tid >> 3;
  int xf = tid >> 1, xj8 = (tid & 1) << 3;
  float di[4];
#pragma unroll
  for (int q = 0; q < 4; ++q) di[q] = dst[(i0 + si + q * 32) * H + h];
  const unsigned short* xg = XpS + ((size_t)h * F + f0 + xf) * N;

  float4 aw[4];
  float s4[4];
  uint4 xv[3][2];
  {
#pragma unroll
    for (int e = 0; e < 4; ++e) s4[e] = src[(jb0 + sj4 + e) * H + h];
#pragma unroll
    for (int q = 0; q < 4; ++q)
      aw[q] = *reinterpret_cast<const float4*>(&Adj[(size_t)(i0 + si + q * 32) * N + jb0 + sj4]);
#pragma unroll
    for (int p = 0; p < 3; ++p) {
      xv[p][0] = *reinterpret_cast<const uint4*>(&xg[p * PS + jb0 + xj8]);
      xv[p][1] = *reinterpret_cast<const uint4*>(&xg[p * PS + jb0 + xj8 + 16]);
    }
  }

  f32x4 acc[4][4] = {};
  int ntiles = jchunk >> 5;
  for (int t = 0; t < ntiles; ++t) {
    int jb = jb0 + (t << 5);
    // truncation 3-way split of w (w >= 0 so truncation residuals stay >= 0)
    uint2 wp[4][3];
#pragma unroll
    for (int q = 0; q < 4; ++q) {
      int gi = i0 + si + q * 32;
      float dq = di[q];
      const float* a = (const float*)&aw[q];
      unsigned short h1[4], h2[4], h3[4];
#pragma unroll
      for (int e = 0; e < 4; ++e) {
        float wv = 0.f;
        if (a[e] != 0.f || (jb + sj4 + e) == gi) {
          float tt = dq + s4[e];
          tt = tt >= 0.f ? tt : 0.2f * tt;
          wv = __expf(tt);
        }
        unsigned u1 = __float_as_uint(wv);
        h1[e] = (unsigned short)(u1 >> 16);
        float r1 = wv - __uint_as_float(u1 & 0xffff0000u);
        unsigned u2 = __float_as_uint(r1);
        h2[e] = (unsigned short)(u2 >> 16);
        float r2 = r1 - __uint_as_float(u2 & 0xffff0000u);
        h3[e] = (unsigned short)(__float_as_uint(r2) >> 16);
      }
      wp[q][0].x = (unsigned)h1[0] | ((unsigned)h1[1] << 16);
      wp[q][0].y = (unsigned)h1[2] | ((unsigned)h1[3] << 16);
      wp[q][1].x = (unsigned)h2[0] | ((unsigned)h2[1] << 16);
      wp[q][1].y = (unsigned)h2[2] | ((unsigned)h2[3] << 16);
      wp[q][2].x = (unsigned)h3[0] | ((unsigned)h3[1] << 16);
      wp[q][2].y = (unsigned)h3[2] | ((unsigned)h3[3] << 16);
    }
    __syncthreads();
#pragma unroll
    for (int q = 0; q < 4; ++q)
#pragma unroll
      for (int p = 0; p < 3; ++p)
        *reinterpret_cast<uint2*>(&wB[p][(si + q * 32) * 40 + sj4]) = wp[q][p];
#pragma unroll
    for (int p = 0; p < 3; ++p) {
      *reinterpret_cast<uint4*>(&xB[p][xf * 40 + xj8]) = xv[p][0];
      *reinterpret_cast<uint4*>(&xB[p][xf * 40 + xj8 + 16]) = xv[p][1];
    }
    __syncthreads();
    if (t + 1 < ntiles) {
      int jn = jb + 32;
#pragma unroll
      for (int e = 0; e < 4; ++e) s4[e] = src[(jn + sj4 + e) * H + h];
#pragma unroll
      for (int q = 0; q < 4; ++q)
        aw[q] = *reinterpret_cast<const float4*>(&Adj[(size_t)(i0 + si + q * 32) * N + jn + sj4]);
#pragma unroll
      for (int p = 0; p < 3; ++p) {
        xv[p][0] = *reinterpret_cast<const uint4*>(&xg[p * PS + jn + xj8]);
        xv[p][1] = *reinterpret_cast<const uint4*>(&xg[p * PS + jn + xj8 + 16]);
      }
    }
    bf16x8 af[4][3], bf_[4][3];
#pragma unroll
    for (int m = 0; m < 4; ++m)
#pragma unroll
      for (int p = 0; p < 3; ++p)
        af[m][p] = *reinterpret_cast<const bf16x8*>(&wB[p][(wr + m * 16 + lr) * 40 + kb * 8]);
#pragma unroll
    for (int n = 0; n < 4; ++n)
#pragma unroll
      for (int p = 0; p < 3; ++p)
        bf_[n][p] = *reinterpret_cast<const bf16x8*>(&xB[p][(wf + n * 16 + lr) * 40 + kb * 8]);
#pragma unroll
    for (int m = 0; m < 4; ++m)
#pragma unroll
      for (int n = 0; n < 4; ++n) {
        acc[m][n] = __builtin_amdgcn_mfma_f32_16x16x32_bf16(af[m][0], bf_[n][0], acc[m][n], 0, 0, 0);
        acc[m][n] = __builtin_amdgcn_mfma_f32_16x16x32_bf16(af[m][0], bf_[n][1], acc[m][n], 0, 0, 0);
        acc[m][n] = __builtin_amdgcn_mfma_f32_16x16x32_bf16(af[m][1], bf_[n][0], acc[m][n], 0, 0, 0);
        acc[m][n] = __builtin_amdgcn_mfma_f32_16x16x32_bf16(af[m][0], bf_[n][2], acc[m][n], 0, 0, 0);
        acc[m][n] = __builtin_amdgcn_mfma_f32_16x16x32_bf16(af[m][2], bf_[n][0], acc[m][n], 0, 0, 0);
        acc[m][n] = __builtin_amdgcn_mfma_f32_16x16x32_bf16(af[m][1], bf_[n][1], acc[m][n], 0, 0, 0);
      }
  }
  float* Pc = P + (size_t)blockIdx.z * N * HF;
  int orow = i0 + wr + (lane >> 4) * 4;
  int ocol = h * F + f0 + wf + lr;
#pragma unroll
  for (int m = 0; m < 4; ++m)
#pragma unroll
    for (int n = 0; n < 4; ++n)
#pragma unroll
      for (int r = 0; r < 4; ++r)
        Pc[(size_t)(orow + m * 16 + r) * HF + ocol + n * 16] = acc[m][n][r];
}

// ---- bf16 MFMA GAT aggregation (non-ordering layers): 256x64 tile ----
__global__ __launch_bounds__(256) void k_gat_mfma(const float* __restrict__ Adj, int N,
    const unsigned short* __restrict__ XpT,
    const float* __restrict__ src, const float* __restrict__ dst,
    float* __restrict__ P, int HF, int F, int jchunk) {
  __shared__ __align__(16) unsigned short wL[256][40];
  __shared__ __align__(16) unsigned short xT[64][40];
  __shared__ float dsl[256];
  int ftiles = F >> 6;
  int h = blockIdx.x / ftiles;
  int f0 = (blockIdx.x % ftiles) << 6;
  int H = HF / F;
  int i0 = blockIdx.y << 8;
  int jb0 = blockIdx.z * jchunk;
  int tid = threadIdx.x;
  int lane = tid & 63, w = tid >> 6;
  int lr = lane & 15, kb = lane >> 4;
  dsl[tid] = dst[(i0 + tid) * H + h];
  int sj4 = (tid & 7) << 2;
  int si = tid >> 3;
  int xf = tid >> 2;
  int xj8 = (tid & 3) << 3;
  const unsigned short* xg = XpT + ((size_t)h * F + f0 + xf) * N;
  f32x4 acc[4][4] = {};
  for (int jb = jb0; jb < jb0 + jchunk; jb += 32) {
    __syncthreads();
    float s4[4];
#pragma unroll
    for (int e = 0; e < 4; ++e) s4[e] = src[(jb + sj4 + e) * H + h];
#pragma unroll
    for (int q = 0; q < 8; ++q) {
      int i = si + q * 32;
      int gi = i0 + i;
      float4 av = *reinterpret_cast<const float4*>(&Adj[(size_t)gi * N + jb + sj4]);
      float di = dsl[i];
      float vv[4] = {av.x, av.y, av.z, av.w};
      unsigned short wb[4];
#pragma unroll
      for (int e = 0; e < 4; ++e) {
        float wv = 0.f;
        if (vv[e] != 0.f || (jb + sj4 + e) == gi) {
          float t = di + s4[e];
          t = t >= 0.f ? t : 0.2f * t;
          wv = __expf(t);
        }
        wb[e] = f2b(wv);
      }
      *reinterpret_cast<uint2*>(&wL[i][sj4]) = *reinterpret_cast<const uint2*>(wb);
    }
    *reinterpret_cast<uint4*>(&xT[xf][xj8]) = *reinterpret_cast<const uint4*>(&xg[jb + xj8]);
    __syncthreads();
    bf16x8 a[4], b[4];
#pragma unroll
    for (int m = 0; m < 4; ++m)
      a[m] = *reinterpret_cast<const bf16x8*>(&wL[w * 64 + m * 16 + lr][kb * 8]);
#pragma unroll
    for (int n = 0; n < 4; ++n)
      b[n] = *reinterpret_cast<const bf16x8*>(&xT[n * 16 + lr][kb * 8]);
#pragma unroll
    for (int m = 0; m < 4; ++m)
#pragma unroll
      for (int n = 0; n < 4; ++n)
        acc[m][n] = __builtin_amdgcn_mfma_f32_16x16x32_bf16(a[m], b[n], acc[m][n], 0, 0, 0);
  }
  float* Pc = P + (size_t)blockIdx.z * N * HF;
  int orow = i0 + w * 64 + (lane >> 4) * 4;
  int ocol = h * F + f0 + (lane & 15);
#pragma unroll
  for (int m = 0; m < 4; ++m)
#pragma unroll
    for (int n = 0; n < 4; ++n)
#pragma unroll
      for (int r = 0; r < 4; ++r)
        Pc[(size_t)(orow + m * 16 + r) * HF + ocol + n * 16] = acc[m][n][r];
}

// Out = relu((sum_c P[c]) / den + bias)
__global__ void k_gat_reduce(const float* __restrict__ P, int nch, size_t chstride,
    const float* __restrict__ den, const float* __restrict__ bias, float* __restrict__ Out,
    int HF, int F, int n_total) {
  int e = (blockIdx.x * 256 + threadIdx.x) * 4;
  if (e >= n_total) return;
  float4 s = *reinterpret_cast<const float4*>(&P[e]);
  for (int c = 1; c < nch; ++c) {
    float4 v = *reinterpret_cast<const float4*>(&P[c * chstride + e]);
    s.x += v.x; s.y += v.y; s.z += v.z; s.w += v.w;
  }
  int i = e / HF;
  int hf = e - i * HF;
  int h = hf / F;
  float inv = 1.f / den[i * (HF / F) + h];
  float4 bz = *reinterpret_cast<const float4*>(&bias[hf]);
  float4 o;
  o.x = fmaxf(fmaf(s.x, inv, bz.x), 0.f);
  o.y = fmaxf(fmaf(s.y, inv, bz.y), 0.f);
  o.z = fmaxf(fmaf(s.z, inv, bz.z), 0.f);
  o.w = fmaxf(fmaf(s.w, inv, bz.w), 0.f);
  *reinterpret_cast<float4*>(&Out[e]) = o;
}

// ---- bf16 MFMA: C = relu(G @ G^T), 128x128 block ----
__global__ __launch_bounds__(256) void k_syrk_mfma(const unsigned short* __restrict__ G,
    int M, int Kd, float* __restrict__ C) {
  __shared__ __align__(16) unsigned short Ai[128 * 40];
  __shared__ __align__(16) unsigned short Bj[128 * 40];
  int tid = threadIdx.x;
  int i0 = blockIdx.y << 7, j0 = blockIdx.x << 7;
  int srow = tid >> 1, scol = (tid & 1) << 3;
  int lane = tid & 63, w = tid >> 6;
  int wr = (w >> 1) << 6, wc = (w & 1) << 6;
  int lr = lane & 15, kb = lane >> 4;
  f32x4 acc[4][4] = {};
  const unsigned short* gA = G + (size_t)i0 * Kd;
  const unsigned short* gB = G + (size_t)j0 * Kd;
  for (int k0 = 0; k0 < Kd; k0 += 32) {
    __syncthreads();
#pragma unroll
    for (int kk = 0; kk < 32; kk += 16) {
      *reinterpret_cast<uint4*>(&Ai[srow * 40 + scol + kk]) =
          *reinterpret_cast<const uint4*>(&gA[(size_t)srow * Kd + k0 + scol + kk]);
      *reinterpret_cast<uint4*>(&Bj[srow * 40 + scol + kk]) =
          *reinterpret_cast<const uint4*>(&gB[(size_t)srow * Kd + k0 + scol + kk]);
    }
    __syncthreads();
    bf16x8 a[4], b[4];
#pragma unroll
    for (int m = 0; m < 4; ++m)
      a[m] = *reinterpret_cast<const bf16x8*>(&Ai[(wr + m * 16 + lr) * 40 + kb * 8]);
#pragma unroll
    for (int n = 0; n < 4; ++n)
      b[n] = *reinterpret_cast<const bf16x8*>(&Bj[(wc + n * 16 + lr) * 40 + kb * 8]);
#pragma unroll
    for (int m = 0; m < 4; ++m)
#pragma unroll
      for (int n = 0; n < 4; ++n)
        acc[m][n] = __builtin_amdgcn_mfma_f32_16x16x32_bf16(a[m], b[n], acc[m][n], 0, 0, 0);
  }
  int orow = i0 + wr + (lane >> 4) * 4;
  int ocol = j0 + wc + (lane & 15);
#pragma unroll
  for (int m = 0; m < 4; ++m)
#pragma unroll
    for (int n = 0; n < 4; ++n)
#pragma unroll
      for (int r = 0; r < 4; ++r)
        C[(size_t)(orow + m * 16 + r) * M + ocol + n * 16] = fmaxf(acc[m][n][r], 0.f);
}

// C[M,N] = A[M,K] @ BT[N,K]^T (+ bias[m] if non-null). bf16 in, f32 out.
__global__ __launch_bounds__(256) void k_gemm_mfma_bt(const unsigned short* __restrict__ Amat,
    const unsigned short* __restrict__ BT, const float* __restrict__ bias,
    float* __restrict__ C, int M, int N, int Kd) {
  __shared__ __align__(16) unsigned short Ai[128 * 40];
  __shared__ __align__(16) unsigned short Bj[128 * 40];
  int tid = threadIdx.x;
  int m0 = blockIdx.y << 7, n0 = blockIdx.x << 7;
  int srow = tid >> 1, scol = (tid & 1) << 3;
  int lane = tid & 63, w = tid >> 6;
  int wr = (w >> 1) << 6, wc = (w & 1) << 6;
  int lr = lane & 15, kb = lane >> 4;
  f32x4 acc[4][4] = {};
  const unsigned short* gA = Amat + (size_t)m0 * Kd;
  const unsigned short* gB = BT + (size_t)n0 * Kd;
  for (int k0 = 0; k0 < Kd; k0 += 32) {
    __syncthreads();
#pragma unroll
    for (int kk = 0; kk < 32; kk += 16) {
      *reinterpret_cast<uint4*>(&Ai[srow * 40 + scol + kk]) =
          *reinterpret_cast<const uint4*>(&gA[(size_t)srow * Kd + k0 + scol + kk]);
      *reinterpret_cast<uint4*>(&Bj[srow * 40 + scol + kk]) =
          *reinterpret_cast<const uint4*>(&gB[(size_t)srow * Kd + k0 + scol + kk]);
    }
    __syncthreads();
    bf16x8 a[4], b[4];
#pragma unroll
    for (int m = 0; m < 4; ++m)
      a[m] = *reinterpret_cast<const bf16x8*>(&Ai[(wr + m * 16 + lr) * 40 + kb * 8]);
#pragma unroll
    for (int n = 0; n < 4; ++n)
      b[n] = *reinterpret_cast<const bf16x8*>(&Bj[(wc + n * 16 + lr) * 40 + kb * 8]);
#pragma unroll
    for (int m = 0; m < 4; ++m)
#pragma unroll
      for (int n = 0; n < 4; ++n)
        acc[m][n] = __builtin_amdgcn_mfma_f32_16x16x32_bf16(a[m], b[n], acc[m][n], 0, 0, 0);
  }
  int orow = m0 + wr + (lane >> 4) * 4;
  int ocol = n0 + wc + (lane & 15);
#pragma unroll
  for (int m = 0; m < 4; ++m)
#pragma unroll
    for (int n = 0; n < 4; ++n)
#pragma unroll
      for (int r = 0; r < 4; ++r) {
        float rb = bias ? bias[orow + m * 16 + r] : 0.f;
        C[(size_t)(orow + m * 16 + r) * N + ocol + n * 16] = acc[m][n][r] + rb;
      }
}

// ---- upsampler GEMM: Pz[kc] = Wup(f32,staged->bf16) @ Xu1T^T, 128x256 tile, split-k ----
__global__ __launch_bounds__(512) void k_gemm_aup(const float* __restrict__ Wg,
    const unsigned short* __restrict__ BT, float* __restrict__ Pz, int Mtot, int Ktot,
    int kc_len) {
  __shared__ __align__(16) unsigned short Ai[128 * 40];
  __shared__ __align__(16) unsigned short Bj[256 * 40];
  int tid = threadIdx.x;
  int m0 = blockIdx.y << 7;
  int k0base = blockIdx.x * kc_len;
  int lane = tid & 63, w = tid >> 6;
  int wr = (w >> 2) << 6, wc = (w & 3) << 6;
  int lr = lane & 15, kb = lane >> 4;
  int ar = tid >> 2, ac8 = (tid & 3) << 3;
  int br = tid >> 1, bc16 = (tid & 1) << 4;
  f32x4 acc[4][4] = {};
  for (int kk = 0; kk < kc_len; kk += 32) {
    int k0 = k0base + kk;
    __syncthreads();
    {
      const float* arow = &Wg[(size_t)(m0 + ar) * Ktot + k0 + ac8];
      float4 v0 = *reinterpret_cast<const float4*>(arow);
      float4 v1 = *reinterpret_cast<const float4*>(arow + 4);
      unsigned short t8[8] = {f2b(v0.x), f2b(v0.y), f2b(v0.z), f2b(v0.w),
                              f2b(v1.x), f2b(v1.y), f2b(v1.z), f2b(v1.w)};
      *reinterpret_cast<uint4*>(&Ai[ar * 40 + ac8]) = *reinterpret_cast<const uint4*>(t8);
      const unsigned short* brow = &BT[(size_t)br * Ktot + k0 + bc16];
      *reinterpret_cast<uint4*>(&Bj[br * 40 + bc16]) = *reinterpret_cast<const uint4*>(brow);
      *reinterpret_cast<uint4*>(&Bj[br * 40 + bc16 + 8]) =
          *reinterpret_cast<const uint4*>(brow + 8);
    }
    __syncthreads();
    bf16x8 a[4], b[4];
#pragma unroll
    for (int m = 0; m < 4; ++m)
      a[m] = *reinterpret_cast<const bf16x8*>(&Ai[(wr + m * 16 + lr) * 40 + kb * 8]);
#pragma unroll
    for (int n = 0; n < 4; ++n)
      b[n] = *reinterpret_cast<const bf16x8*>(&Bj[(wc + n * 16 + lr) * 40 + kb * 8]);
#pragma unroll
    for (int m = 0; m < 4; ++m)
#pragma unroll
      for (int n = 0; n < 4; ++n)
        acc[m][n] = __builtin_amdgcn_mfma_f32_16x16x32_bf16(a[m], b[n], acc[m][n], 0, 0, 0);
  }
  float* outp = Pz + (size_t)blockIdx.x * Mtot * 256;
  int orow = m0 + wr + (lane >> 4) * 4;
  int ocol = wc + (lane & 15);
#pragma unroll
  for (int m = 0; m < 4; ++m)
#pragma unroll
    for (int n = 0; n < 4; ++n)
#pragma unroll
      for (int r = 0; r < 4; ++r)
        outp[(size_t)(orow + m * 16 + r) * 256 + ocol + n * 16] = acc[m][n][r];
}

// row softmax over 256 cols of (sum_c Pz[c] + bias[row]) -> bf16
__global__ __launch_bounds__(256) void k_softmax_fuse(const float* __restrict__ Pz, int nch,
    size_t chstride, const float* __restrict__ bias, unsigned short* __restrict__ ZB) {
  int row = blockIdx.x, tid = threadIdx.x;
  size_t e = (size_t)row * 256 + tid;
  float x = bias[row];
  for (int c = 0; c < nch; ++c) x += Pz[c * chstride + e];
  float m = x;
#pragma unroll
  for (int off = 32; off; off >>= 1) m = fmaxf(m, __shfl_down(m, off));
  __shared__ float red[4];
  __shared__ float bm, bs;
  if ((tid & 63) == 0) red[tid >> 6] = m;
  __syncthreads();
  if (tid == 0) bm = fmaxf(fmaxf(red[0], red[1]), fmaxf(red[2], red[3]));
  __syncthreads();
  float ev = expf(x - bm);
  float sm = wave_sum64(ev);
  __syncthreads();
  if ((tid & 63) == 0) red[tid >> 6] = sm;
  __syncthreads();
  if (tid == 0) bs = red[0] + red[1] + red[2] + red[3];
  __syncthreads();
  ZB[e] = f2b(ev / bs);
}

// src[n,h] = sum_f Xp[n,h,f]*a_src[h,f]; dst likewise.
__global__ void k_src_dst(const float* __restrict__ Xp, const float* __restrict__ a_src,
    const float* __restrict__ a_dst, float* __restrict__ src, float* __restrict__ dst,
    int H, int F) {
  int n = blockIdx.x;
  int h = threadIdx.x >> 6, lane = threadIdx.x & 63;
  const float* x = Xp + ((size_t)n * H + h) * F;
  const float* as = a_src + h * F;
  const float* ad = a_dst + h * F;
  float ps = 0.f, pd = 0.f;
  for (int f = lane; f < F; f += 64) {
    float xv = x[f];
    ps = fmaf(xv, as[f], ps);
    pd = fmaf(xv, ad[f], pd);
  }
  ps = wave_sum64(ps);
  pd = wave_sum64(pd);
  if (lane == 0) { src[n * H + h] = ps; dst[n * H + h] = pd; }
}

// denom[i,h] = sum_j valid(i,j) * exp(lrelu(dst[i,h]+src[j,h]))
__global__ __launch_bounds__(256) void k_att_denom(const float* __restrict__ Adj,
    const float* __restrict__ src, const float* __restrict__ dst, float* __restrict__ denom,
    int N, int H) {
  int i = blockIdx.x, tid = threadIdx.x;
  float di[4];
#pragma unroll
  for (int h = 0; h < 4; ++h) di[h] = (h < H) ? dst[i * H + h] : 0.f;
  float acc[4] = {0.f, 0.f, 0.f, 0.f};
  const float* row = Adj + (size_t)i * N;
  for (int j = tid; j < N; j += 256) {
    float av = row[j];
    if (av != 0.f || j == i) {
#pragma unroll
      for (int h = 0; h < 4; ++h) {
        if (h < H) {
          float t = di[h] + src[j * H + h];
          t = t >= 0.f ? t : 0.2f * t;
          acc[h] += __expf(t);
        }
      }
    }
  }
  __shared__ float red[4][4];
#pragma unroll
  for (int h = 0; h < 4; ++h) acc[h] = wave_sum64(acc[h]);
  if ((tid & 63) == 0) {
#pragma unroll
    for (int h = 0; h < 4; ++h) red[tid >> 6][h] = acc[h];
  }
  __syncthreads();
  if (tid < H) denom[i * H + tid] = red[0][tid] + red[1][tid] + red[2][tid] + red[3][tid];
}

// s[row] = sigmoid(dot(X[row,:], w) + b)
__global__ __launch_bounds__(256) void k_score(const float* __restrict__ Xf,
    const float* __restrict__ wv, const float* __restrict__ bsc, float* __restrict__ s, int D) {
  int row = blockIdx.x * 4 + (threadIdx.x >> 6);
  int lane = threadIdx.x & 63;
  const float* x = Xf + (size_t)row * D;
  float p = 0.f;
  for (int f = lane; f < D; f += 64) p = fmaf(x[f], wv[f], p);
  p = wave_sum64(p);
  if (lane == 0) s[row] = 1.f / (1.f + expf(-(p + bsc[0])));
}

// top-k by exact rank counting. grid = n/256, dyn LDS = n*8 bytes.
__global__ __launch_bounds__(256) void k_topk_rank(const float* __restrict__ s, int n, int k,
    int* __restrict__ idx, float* __restrict__ vals) {
  extern __shared__ unsigned long long keys[];
  int tid = threadIdx.x;
  for (int j = tid; j < n; j += 256) {
    unsigned u = __float_as_uint(s[j]);
    unsigned ord = (u & 0x80000000u) ? ~u : (u | 0x80000000u);
    keys[j] = ((unsigned long long)ord << 32) | (unsigned)(~j);
  }
  __syncthreads();
  int i = blockIdx.x * 256 + tid;
  unsigned long long mykey = keys[i];
  int rank = 0;
#pragma unroll 4
  for (int j = 0; j < n; ++j) rank += (keys[j] > mykey);
  if (rank < k) { idx[rank] = i; vals[rank] = s[i]; }
}

// sv[i] = rsqrt(dot(A0[idx[i],:], mask) + 1e-5)  -- fully coalesced row reads
__global__ __launch_bounds__(256) void k_rowsum_mask(const float* __restrict__ A0, int N,
    const int* __restrict__ idx, const float* __restrict__ m, float* __restrict__ sv) {
  int i = blockIdx.x, tid = threadIdx.x;
  const float* row = A0 + (size_t)idx[i] * N;
  float p = 0.f;
  for (int j = tid * 4; j < N; j += 1024) {
    float4 a = *reinterpret_cast<const float4*>(&row[j]);
    float4 b = *reinterpret_cast<const float4*>(&m[j]);
    p += a.x * b.x + a.y * b.y + a.z * b.z + a.w * b.w;
  }
  p = wave_sum64(p);
  __shared__ float red[4];
  if ((tid & 63) == 0) red[tid >> 6] = p;
  __syncthreads();
  if (tid == 0) sv[i] = rsqrtf(red[0] + red[1] + red[2] + red[3] + 1e-5f);
}

// T1[c][i] = A0[idx[i]][c]  (gather rows + transpose, coalesced both sides)
__global__ __launch_bounds__(256) void k_gatherT(const float* __restrict__ A0, int N,
    const int* __restrict__ idx, float* __restrict__ T1, int k) {
  __shared__ float T[64][65];
  int i0 = blockIdx.x << 6, c0 = blockIdx.y << 6;
  int tid = threadIdx.x;
  int tr = tid >> 4, tc4 = (tid & 15) << 2;
#pragma unroll
  for (int q = 0; q < 4; ++q) {
    int row = tr + q * 16;
    float4 v = *reinterpret_cast<const float4*>(&A0[(size_t)idx[i0 + row] * N + c0 + tc4]);
    T[tc4 + 0][row] = v.x; T[tc4 + 1][row] = v.y; T[tc4 + 2][row] = v.z; T[tc4 + 3][row] = v.w;
  }
  __syncthreads();
#pragma unroll
  for (int q = 0; q < 4; ++q) {
    int row = tr + q * 16;
    float4 o;
    o.x = T[row][tc4]; o.y = T[row][tc4 + 1]; o.z = T[row][tc4 + 2]; o.w = T[row][tc4 + 3];
    *reinterpret_cast<float4*>(&T1[(size_t)(c0 + row) * k + i0 + tc4]) = o;
  }
}

// A1[j][i] = T1[idx[j]][i] * sv[j] * sv[i]   (A1 symmetric; row-gather coalesced)
__global__ void k_scaleT(const float* __restrict__ T1, int k, const int* __restrict__ idx,
    const float* __restrict__ sv, float* __restrict__ A1) {
  int j = blockIdx.y;
  int i = (blockIdx.x * 256 + threadIdx.x) * 4;
  float sj = sv[j];
  const float* r = T1 + (size_t)idx[j] * k;
  float4 v = *reinterpret_cast<const float4*>(&r[i]);
  float4 s = *reinterpret_cast<const float4*>(&sv[i]);
  v.x *= sj * s.x; v.y *= sj * s.y; v.z *= sj * s.z; v.w *= sj * s.w;
  *reinterpret_cast<float4*>(&A1[(size_t)j * k + i]) = v;
}

__global__ void k_gather_mat(const float* __restrict__ Asrc, int lda,
    const int* __restrict__ idx, float* __restrict__ B, int k) {
  int j = blockIdx.x * 256 + threadIdx.x;
  int i = blockIdx.y;
  B[(size_t)i * k + j] = Asrc[(size_t)idx[i] * lda + idx[j]];
}

__global__ void k_gather_scale_rows(const float* __restrict__ Xs, int D,
    const int* __restrict__ idx, const float* __restrict__ v, float* __restrict__ Xo) {
  int f = blockIdx.x * 256 + threadIdx.x;
  int i = blockIdx.y;
  Xo[(size_t)i * D + f] = Xs[(size_t)idx[i] * D + f] * v[i];
}

__global__ void k_scatter_rows(const float* __restrict__ P, int D, const int* __restrict__ idx,
                               float* __restrict__ Xo) {
  int f = blockIdx.x * 256 + threadIdx.x;
  int i = blockIdx.y;
  Xo[(size_t)idx[i] * D + f] = P[(size_t)i * D + f];
}

extern "C" void kernel_launch(void* const* d_in, const int* in_sizes, int n_in,
                              void* d_out, int out_size, void* d_ws, size_t ws_size,
                              hipStream_t stream) {
  const float* A    = (const float*)d_in[0];
  const float* X    = (const float*)d_in[1];
  const float* Wd0  = (const float*)d_in[2];
  const float* asd0 = (const float*)d_in[3];
  const float* add0 = (const float*)d_in[4];
  const float* bd0  = (const float*)d_in[5];
  const float* Wd1  = (const float*)d_in[6];
  const float* asd1 = (const float*)d_in[7];
  const float* add1 = (const float*)d_in[8];
  const float* bd1  = (const float*)d_in[9];
  const float* wp0  = (const float*)d_in[10];
  const float* bp0  = (const float*)d_in[11];
  const float* wp1  = (const float*)d_in[12];
  const float* bp1  = (const float*)d_in[13];
  const float* Wb   = (const float*)d_in[14];
  const float* asb  = (const float*)d_in[15];
  const float* adb  = (const float*)d_in[16];
  const float* bb   = (const float*)d_in[17];
  const float* Wu0  = (const float*)d_in[18];
  const float* asu0 = (const float*)d_in[19];
  const float* adu0 = (const float*)d_in[20];
  const float* bu0  = (const float*)d_in[21];
  const float* Wu1  = (const float*)d_in[22];
  const float* asu1 = (const float*)d_in[23];
  const float* adu1 = (const float*)d_in[24];
  const float* bu1  = (const float*)d_in[25];
  const float* Wup  = (const float*)d_in[26];
  const float* bup  = (const float*)d_in[27];
  (void)in_sizes; (void)n_in; (void)out_size; (void)ws_size;

  float* out  = (float*)d_out;
  float* Aup  = out;                    // [8192*8192]
  float* A0   = out + 67108864ULL;      // [4096*4096]
  float* A1   = A0 + 16777216ULL;       // [2048*2048]
  float* rec0 = A1 + 4194304ULL;        // [2048*2048]
  float* rec1 = rec0 + 4194304ULL;      // [4096*4096]

  // Scratch in the A_up output region (dead before A_up syrk writes).
  float* S = Aup;
  size_t off = 0;
  auto nxt = [&](size_t n) { float* p = S + off; off += (n + 1023) & ~(size_t)1023; return p; };
  float* Xp0  = nxt(4096 * 512);
  float* X0   = nxt(4096 * 512);
  float* src0 = nxt(4096 * 4);
  float* dst0 = nxt(4096 * 4);
  float* den0 = nxt(4096 * 4);
  float* sc0  = nxt(4096);
  int*   idx0 = (int*)nxt(2048);
  float* v0   = nxt(2048);
  float* sv0  = nxt(2048);
  float* maskv = nxt(4096);
  float* X1in = nxt(2048 * 512);
  float* Xp1  = nxt(2048 * 1024);
  float* X1   = nxt(2048 * 1024);
  float* src1 = nxt(2048 * 4);
  float* dst1 = nxt(2048 * 4);
  float* den1 = nxt(2048 * 4);
  float* sc1  = nxt(2048);
  int*   idx1 = (int*)nxt(1024);
  float* v1   = nxt(1024);
  float* A2m  = nxt(1024 * 1024);
  float* X2in = nxt(1024 * 1024);
  float* Xpb  = nxt(1024 * 1024);
  float* Xb   = nxt(1024 * 1024);
  float* srcb = nxt(1024 * 2);
  float* dstb = nxt(1024 * 2);
  float* denb = nxt(1024 * 2);
  float* Pu0  = nxt(1024 * 512);
  float* Xpu0 = nxt(2048 * 512);
  float* Xu0  = nxt(2048 * 512);
  float* su0  = nxt(2048 * 4);
  float* du0  = nxt(2048 * 4);
  float* dn0  = nxt(2048 * 4);
  float* Pu1  = nxt(2048 * 256);
  float* Xpu1 = nxt(4096 * 256);
  float* su1  = nxt(4096 * 4);
  float* du1  = nxt(4096 * 4);
  float* dn1  = nxt(4096 * 4);
  float* P    = nxt((size_t)8 * 4096 * 512);               // split-j partials
  float* T1   = nxt((size_t)4096 * 2048);                  // gather-transpose buffer
  unsigned short* XpS  = (unsigned short*)nxt(3200000);    // 3 planes [H][F][N] bf16
  unsigned short* XSp  = (unsigned short*)nxt(1572864);    // 3-plane row split (A side)
  unsigned short* Wd0T = (unsigned short*)nxt(196608);     // 3 planes [512][256]
  unsigned short* Wd1T = (unsigned short*)nxt(786432);     // 3 planes [1024][512]
  unsigned short* XpT  = (unsigned short*)nxt(524288);     // [H][F][N] bf16 (single plane)
  unsigned short* X2inB = (unsigned short*)nxt(524288);
  unsigned short* XbB   = (unsigned short*)nxt(524288);
  unsigned short* WbT   = (unsigned short*)nxt(524288);
  unsigned short* Wu0T  = (unsigned short*)nxt(262144);
  unsigned short* Wu1T  = (unsigned short*)nxt(65536);

  // d_ws: final-stage-live buffers
  float* W = (float*)d_ws;
  float* Xu1 = W;                                               // 4096*256 f32
  unsigned short* Xu1B = (unsigned short*)(W + 1048576);        // 4096*256 bf16
  unsigned short* Xu0B = (unsigned short*)(W + 1048576 + 524288);  // 2048*512 bf16

  // rec1 output region as late scratch (dead before rec1 syrk writes)
  float* Pz = rec1;                                             // 4 x 8192*256 f32 (32 MB)
  unsigned short* ZB = (unsigned short*)(rec1 + 4 * 2097152);   // 8192*256 bf16
  unsigned short* Xu1T = (unsigned short*)(rec1 + 4 * 2097152 + 1048576);  // 256*4096 bf16

  const size_t PS0 = (size_t)4 * 128 * 4096;  // plane stride GAT0
  const size_t PS1 = (size_t)4 * 256 * 2048;  // plane stride GAT1

  // ---- A0 = A + I ----
  k_add_eye<<<16384, 256, 0, stream>>>(A, A0);

  // ---- down level 0: GAT(256 -> 4x128), bf16x6 split MFMA throughout ----
  k_split3<<<1024, 256, 0, stream>>>(X, XSp, (size_t)4096 * 256, 4096 * 256);
  k_transpose_split<<<dim3(8, 4, 1), 256, 0, stream>>>(Wd0, 512, 512, Wd0T, 256,
                                                       (size_t)512 * 256);
  k_gemm_x6_bt<<<dim3(4, 32), 256, 0, stream>>>(XSp, (size_t)4096 * 256, Wd0T,
                                                (size_t)512 * 256, Xp0, 4096, 512, 256);
  k_src_dst<<<4096, 256, 0, stream>>>(Xp0, asd0, add0, src0, dst0, 4, 128);
  k_att_denom<<<4096, 256, 0, stream>>>(A0, src0, dst0, den0, 4096, 4);
  k_transpose_split<<<dim3(2, 64, 4), 256, 0, stream>>>(Xp0, 512, 128, XpS, 4096, PS0);
  k_gat_x6<<<dim3(4, 32, 4), 256, 0, stream>>>(A0, 4096, XpS, PS0, src0, dst0, P, 512, 128,
                                               1024);
  k_gat_reduce<<<2048, 256, 0, stream>>>(P, 4, (size_t)4096 * 512, den0, bd0, X0, 512, 128,
                                         4096 * 512);
  k_score<<<1024, 256, 0, stream>>>(X0, wp0, bp0, sc0, 512);
  k_topk_rank<<<16, 256, 4096 * 8, stream>>>(sc0, 4096, 2048, idx0, v0);
  k_fill0<<<16, 256, 0, stream>>>(maskv, 4096);
  k_scatter_ones<<<8, 256, 0, stream>>>(idx0, maskv, 2048);
  k_rowsum_mask<<<2048, 256, 0, stream>>>(A0, 4096, idx0, maskv, sv0);
  k_gatherT<<<dim3(32, 64), 256, 0, stream>>>(A0, 4096, idx0, T1, 2048);
  k_scaleT<<<dim3(2, 2048), 256, 0, stream>>>(T1, 2048, idx0, sv0, A1);
  k_gather_scale_rows<<<dim3(2, 2048), 256, 0, stream>>>(X0, 512, idx0, v0, X1in);

  // ---- down level 1: GAT(512 -> 4x256), bf16x6 split MFMA throughout ----
  k_split3<<<1024, 256, 0, stream>>>(X1in, XSp, (size_t)2048 * 512, 2048 * 512);
  k_transpose_split<<<dim3(16, 8, 1), 256, 0, stream>>>(Wd1, 1024, 1024, Wd1T, 512,
                                                        (size_t)1024 * 512);
  k_gemm_x6_bt<<<dim3(8, 16), 256, 0, stream>>>(XSp, (size_t)2048 * 512, Wd1T,
                                                (size_t)1024 * 512, Xp1, 2048, 1024, 512);
  k_src_dst<<<2048, 256, 0, stream>>>(Xp1, asd1, add1, src1, dst1, 4, 256);
  k_att_denom<<<2048, 256, 0, stream>>>(A1, src1, dst1, den1, 2048, 4);
  k_transpose_split<<<dim3(4, 32, 4), 256, 0, stream>>>(Xp1, 1024, 256, XpS, 2048, PS1);
  k_gat_x6<<<dim3(8, 16, 4), 256, 0, stream>>>(A1, 2048, XpS, PS1, src1, dst1, P, 1024, 256,
                                               512);
  k_gat_reduce<<<2048, 256, 0, stream>>>(P, 4, (size_t)2048 * 1024, den1, bd1, X1, 1024, 256,
                                         2048 * 1024);
  k_score<<<512, 256, 0, stream>>>(X1, wp1, bp1, sc1, 1024);
  k_topk_rank<<<8, 256, 2048 * 8, stream>>>(sc1, 2048, 1024, idx1, v1);
  k_gather_mat<<<dim3(4, 1024), 256, 0, stream>>>(A1, 2048, idx1, A2m, 1024);
  k_gather_scale_rows<<<dim3(4, 1024), 256, 0, stream>>>(X1, 1024, idx1, v1, X2in);

  // ---- bottom: GAT(1024 -> 2x512), bf16 MFMA ----
  k_f32_to_bf16<<<1024, 256, 0, stream>>>(X2in, X2inB, 1024 * 1024);
  k_transpose_bf16<<<dim3(16, 16), 256, 0, stream>>>(Wb, 1024, WbT, 1024, 1024);
  k_gemm_mfma_bt<<<dim3(8, 8), 256, 0, stream>>>(X2inB, WbT, nullptr, Xpb, 1024, 1024, 1024);
  k_src_dst<<<1024, 128, 0, stream>>>(Xpb, asb, adb, srcb, dstb, 2, 512);
  k_att_denom<<<1024, 256, 0, stream>>>(A2m, srcb, dstb, denb, 1024, 2);
  for (int h = 0; h < 2; ++h)
    k_transpose_bf16<<<dim3(8, 16), 256, 0, stream>>>(Xpb + h * 512, 1024,
                                                      XpT + (size_t)h * 512 * 1024, 1024, 512);
  k_gat_mfma<<<dim3(16, 4, 8), 256, 0, stream>>>(A2m, 1024, XpT, srcb, dstb, P, 1024, 512, 128);
  k_gat_reduce<<<1024, 256, 0, stream>>>(P, 8, (size_t)1024 * 1024, denb, bb, Xb, 1024, 512,
                                         1024 * 1024);

  // ---- up level 0: unpool -> GAT(1024 -> 4x128) over A1, bf16 MFMA ----
  k_f32_to_bf16<<<1024, 256, 0, stream>>>(Xb, XbB, 1024 * 1024);
  k_transpose_bf16<<<dim3(8, 16), 256, 0, stream>>>(Wu0, 512, Wu0T, 1024, 512);
  k_gemm_mfma_bt<<<dim3(4, 8), 256, 0, stream>>>(XbB, Wu0T, nullptr, Pu0, 1024, 512, 1024);
  k_fill0<<<1024, 256, 0, stream>>>(Xpu0, 2048 * 512);
  k_scatter_rows<<<dim3(2, 1024), 256, 0, stream>>>(Pu0, 512, idx1, Xpu0);
  k_src_dst<<<2048, 256, 0, stream>>>(Xpu0, asu0, adu0, su0, du0, 4, 128);
  k_att_denom<<<2048, 256, 0, stream>>>(A1, su0, du0, dn0, 2048, 4);
  for (int h = 0; h < 4; ++h)
    k_transpose_bf16<<<dim3(2, 32), 256, 0, stream>>>(Xpu0 + h * 128, 512,
                                                      XpT + (size_t)h * 128 * 2048, 2048, 128);
  k_gat_mfma<<<dim3(8, 8, 8), 256, 0, stream>>>(A1, 2048, XpT, su0, du0, P, 512, 128, 256);
  k_gat_reduce<<<1024, 256, 0, stream>>>(P, 8, (size_t)2048 * 512, dn0, bu0, Xu0, 512, 128,
                                         2048 * 512);
  k_f32_to_bf16<<<1024, 256, 0, stream>>>(Xu0, Xu0B, 2048 * 512);

  // ---- up level 1: unpool -> GAT(512 -> 4x64) over A0, bf16 MFMA ----
  k_transpose_bf16<<<dim3(4, 8), 256, 0, stream>>>(Wu1, 256, Wu1T, 512, 256);
  k_gemm_mfma_bt<<<dim3(2, 16), 256, 0, stream>>>(Xu0B, Wu1T, nullptr, Pu1, 2048, 256, 512);
  k_fill0<<<1024, 256, 0, stream>>>(Xpu1, 4096 * 256);
  k_scatter_rows<<<dim3(1, 2048), 256, 0, stream>>>(Pu1, 256, idx0, Xpu1);
  k_src_dst<<<4096, 256, 0, stream>>>(Xpu1, asu1, adu1, su1, du1, 4, 64);
  k_att_denom<<<4096, 256, 0, stream>>>(A0, su1, du1, dn1, 4096, 4);
  for (int h = 0; h < 4; ++h)
    k_transpose_bf16<<<dim3(1, 64), 256, 0, stream>>>(Xpu1 + h * 64, 256,
                                                      XpT + (size_t)h * 64 * 4096, 4096, 64);
  k_gat_mfma<<<dim3(4, 16, 8), 256, 0, stream>>>(A0, 4096, XpT, su1, du1, P, 256, 64, 512);
  k_gat_reduce<<<1024, 256, 0, stream>>>(P, 8, (size_t)4096 * 256, dn1, bu1, Xu1, 256, 64,
                                         4096 * 256);
  k_f32_to_bf16<<<1024, 256, 0, stream>>>(Xu1, Xu1B, 4096 * 256);
  k_transpose_bf16<<<dim3(4, 64), 256, 0, stream>>>(Xu1, 256, Xu1T, 4096, 256);

  // ---- upsampler: split-k GEMM (fused f32->bf16 A staging) + fused softmax ----
  k_gemm_aup<<<dim3(4, 64), 512, 0, stream>>>(Wup, Xu1T, Pz, 8192, 4096, 1024);
  k_softmax_fuse<<<8192, 256, 0, stream>>>(Pz, 4, (size_t)8192 * 256, bup, ZB);
  k_syrk_mfma<<<dim3(64, 64), 256, 0, stream>>>(ZB, 8192, 256, Aup);

  // ---- reconstructions ----
  k_syrk_mfma<<<dim3(32, 32), 256, 0, stream>>>(Xu1B, 4096, 256, rec1);
  k_syrk_mfma<<<dim3(16, 16), 256, 0, stream>>>(Xu0B, 2048, 512, rec0);
}

// Round 7
// 1143.936 us; speedup vs baseline: 2.3621x; 1.0861x over previous
//
#include <hip/hip_runtime.h>
#include <math.h>

// ---------------------------------------------------------------------------
// Graph U-Net forward on MI355X.
// Ordering-critical math (down path) = bf16x6 split MFMA (~3e-8 rel err),
// with producer/consumer wave specialization. Denominator fused into GAT
// aggregation kernels. Non-ordering layers = plain bf16 MFMA.
// ---------------------------------------------------------------------------

typedef short bf16x8 __attribute__((ext_vector_type(8)));
typedef float f32x4 __attribute__((ext_vector_type(4)));

static __device__ __forceinline__ float wave_sum64(float v) {
#pragma unroll
  for (int off = 32; off; off >>= 1) v += __shfl_down(v, off);
  return v;
}

static __device__ __forceinline__ unsigned short f2b(float x) {
  unsigned u = __float_as_uint(x);
  unsigned r = (u + 0x7fffu + ((u >> 16) & 1u)) >> 16;
  return (unsigned short)r;
}

static __device__ __forceinline__ float b2f(unsigned short h) {
  return __uint_as_float(((unsigned)h) << 16);
}

// A0 = A + I  (4096x4096), float4
__global__ void k_add_eye(const float* __restrict__ A, float* __restrict__ O) {
  size_t i = ((size_t)blockIdx.x * 256 + threadIdx.x) * 4;
  size_t r = i >> 12, c = i & 4095;
  float4 v = *reinterpret_cast<const float4*>(&A[i]);
  if (r >= c && r < c + 4) ((float*)&v)[r - c] += 1.f;
  *reinterpret_cast<float4*>(&O[i]) = v;
}

__global__ void k_fill0(float* __restrict__ p, int n) {
  int stride = gridDim.x * 256;
  for (int i = blockIdx.x * 256 + threadIdx.x; i < n; i += stride) p[i] = 0.f;
}

__global__ void k_scatter_ones(const int* __restrict__ idx, float* __restrict__ m, int k) {
  int i = blockIdx.x * 256 + threadIdx.x;
  if (i < k) m[idx[i]] = 1.f;
}

__global__ void k_f32_to_bf16(const float* __restrict__ S, unsigned short* __restrict__ D,
                              int n) {
  int stride = gridDim.x * 1024;
  for (int i = (blockIdx.x * 256 + threadIdx.x) * 4; i < n; i += stride) {
    float4 v = *reinterpret_cast<const float4*>(&S[i]);
    uint2 o;
    o.x = (unsigned)f2b(v.x) | ((unsigned)f2b(v.y) << 16);
    o.y = (unsigned)f2b(v.z) | ((unsigned)f2b(v.w) << 16);
    *reinterpret_cast<uint2*>(&D[i]) = o;
  }
}

// row-major 3-plane bf16 split: D[p*PS + i] = split_p(S[i])
__global__ void k_split3(const float* __restrict__ S, unsigned short* __restrict__ D,
                         size_t PS, int n) {
  int stride = gridDim.x * 1024;
  for (int i = (blockIdx.x * 256 + threadIdx.x) * 4; i < n; i += stride) {
    float4 v = *reinterpret_cast<const float4*>(&S[i]);
    float xv[4] = {v.x, v.y, v.z, v.w};
    unsigned short o1[4], o2[4], o3[4];
#pragma unroll
    for (int e = 0; e < 4; ++e) {
      float x = xv[e];
      unsigned short a = f2b(x);
      float r1 = x - b2f(a);
      unsigned short b = f2b(r1);
      float r2 = r1 - b2f(b);
      o1[e] = a; o2[e] = b; o3[e] = f2b(r2);
    }
    *reinterpret_cast<uint2*>(&D[i]) = *reinterpret_cast<const uint2*>(o1);
    *reinterpret_cast<uint2*>(&D[PS + i]) = *reinterpret_cast<const uint2*>(o2);
    *reinterpret_cast<uint2*>(&D[2 * PS + i]) = *reinterpret_cast<const uint2*>(o3);
  }
}

// D[c][r] = bf16(S[r*ldS + c]); S has R rows, Cc cols; D is [Cc][R].
__global__ __launch_bounds__(256) void k_transpose_bf16(const float* __restrict__ S, int ldS,
    unsigned short* __restrict__ D, int R, int Cc) {
  __shared__ unsigned short T[64][72];
  int r0 = blockIdx.y << 6, c0 = blockIdx.x << 6;
  int tid = threadIdx.x;
  int tr = tid >> 4, tc4 = (tid & 15) << 2;
#pragma unroll
  for (int q = 0; q < 4; ++q) {
    int row = tr + q * 16;
    float4 v = *reinterpret_cast<const float4*>(&S[(size_t)(r0 + row) * ldS + c0 + tc4]);
    T[tc4 + 0][row] = f2b(v.x);
    T[tc4 + 1][row] = f2b(v.y);
    T[tc4 + 2][row] = f2b(v.z);
    T[tc4 + 3][row] = f2b(v.w);
  }
  __syncthreads();
#pragma unroll
  for (int q = 0; q < 4; ++q) {
    int row = tr + q * 16;
    *reinterpret_cast<uint2*>(&D[(size_t)(c0 + row) * R + r0 + tc4]) =
        *reinterpret_cast<const uint2*>(&T[row][tc4]);
  }
}

// per-head transpose: D[(h*F + c)*R + r] = bf16(S[r*ldS + h*F + c]); z = head
__global__ __launch_bounds__(256) void k_transpose_bf16h(const float* __restrict__ S, int ldS,
    int F, unsigned short* __restrict__ D, int R) {
  __shared__ unsigned short T[64][72];
  int h = blockIdx.z;
  int r0 = blockIdx.y << 6, c0 = blockIdx.x << 6;
  int tid = threadIdx.x;
  int tr = tid >> 4, tc4 = (tid & 15) << 2;
#pragma unroll
  for (int q = 0; q < 4; ++q) {
    int row = tr + q * 16;
    float4 v = *reinterpret_cast<const float4*>(&S[(size_t)(r0 + row) * ldS + h * F + c0 + tc4]);
    T[tc4 + 0][row] = f2b(v.x);
    T[tc4 + 1][row] = f2b(v.y);
    T[tc4 + 2][row] = f2b(v.z);
    T[tc4 + 3][row] = f2b(v.w);
  }
  __syncthreads();
#pragma unroll
  for (int q = 0; q < 4; ++q) {
    int row = tr + q * 16;
    *reinterpret_cast<uint2*>(&D[((size_t)h * F + c0 + row) * R + r0 + tc4]) =
        *reinterpret_cast<const uint2*>(&T[row][tc4]);
  }
}

// 3-way bf16 split + transpose: D[p*PS + (h*F + c)*R + r] = split_p(S[r*ldS + h*F + c]).
__global__ __launch_bounds__(256) void k_transpose_split(const float* __restrict__ S, int ldS,
    int F, unsigned short* __restrict__ D, int R, size_t PS) {
  __shared__ unsigned short T[3][64][72];
  int h = blockIdx.z;
  int c0 = blockIdx.x << 6, r0 = blockIdx.y << 6;
  int tid = threadIdx.x;
  int tr = tid >> 4, tc4 = (tid & 15) << 2;
#pragma unroll
  for (int q = 0; q < 4; ++q) {
    int row = tr + q * 16;
    float4 v = *reinterpret_cast<const float4*>(&S[(size_t)(r0 + row) * ldS + h * F + c0 + tc4]);
    float xv[4] = {v.x, v.y, v.z, v.w};
#pragma unroll
    for (int e = 0; e < 4; ++e) {
      float x = xv[e];
      unsigned short h1 = f2b(x);
      float r1 = x - b2f(h1);
      unsigned short h2 = f2b(r1);
      float r2 = r1 - b2f(h2);
      T[0][tc4 + e][row] = h1;
      T[1][tc4 + e][row] = h2;
      T[2][tc4 + e][row] = f2b(r2);
    }
  }
  __syncthreads();
#pragma unroll
  for (int p = 0; p < 3; ++p)
#pragma unroll
    for (int q = 0; q < 4; ++q) {
      int row = tr + q * 16;
      *reinterpret_cast<uint2*>(&D[p * PS + (size_t)(h * F + c0 + row) * R + r0 + tc4]) =
          *reinterpret_cast<const uint2*>(&T[p][row][tc4]);
    }
}

// ---- bf16x6 GEMM: C[M,N] = A @ BT^T from 3-plane splits. 128x128 block. ----
__global__ __launch_bounds__(256, 2) void k_gemm_x6_bt(const unsigned short* __restrict__ As,
    size_t APS, const unsigned short* __restrict__ BTs, size_t BPS, float* __restrict__ C,
    int M, int N, int K) {
  __shared__ __align__(16) unsigned short Ai[3][128 * 40];
  __shared__ __align__(16) unsigned short Bj[3][128 * 40];
  int tid = threadIdx.x;
  int m0 = blockIdx.y << 7, n0 = blockIdx.x << 7;
  int lane = tid & 63, w = tid >> 6;
  int lr = lane & 15, kb = lane >> 4;
  int wr = (w >> 1) << 6, wc = (w & 1) << 6;
  int sr = tid >> 1, sc = (tid & 1) << 4;
  f32x4 acc[4][4] = {};
  for (int k0 = 0; k0 < K; k0 += 32) {
    __syncthreads();
#pragma unroll
    for (int p = 0; p < 3; ++p) {
      const unsigned short* ga = &As[p * APS + (size_t)(m0 + sr) * K + k0 + sc];
      *reinterpret_cast<uint4*>(&Ai[p][sr * 40 + sc]) = *reinterpret_cast<const uint4*>(ga);
      *reinterpret_cast<uint4*>(&Ai[p][sr * 40 + sc + 8]) =
          *reinterpret_cast<const uint4*>(ga + 8);
      const unsigned short* gb = &BTs[p * BPS + (size_t)(n0 + sr) * K + k0 + sc];
      *reinterpret_cast<uint4*>(&Bj[p][sr * 40 + sc]) = *reinterpret_cast<const uint4*>(gb);
      *reinterpret_cast<uint4*>(&Bj[p][sr * 40 + sc + 8]) =
          *reinterpret_cast<const uint4*>(gb + 8);
    }
    __syncthreads();
    bf16x8 af[4][3], bf_[4][3];
#pragma unroll
    for (int m = 0; m < 4; ++m)
#pragma unroll
      for (int p = 0; p < 3; ++p)
        af[m][p] = *reinterpret_cast<const bf16x8*>(&Ai[p][(wr + m * 16 + lr) * 40 + kb * 8]);
#pragma unroll
    for (int n = 0; n < 4; ++n)
#pragma unroll
      for (int p = 0; p < 3; ++p)
        bf_[n][p] = *reinterpret_cast<const bf16x8*>(&Bj[p][(wc + n * 16 + lr) * 40 + kb * 8]);
#pragma unroll
    for (int m = 0; m < 4; ++m)
#pragma unroll
      for (int n = 0; n < 4; ++n) {
        acc[m][n] = __builtin_amdgcn_mfma_f32_16x16x32_bf16(af[m][0], bf_[n][0], acc[m][n], 0, 0, 0);
        acc[m][n] = __builtin_amdgcn_mfma_f32_16x16x32_bf16(af[m][0], bf_[n][1], acc[m][n], 0, 0, 0);
        acc[m][n] = __builtin_amdgcn_mfma_f32_16x16x32_bf16(af[m][1], bf_[n][0], acc[m][n], 0, 0, 0);
        acc[m][n] = __builtin_amdgcn_mfma_f32_16x16x32_bf16(af[m][0], bf_[n][2], acc[m][n], 0, 0, 0);
        acc[m][n] = __builtin_amdgcn_mfma_f32_16x16x32_bf16(af[m][2], bf_[n][0], acc[m][n], 0, 0, 0);
        acc[m][n] = __builtin_amdgcn_mfma_f32_16x16x32_bf16(af[m][1], bf_[n][1], acc[m][n], 0, 0, 0);
      }
  }
  int orow = m0 + wr + (lane >> 4) * 4;
  int ocol = n0 + wc + lr;
#pragma unroll
  for (int m = 0; m < 4; ++m)
#pragma unroll
    for (int n = 0; n < 4; ++n)
#pragma unroll
      for (int r = 0; r < 4; ++r)
        C[(size_t)(orow + m * 16 + r) * N + ocol + n * 16] = acc[m][n][r];
}

// ---- bf16x6 GAT aggregation v3: producer/consumer wave specialization ----
// 512 threads: waves 0-3 stage (Adj->w split + x + denom), waves 4-7 MFMA.
// Tile 128i x 128f x 32j, double-buffered LDS. grid: (h*ftiles+ft, N/128, JC).
// P[chunk][N][HF] partials; dP[chunk][N*H] denom partials (written by ft==0).
__global__ __launch_bounds__(512) void k_gat_x6(const float* __restrict__ Adj, int N,
    const unsigned short* __restrict__ XpS, size_t PS,
    const float* __restrict__ src, const float* __restrict__ dst,
    float* __restrict__ P, float* __restrict__ dP, int HF, int F, int jchunk) {
  __shared__ __align__(16) unsigned short wB[2][3][128 * 40];
  __shared__ __align__(16) unsigned short xB[2][3][128 * 40];
  int ftiles = F >> 7;
  int h = blockIdx.x / ftiles;
  int ft = blockIdx.x % ftiles;
  int f0 = ft << 7;
  int H = HF / F;
  int i0 = blockIdx.y << 7;
  int jb0 = blockIdx.z * jchunk;
  int tid = threadIdx.x;
  bool producer = tid < 256;
  int ntiles = jchunk >> 5;

  // producer state
  int sj4 = (tid & 7) << 2, si = tid >> 3;        // valid for tid<256
  int xf = tid >> 1, xj8 = (tid & 1) << 3;
  float di[4];
  float dsum[4] = {0.f, 0.f, 0.f, 0.f};
  const unsigned short* xg = XpS + ((size_t)h * F + f0 + (producer ? xf : 0)) * N;
  float4 aw[4];
  float s4[4];
  uint4 xv[3][2];

  auto load_tile = [&](int jb) {
#pragma unroll
    for (int e = 0; e < 4; ++e) s4[e] = src[(jb + sj4 + e) * H + h];
#pragma unroll
    for (int q = 0; q < 4; ++q)
      aw[q] = *reinterpret_cast<const float4*>(&Adj[(size_t)(i0 + si + q * 32) * N + jb + sj4]);
#pragma unroll
    for (int p = 0; p < 3; ++p) {
      xv[p][0] = *reinterpret_cast<const uint4*>(&xg[p * PS + jb + xj8]);
      xv[p][1] = *reinterpret_cast<const uint4*>(&xg[p * PS + jb + xj8 + 16]);
    }
  };
  auto emit_tile = [&](int b, int jb) {
#pragma unroll
    for (int q = 0; q < 4; ++q) {
      int gi = i0 + si + q * 32;
      float dq = di[q];
      const float* a = (const float*)&aw[q];
      unsigned short h1[4], h2[4], h3[4];
      float ds = 0.f;
#pragma unroll
      for (int e = 0; e < 4; ++e) {
        float wv = 0.f;
        if (a[e] != 0.f || (jb + sj4 + e) == gi) {
          float tt = dq + s4[e];
          tt = tt >= 0.f ? tt : 0.2f * tt;
          wv = __expf(tt);
        }
        ds += wv;
        unsigned u1 = __float_as_uint(wv);
        h1[e] = (unsigned short)(u1 >> 16);
        float r1 = wv - __uint_as_float(u1 & 0xffff0000u);
        unsigned u2 = __float_as_uint(r1);
        h2[e] = (unsigned short)(u2 >> 16);
        float r2 = r1 - __uint_as_float(u2 & 0xffff0000u);
        h3[e] = (unsigned short)(__float_as_uint(r2) >> 16);
      }
      dsum[q] += ds;
      int ro = (si + q * 32) * 40 + sj4;
      uint2 o;
      o.x = (unsigned)h1[0] | ((unsigned)h1[1] << 16);
      o.y = (unsigned)h1[2] | ((unsigned)h1[3] << 16);
      *reinterpret_cast<uint2*>(&wB[b][0][ro]) = o;
      o.x = (unsigned)h2[0] | ((unsigned)h2[1] << 16);
      o.y = (unsigned)h2[2] | ((unsigned)h2[3] << 16);
      *reinterpret_cast<uint2*>(&wB[b][1][ro]) = o;
      o.x = (unsigned)h3[0] | ((unsigned)h3[1] << 16);
      o.y = (unsigned)h3[2] | ((unsigned)h3[3] << 16);
      *reinterpret_cast<uint2*>(&wB[b][2][ro]) = o;
    }
#pragma unroll
    for (int p = 0; p < 3; ++p) {
      *reinterpret_cast<uint4*>(&xB[b][p][xf * 40 + xj8]) = xv[p][0];
      *reinterpret_cast<uint4*>(&xB[b][p][xf * 40 + xj8 + 16]) = xv[p][1];
    }
  };

  // consumer state
  int lane = tid & 63, cw = (tid >> 6) - 4;
  int clr = lane & 15, ckb = lane >> 4;
  int wr = ((cw >> 1) & 1) << 6, wf = (cw & 1) << 6;
  f32x4 acc[4][4] = {};

  if (producer) {
#pragma unroll
    for (int q = 0; q < 4; ++q) di[q] = dst[(i0 + si + q * 32) * H + h];
    load_tile(jb0);
    emit_tile(0, jb0);
    if (ntiles > 1) load_tile(jb0 + 32);
  }
  __syncthreads();
  for (int t = 0; t < ntiles; ++t) {
    if (producer) {
      int tn = t + 1;
      if (tn < ntiles) {
        emit_tile(tn & 1, jb0 + tn * 32);
        if (tn + 1 < ntiles) load_tile(jb0 + (tn + 1) * 32);
      }
    } else {
      int b = t & 1;
      bf16x8 af[4][3], bf_[4][3];
#pragma unroll
      for (int m = 0; m < 4; ++m)
#pragma unroll
        for (int p = 0; p < 3; ++p)
          af[m][p] =
              *reinterpret_cast<const bf16x8*>(&wB[b][p][(wr + m * 16 + clr) * 40 + ckb * 8]);
#pragma unroll
      for (int n = 0; n < 4; ++n)
#pragma unroll
        for (int p = 0; p < 3; ++p)
          bf_[n][p] =
              *reinterpret_cast<const bf16x8*>(&xB[b][p][(wf + n * 16 + clr) * 40 + ckb * 8]);
#pragma unroll
      for (int m = 0; m < 4; ++m)
#pragma unroll
        for (int n = 0; n < 4; ++n) {
          acc[m][n] = __builtin_amdgcn_mfma_f32_16x16x32_bf16(af[m][0], bf_[n][0], acc[m][n], 0, 0, 0);
          acc[m][n] = __builtin_amdgcn_mfma_f32_16x16x32_bf16(af[m][0], bf_[n][1], acc[m][n], 0, 0, 0);
          acc[m][n] = __builtin_amdgcn_mfma_f32_16x16x32_bf16(af[m][1], bf_[n][0], acc[m][n], 0, 0, 0);
          acc[m][n] = __builtin_amdgcn_mfma_f32_16x16x32_bf16(af[m][0], bf_[n][2], acc[m][n], 0, 0, 0);
          acc[m][n] = __builtin_amdgcn_mfma_f32_16x16x32_bf16(af[m][2], bf_[n][0], acc[m][n], 0, 0, 0);
          acc[m][n] = __builtin_amdgcn_mfma_f32_16x16x32_bf16(af[m][1], bf_[n][1], acc[m][n], 0, 0, 0);
        }
    }
    __syncthreads();
  }
  if (producer) {
    if (ft == 0) {
#pragma unroll
      for (int q = 0; q < 4; ++q) {
        float v = dsum[q];
        v += __shfl_xor(v, 1);
        v += __shfl_xor(v, 2);
        v += __shfl_xor(v, 4);
        if ((tid & 7) == 0)
          dP[(size_t)blockIdx.z * N * H + (i0 + si + q * 32) * H + h] = v;
      }
    }
  } else {
    float* Pc = P + (size_t)blockIdx.z * N * HF;
    int orow = i0 + wr + (lane >> 4) * 4;
    int ocol = h * F + f0 + wf + clr;
#pragma unroll
    for (int m = 0; m < 4; ++m)
#pragma unroll
      for (int n = 0; n < 4; ++n)
#pragma unroll
        for (int r = 0; r < 4; ++r)
          Pc[(size_t)(orow + m * 16 + r) * HF + ocol + n * 16] = acc[m][n][r];
  }
}

// ---- bf16 MFMA GAT aggregation (non-ordering layers): 256x64 tile, fused denom ----
__global__ __launch_bounds__(256) void k_gat_mfma(const float* __restrict__ Adj, int N,
    const unsigned short* __restrict__ XpT,
    const float* __restrict__ src, const float* __restrict__ dst,
    float* __restrict__ P, float* __restrict__ dP, int HF, int F, int jchunk) {
  __shared__ __align__(16) unsigned short wL[256][40];
  __shared__ __align__(16) unsigned short xT[64][40];
  __shared__ float dsl[256];
  int ftiles = F >> 6;
  int h = blockIdx.x / ftiles;
  int ft = blockIdx.x % ftiles;
  int f0 = ft << 6;
  int H = HF / F;
  int i0 = blockIdx.y << 8;
  int jb0 = blockIdx.z * jchunk;
  int tid = threadIdx.x;
  int lane = tid & 63, w = tid >> 6;
  int lr = lane & 15, kb = lane >> 4;
  dsl[tid] = dst[(i0 + tid) * H + h];
  int sj4 = (tid & 7) << 2;
  int si = tid >> 3;
  int xf = tid >> 2;
  int xj8 = (tid & 3) << 3;
  const unsigned short* xg = XpT + ((size_t)h * F + f0 + xf) * N;
  float dsum[8] = {};
  f32x4 acc[4][4] = {};
  for (int jb = jb0; jb < jb0 + jchunk; jb += 32) {
    __syncthreads();
    float s4[4];
#pragma unroll
    for (int e = 0; e < 4; ++e) s4[e] = src[(jb + sj4 + e) * H + h];
#pragma unroll
    for (int q = 0; q < 8; ++q) {
      int i = si + q * 32;
      int gi = i0 + i;
      float4 av = *reinterpret_cast<const float4*>(&Adj[(size_t)gi * N + jb + sj4]);
      float di = dsl[i];
      float vv[4] = {av.x, av.y, av.z, av.w};
      unsigned short wb[4];
      float ds = 0.f;
#pragma unroll
      for (int e = 0; e < 4; ++e) {
        float wv = 0.f;
        if (vv[e] != 0.f || (jb + sj4 + e) == gi) {
          float t = di + s4[e];
          t = t >= 0.f ? t : 0.2f * t;
          wv = __expf(t);
        }
        ds += wv;
        wb[e] = f2b(wv);
      }
      dsum[q] += ds;
      *reinterpret_cast<uint2*>(&wL[i][sj4]) = *reinterpret_cast<const uint2*>(wb);
    }
    *reinterpret_cast<uint4*>(&xT[xf][xj8]) = *reinterpret_cast<const uint4*>(&xg[jb + xj8]);
    __syncthreads();
    bf16x8 a[4], b[4];
#pragma unroll
    for (int m = 0; m < 4; ++m)
      a[m] = *reinterpret_cast<const bf16x8*>(&wL[w * 64 + m * 16 + lr][kb * 8]);
#pragma unroll
    for (int n = 0; n < 4; ++n)
      b[n] = *reinterpret_cast<const bf16x8*>(&xT[n * 16 + lr][kb * 8]);
#pragma unroll
    for (int m = 0; m < 4; ++m)
#pragma unroll
      for (int n = 0; n < 4; ++n)
        acc[m][n] = __builtin_amdgcn_mfma_f32_16x16x32_bf16(a[m], b[n], acc[m][n], 0, 0, 0);
  }
  if (ft == 0) {
#pragma unroll
    for (int q = 0; q < 8; ++q) {
      float v = dsum[q];
      v += __shfl_xor(v, 1);
      v += __shfl_xor(v, 2);
      v += __shfl_xor(v, 4);
      if ((tid & 7) == 0)
        dP[(size_t)blockIdx.z * N * H + (i0 + si + q * 32) * H + h] = v;
    }
  }
  float* Pc = P + (size_t)blockIdx.z * N * HF;
  int orow = i0 + w * 64 + (lane >> 4) * 4;
  int ocol = h * F + f0 + (lane & 15);
#pragma unroll
  for (int m = 0; m < 4; ++m)
#pragma unroll
    for (int n = 0; n < 4; ++n)
#pragma unroll
      for (int r = 0; r < 4; ++r)
        Pc[(size_t)(orow + m * 16 + r) * HF + ocol + n * 16] = acc[m][n][r];
}

// Out = relu((sum_c P[c]) / (sum_c dP[c]) + bias)
__global__ void k_gat_reduce(const float* __restrict__ P, int nch, size_t chstride,
    const float* __restrict__ dP, size_t dstride, const float* __restrict__ bias,
    float* __restrict__ Out, int HF, int F, int n_total) {
  int e = (blockIdx.x * 256 + threadIdx.x) * 4;
  if (e >= n_total) return;
  float4 s = *reinterpret_cast<const float4*>(&P[e]);
  for (int c = 1; c < nch; ++c) {
    float4 v = *reinterpret_cast<const float4*>(&P[c * chstride + e]);
    s.x += v.x; s.y += v.y; s.z += v.z; s.w += v.w;
  }
  int i = e / HF;
  int hf = e - i * HF;
  int h = hf / F;
  float den = 0.f;
  for (int c = 0; c < nch; ++c) den += dP[c * dstride + i * (HF / F) + h];
  float inv = 1.f / den;
  float4 bz = *reinterpret_cast<const float4*>(&bias[hf]);
  float4 o;
  o.x = fmaxf(fmaf(s.x, inv, bz.x), 0.f);
  o.y = fmaxf(fmaf(s.y, inv, bz.y), 0.f);
  o.z = fmaxf(fmaf(s.z, inv, bz.z), 0.f);
  o.w = fmaxf(fmaf(s.w, inv, bz.w), 0.f);
  *reinterpret_cast<float4*>(&Out[e]) = o;
}

// ---- bf16 MFMA: C = relu(G @ G^T), 128x128 block, triangular + mirror ----
__global__ __launch_bounds__(256) void k_syrk_mfma(const unsigned short* __restrict__ G,
    int M, int Kd, float* __restrict__ C) {
  if (blockIdx.x < blockIdx.y) return;
  __shared__ __align__(16) unsigned short Ai[128 * 40];
  __shared__ __align__(16) unsigned short Bj[128 * 40];
  int tid = threadIdx.x;
  int i0 = blockIdx.y << 7, j0 = blockIdx.x << 7;
  int srow = tid >> 1, scol = (tid & 1) << 3;
  int lane = tid & 63, w = tid >> 6;
  int wr = (w >> 1) << 6, wc = (w & 1) << 6;
  int lr = lane & 15, kb = lane >> 4;
  f32x4 acc[4][4] = {};
  const unsigned short* gA = G + (size_t)i0 * Kd;
  const unsigned short* gB = G + (size_t)j0 * Kd;
  for (int k0 = 0; k0 < Kd; k0 += 32) {
    __syncthreads();
#pragma unroll
    for (int kk = 0; kk < 32; kk += 16) {
      *reinterpret_cast<uint4*>(&Ai[srow * 40 + scol + kk]) =
          *reinterpret_cast<const uint4*>(&gA[(size_t)srow * Kd + k0 + scol + kk]);
      *reinterpret_cast<uint4*>(&Bj[srow * 40 + scol + kk]) =
          *reinterpret_cast<const uint4*>(&gB[(size_t)srow * Kd + k0 + scol + kk]);
    }
    __syncthreads();
    bf16x8 a[4], b[4];
#pragma unroll
    for (int m = 0; m < 4; ++m)
      a[m] = *reinterpret_cast<const bf16x8*>(&Ai[(wr + m * 16 + lr) * 40 + kb * 8]);
#pragma unroll
    for (int n = 0; n < 4; ++n)
      b[n] = *reinterpret_cast<const bf16x8*>(&Bj[(wc + n * 16 + lr) * 40 + kb * 8]);
#pragma unroll
    for (int m = 0; m < 4; ++m)
#pragma unroll
      for (int n = 0; n < 4; ++n)
        acc[m][n] = __builtin_amdgcn_mfma_f32_16x16x32_bf16(a[m], b[n], acc[m][n], 0, 0, 0);
  }
  int orow = i0 + wr + (lane >> 4) * 4;
  int ocol = j0 + wc + (lane & 15);
  bool mirror = (j0 != i0);
#pragma unroll
  for (int m = 0; m < 4; ++m)
#pragma unroll
    for (int n = 0; n < 4; ++n) {
      float4 v;
      v.x = fmaxf(acc[m][n][0], 0.f);
      v.y = fmaxf(acc[m][n][1], 0.f);
      v.z = fmaxf(acc[m][n][2], 0.f);
      v.w = fmaxf(acc[m][n][3], 0.f);
#pragma unroll
      for (int r = 0; r < 4; ++r)
        C[(size_t)(orow + m * 16 + r) * M + ocol + n * 16] = ((const float*)&v)[r];
      if (mirror)
        *reinterpret_cast<float4*>(
            &C[(size_t)(j0 + wc + n * 16 + lr) * M + i0 + wr + m * 16 + (lane >> 4) * 4]) = v;
    }
}

// C[M,N] = A[M,K] @ BT[N,K]^T (+ bias[m] if non-null). bf16 in, f32 out.
__global__ __launch_bounds__(256) void k_gemm_mfma_bt(const unsigned short* __restrict__ Amat,
    const unsigned short* __restrict__ BT, const float* __restrict__ bias,
    float* __restrict__ C, int M, int N, int Kd) {
  __shared__ __align__(16) unsigned short Ai[128 * 40];
  __shared__ __align__(16) unsigned short Bj[128 * 40];
  int tid = threadIdx.x;
  int m0 = blockIdx.y << 7, n0 = blockIdx.x << 7;
  int srow = tid >> 1, scol = (tid & 1) << 3;
  int lane = tid & 63, w = tid >> 6;
  int wr = (w >> 1) << 6, wc = (w & 1) << 6;
  int lr = lane & 15, kb = lane >> 4;
  f32x4 acc[4][4] = {};
  const unsigned short* gA = Amat + (size_t)m0 * Kd;
  const unsigned short* gB = BT + (size_t)n0 * Kd;
  for (int k0 = 0; k0 < Kd; k0 += 32) {
    __syncthreads();
#pragma unroll
    for (int kk = 0; kk < 32; kk += 16) {
      *reinterpret_cast<uint4*>(&Ai[srow * 40 + scol + kk]) =
          *reinterpret_cast<const uint4*>(&gA[(size_t)srow * Kd + k0 + scol + kk]);
      *reinterpret_cast<uint4*>(&Bj[srow * 40 + scol + kk]) =
          *reinterpret_cast<const uint4*>(&gB[(size_t)srow * Kd + k0 + scol + kk]);
    }
    __syncthreads();
    bf16x8 a[4], b[4];
#pragma unroll
    for (int m = 0; m < 4; ++m)
      a[m] = *reinterpret_cast<const bf16x8*>(&Ai[(wr + m * 16 + lr) * 40 + kb * 8]);
#pragma unroll
    for (int n = 0; n < 4; ++n)
      b[n] = *reinterpret_cast<const bf16x8*>(&Bj[(wc + n * 16 + lr) * 40 + kb * 8]);
#pragma unroll
    for (int m = 0; m < 4; ++m)
#pragma unroll
      for (int n = 0; n < 4; ++n)
        acc[m][n] = __builtin_amdgcn_mfma_f32_16x16x32_bf16(a[m], b[n], acc[m][n], 0, 0, 0);
  }
  int orow = m0 + wr + (lane >> 4) * 4;
  int ocol = n0 + wc + (lane & 15);
#pragma unroll
  for (int m = 0; m < 4; ++m)
#pragma unroll
    for (int n = 0; n < 4; ++n)
#pragma unroll
      for (int r = 0; r < 4; ++r) {
        float rb = bias ? bias[orow + m * 16 + r] : 0.f;
        C[(size_t)(orow + m * 16 + r) * N + ocol + n * 16] = acc[m][n][r] + rb;
      }
}

// ---- upsampler GEMM: Pz[kc] = Wup(f32,staged->bf16) @ Xu1T^T, 128x256 tile, split-k ----
__global__ __launch_bounds__(512) void k_gemm_aup(const float* __restrict__ Wg,
    const unsigned short* __restrict__ BT, float* __restrict__ Pz, int Mtot, int Ktot,
    int kc_len) {
  __shared__ __align__(16) unsigned short Ai[128 * 40];
  __shared__ __align__(16) unsigned short Bj[256 * 40];
  int tid = threadIdx.x;
  int m0 = blockIdx.y << 7;
  int k0base = blockIdx.x * kc_len;
  int lane = tid & 63, w = tid >> 6;
  int wr = (w >> 2) << 6, wc = (w & 3) << 6;
  int lr = lane & 15, kb = lane >> 4;
  int ar = tid >> 2, ac8 = (tid & 3) << 3;
  int br = tid >> 1, bc16 = (tid & 1) << 4;
  f32x4 acc[4][4] = {};
  for (int kk = 0; kk < kc_len; kk += 32) {
    int k0 = k0base + kk;
    __syncthreads();
    {
      const float* arow = &Wg[(size_t)(m0 + ar) * Ktot + k0 + ac8];
      float4 v0 = *reinterpret_cast<const float4*>(arow);
      float4 v1 = *reinterpret_cast<const float4*>(arow + 4);
      unsigned short t8[8] = {f2b(v0.x), f2b(v0.y), f2b(v0.z), f2b(v0.w),
                              f2b(v1.x), f2b(v1.y), f2b(v1.z), f2b(v1.w)};
      *reinterpret_cast<uint4*>(&Ai[ar * 40 + ac8]) = *reinterpret_cast<const uint4*>(t8);
      const unsigned short* brow = &BT[(size_t)br * Ktot + k0 + bc16];
      *reinterpret_cast<uint4*>(&Bj[br * 40 + bc16]) = *reinterpret_cast<const uint4*>(brow);
      *reinterpret_cast<uint4*>(&Bj[br * 40 + bc16 + 8]) =
          *reinterpret_cast<const uint4*>(brow + 8);
    }
    __syncthreads();
    bf16x8 a[4], b[4];
#pragma unroll
    for (int m = 0; m < 4; ++m)
      a[m] = *reinterpret_cast<const bf16x8*>(&Ai[(wr + m * 16 + lr) * 40 + kb * 8]);
#pragma unroll
    for (int n = 0; n < 4; ++n)
      b[n] = *reinterpret_cast<const bf16x8*>(&Bj[(wc + n * 16 + lr) * 40 + kb * 8]);
#pragma unroll
    for (int m = 0; m < 4; ++m)
#pragma unroll
      for (int n = 0; n < 4; ++n)
        acc[m][n] = __builtin_amdgcn_mfma_f32_16x16x32_bf16(a[m], b[n], acc[m][n], 0, 0, 0);
  }
  float* outp = Pz + (size_t)blockIdx.x * Mtot * 256;
  int orow = m0 + wr + (lane >> 4) * 4;
  int ocol = wc + (lane & 15);
#pragma unroll
  for (int m = 0; m < 4; ++m)
#pragma unroll
    for (int n = 0; n < 4; ++n)
#pragma unroll
      for (int r = 0; r < 4; ++r)
        outp[(size_t)(orow + m * 16 + r) * 256 + ocol + n * 16] = acc[m][n][r];
}

// row softmax over 256 cols of (sum_c Pz[c] + bias[row]) -> bf16
__global__ __launch_bounds__(256) void k_softmax_fuse(const float* __restrict__ Pz, int nch,
    size_t chstride, const float* __restrict__ bias, unsigned short* __restrict__ ZB) {
  int row = blockIdx.x, tid = threadIdx.x;
  size_t e = (size_t)row * 256 + tid;
  float x = bias[row];
  for (int c = 0; c < nch; ++c) x += Pz[c * chstride + e];
  float m = x;
#pragma unroll
  for (int off = 32; off; off >>= 1) m = fmaxf(m, __shfl_down(m, off));
  __shared__ float red[4];
  __shared__ float bm, bs;
  if ((tid & 63) == 0) red[tid >> 6] = m;
  __syncthreads();
  if (tid == 0) bm = fmaxf(fmaxf(red[0], red[1]), fmaxf(red[2], red[3]));
  __syncthreads();
  float ev = expf(x - bm);
  float sm = wave_sum64(ev);
  __syncthreads();
  if ((tid & 63) == 0) red[tid >> 6] = sm;
  __syncthreads();
  if (tid == 0) bs = red[0] + red[1] + red[2] + red[3];
  __syncthreads();
  ZB[e] = f2b(ev / bs);
}

// src[n,h] = sum_f Xp[n,h,f]*a_src[h,f]; dst likewise.
__global__ void k_src_dst(const float* __restrict__ Xp, const float* __restrict__ a_src,
    const float* __restrict__ a_dst, float* __restrict__ src, float* __restrict__ dst,
    int H, int F) {
  int n = blockIdx.x;
  int h = threadIdx.x >> 6, lane = threadIdx.x & 63;
  const float* x = Xp + ((size_t)n * H + h) * F;
  const float* as = a_src + h * F;
  const float* ad = a_dst + h * F;
  float ps = 0.f, pd = 0.f;
  for (int f = lane; f < F; f += 64) {
    float xv = x[f];
    ps = fmaf(xv, as[f], ps);
    pd = fmaf(xv, ad[f], pd);
  }
  ps = wave_sum64(ps);
  pd = wave_sum64(pd);
  if (lane == 0) { src[n * H + h] = ps; dst[n * H + h] = pd; }
}

// s[row] = sigmoid(dot(X[row,:], w) + b)
__global__ __launch_bounds__(256) void k_score(const float* __restrict__ Xf,
    const float* __restrict__ wv, const float* __restrict__ bsc, float* __restrict__ s, int D) {
  int row = blockIdx.x * 4 + (threadIdx.x >> 6);
  int lane = threadIdx.x & 63;
  const float* x = Xf + (size_t)row * D;
  float p = 0.f;
  for (int f = lane; f < D; f += 64) p = fmaf(x[f], wv[f], p);
  p = wave_sum64(p);
  if (lane == 0) s[row] = 1.f / (1.f + expf(-(p + bsc[0])));
}

// top-k by exact rank counting. grid = n/256, dyn LDS = n*8 bytes.
__global__ __launch_bounds__(256) void k_topk_rank(const float* __restrict__ s, int n, int k,
    int* __restrict__ idx, float* __restrict__ vals) {
  extern __shared__ unsigned long long keys[];
  int tid = threadIdx.x;
  for (int j = tid; j < n; j += 256) {
    unsigned u = __float_as_uint(s[j]);
    unsigned ord = (u & 0x80000000u) ? ~u : (u | 0x80000000u);
    keys[j] = ((unsigned long long)ord << 32) | (unsigned)(~j);
  }
  __syncthreads();
  int i = blockIdx.x * 256 + tid;
  unsigned long long mykey = keys[i];
  int rank = 0;
#pragma unroll 4
  for (int j = 0; j < n; ++j) rank += (keys[j] > mykey);
  if (rank < k) { idx[rank] = i; vals[rank] = s[i]; }
}

// sv[i] = rsqrt(dot(A0[idx[i],:], mask) + 1e-5)
__global__ __launch_bounds__(256) void k_rowsum_mask(const float* __restrict__ A0, int N,
    const int* __restrict__ idx, const float* __restrict__ m, float* __restrict__ sv) {
  int i = blockIdx.x, tid = threadIdx.x;
  const float* row = A0 + (size_t)idx[i] * N;
  float p = 0.f;
  for (int j = tid * 4; j < N; j += 1024) {
    float4 a = *reinterpret_cast<const float4*>(&row[j]);
    float4 b = *reinterpret_cast<const float4*>(&m[j]);
    p += a.x * b.x + a.y * b.y + a.z * b.z + a.w * b.w;
  }
  p = wave_sum64(p);
  __shared__ float red[4];
  if ((tid & 63) == 0) red[tid >> 6] = p;
  __syncthreads();
  if (tid == 0) sv[i] = rsqrtf(red[0] + red[1] + red[2] + red[3] + 1e-5f);
}

// T1[c][i] = A0[idx[i]][c]
__global__ __launch_bounds__(256) void k_gatherT(const float* __restrict__ A0, int N,
    const int* __restrict__ idx, float* __restrict__ T1, int k) {
  __shared__ float T[64][65];
  int i0 = blockIdx.x << 6, c0 = blockIdx.y << 6;
  int tid = threadIdx.x;
  int tr = tid >> 4, tc4 = (tid & 15) << 2;
#pragma unroll
  for (int q = 0; q < 4; ++q) {
    int row = tr + q * 16;
    float4 v = *reinterpret_cast<const float4*>(&A0[(size_t)idx[i0 + row] * N + c0 + tc4]);
    T[tc4 + 0][row] = v.x; T[tc4 + 1][row] = v.y; T[tc4 + 2][row] = v.z; T[tc4 + 3][row] = v.w;
  }
  __syncthreads();
#pragma unroll
  for (int q = 0; q < 4; ++q) {
    int row = tr + q * 16;
    float4 o;
    o.x = T[row][tc4]; o.y = T[row][tc4 + 1]; o.z = T[row][tc4 + 2]; o.w = T[row][tc4 + 3];
    *reinterpret_cast<float4*>(&T1[(size_t)(c0 + row) * k + i0 + tc4]) = o;
  }
}

// A1[j][i] = T1[idx[j]][i] * sv[j] * sv[i]
__global__ void k_scaleT(const float* __restrict__ T1, int k, const int* __restrict__ idx,
    const float* __restrict__ sv, float* __restrict__ A1) {
  int j = blockIdx.y;
  int i = (blockIdx.x * 256 + threadIdx.x) * 4;
  float sj = sv[j];
  const float* r = T1 + (size_t)idx[j] * k;
  float4 v = *reinterpret_cast<const float4*>(&r[i]);
  float4 s = *reinterpret_cast<const float4*>(&sv[i]);
  v.x *= sj * s.x; v.y *= sj * s.y; v.z *= sj * s.z; v.w *= sj * s.w;
  *reinterpret_cast<float4*>(&A1[(size_t)j * k + i]) = v;
}

__global__ void k_gather_mat(const float* __restrict__ Asrc, int lda,
    const int* __restrict__ idx, float* __restrict__ B, int k) {
  int j = blockIdx.x * 256 + threadIdx.x;
  int i = blockIdx.y;
  B[(size_t)i * k + j] = Asrc[(size_t)idx[i] * lda + idx[j]];
}

__global__ void k_gather_scale_rows(const float* __restrict__ Xs, int D,
    const int* __restrict__ idx, const float* __restrict__ v, float* __restrict__ Xo) {
  int f = blockIdx.x * 256 + threadIdx.x;
  int i = blockIdx.y;
  Xo[(size_t)i * D + f] = Xs[(size_t)idx[i] * D + f] * v[i];
}

__global__ void k_scatter_rows(const float* __restrict__ P, int D, const int* __restrict__ idx,
                               float* __restrict__ Xo) {
  int f = blockIdx.x * 256 + threadIdx.x;
  int i = blockIdx.y;
  Xo[(size_t)idx[i] * D + f] = P[(size_t)i * D + f];
}

extern "C" void kernel_launch(void* const* d_in, const int* in_sizes, int n_in,
                              void* d_out, int out_size, void* d_ws, size_t ws_size,
                              hipStream_t stream) {
  const float* A    = (const float*)d_in[0];
  const float* X    = (const float*)d_in[1];
  const float* Wd0  = (const float*)d_in[2];
  const float* asd0 = (const float*)d_in[3];
  const float* add0 = (const float*)d_in[4];
  const float* bd0  = (const float*)d_in[5];
  const float* Wd1  = (const float*)d_in[6];
  const float* asd1 = (const float*)d_in[7];
  const float* add1 = (const float*)d_in[8];
  const float* bd1  = (const float*)d_in[9];
  const float* wp0  = (const float*)d_in[10];
  const float* bp0  = (const float*)d_in[11];
  const float* wp1  = (const float*)d_in[12];
  const float* bp1  = (const float*)d_in[13];
  const float* Wb   = (const float*)d_in[14];
  const float* asb  = (const float*)d_in[15];
  const float* adb  = (const float*)d_in[16];
  const float* bb   = (const float*)d_in[17];
  const float* Wu0  = (const float*)d_in[18];
  const float* asu0 = (const float*)d_in[19];
  const float* adu0 = (const float*)d_in[20];
  const float* bu0  = (const float*)d_in[21];
  const float* Wu1  = (const float*)d_in[22];
  const float* asu1 = (const float*)d_in[23];
  const float* adu1 = (const float*)d_in[24];
  const float* bu1  = (const float*)d_in[25];
  const float* Wup  = (const float*)d_in[26];
  const float* bup  = (const float*)d_in[27];
  (void)in_sizes; (void)n_in; (void)out_size; (void)ws_size;

  float* out  = (float*)d_out;
  float* Aup  = out;                    // [8192*8192]
  float* A0   = out + 67108864ULL;      // [4096*4096]
  float* A1   = A0 + 16777216ULL;       // [2048*2048]
  float* rec0 = A1 + 4194304ULL;        // [2048*2048]
  float* rec1 = rec0 + 4194304ULL;      // [4096*4096]

  // Scratch in the A_up output region (dead before A_up syrk writes).
  float* S = Aup;
  size_t off = 0;
  auto nxt = [&](size_t n) { float* p = S + off; off += (n + 1023) & ~(size_t)1023; return p; };
  float* Xp0  = nxt(4096 * 512);
  float* X0   = nxt(4096 * 512);
  float* src0 = nxt(4096 * 4);
  float* dst0 = nxt(4096 * 4);
  float* sc0  = nxt(4096);
  int*   idx0 = (int*)nxt(2048);
  float* v0   = nxt(2048);
  float* sv0  = nxt(2048);
  float* maskv = nxt(4096);
  float* X1in = nxt(2048 * 512);
  float* Xp1  = nxt(2048 * 1024);
  float* X1   = nxt(2048 * 1024);
  float* src1 = nxt(2048 * 4);
  float* dst1 = nxt(2048 * 4);
  float* sc1  = nxt(2048);
  int*   idx1 = (int*)nxt(1024);
  float* v1   = nxt(1024);
  float* A2m  = nxt(1024 * 1024);
  float* X2in = nxt(1024 * 1024);
  float* Xpb  = nxt(1024 * 1024);
  float* Xb   = nxt(1024 * 1024);
  float* srcb = nxt(1024 * 2);
  float* dstb = nxt(1024 * 2);
  float* Pu0  = nxt(1024 * 512);
  float* Xpu0 = nxt(2048 * 512);
  float* Xu0  = nxt(2048 * 512);
  float* su0  = nxt(2048 * 4);
  float* du0  = nxt(2048 * 4);
  float* Pu1  = nxt(2048 * 256);
  float* Xpu1 = nxt(4096 * 256);
  float* su1  = nxt(4096 * 4);
  float* du1  = nxt(4096 * 4);
  float* dPp  = nxt(8 * 4096 * 4);                         // denom partials
  float* P    = nxt((size_t)8 * 4096 * 512);               // split-j partials
  float* T1   = nxt((size_t)4096 * 2048);                  // gather-transpose buffer
  unsigned short* XpS  = (unsigned short*)nxt(3200000);    // 3 planes [H][F][N] bf16
  unsigned short* XSp  = (unsigned short*)nxt(1572864);    // 3-plane row split (A side)
  unsigned short* Wd0T = (unsigned short*)nxt(196608);
  unsigned short* Wd1T = (unsigned short*)nxt(786432);
  unsigned short* XpT  = (unsigned short*)nxt(524288);     // [H][F][N] bf16 (single plane)
  unsigned short* X2inB = (unsigned short*)nxt(524288);
  unsigned short* XbB   = (unsigned short*)nxt(524288);
  unsigned short* WbT   = (unsigned short*)nxt(524288);
  unsigned short* Wu0T  = (unsigned short*)nxt(262144);
  unsigned short* Wu1T  = (unsigned short*)nxt(65536);

  // d_ws: final-stage-live buffers
  float* W = (float*)d_ws;
  float* Xu1 = W;                                               // 4096*256 f32
  unsigned short* Xu1B = (unsigned short*)(W + 1048576);        // 4096*256 bf16
  unsigned short* Xu0B = (unsigned short*)(W + 1048576 + 524288);  // 2048*512 bf16

  // rec1 output region as late scratch (dead before rec1 syrk writes)
  float* Pz = rec1;                                             // 4 x 8192*256 f32
  unsigned short* ZB = (unsigned short*)(rec1 + 4 * 2097152);   // 8192*256 bf16
  unsigned short* Xu1T = (unsigned short*)(rec1 + 4 * 2097152 + 1048576);  // 256*4096 bf16

  const size_t PS0 = (size_t)4 * 128 * 4096;  // plane stride GAT0
  const size_t PS1 = (size_t)4 * 256 * 2048;  // plane stride GAT1

  // ---- A0 = A + I ----
  k_add_eye<<<16384, 256, 0, stream>>>(A, A0);

  // ---- down level 0: GAT(256 -> 4x128), bf16x6 split MFMA ----
  k_split3<<<1024, 256, 0, stream>>>(X, XSp, (size_t)4096 * 256, 4096 * 256);
  k_transpose_split<<<dim3(8, 4, 1), 256, 0, stream>>>(Wd0, 512, 512, Wd0T, 256,
                                                       (size_t)512 * 256);
  k_gemm_x6_bt<<<dim3(4, 32), 256, 0, stream>>>(XSp, (size_t)4096 * 256, Wd0T,
                                                (size_t)512 * 256, Xp0, 4096, 512, 256);
  k_src_dst<<<4096, 256, 0, stream>>>(Xp0, asd0, add0, src0, dst0, 4, 128);
  k_transpose_split<<<dim3(2, 64, 4), 256, 0, stream>>>(Xp0, 512, 128, XpS, 4096, PS0);
  k_gat_x6<<<dim3(4, 32, 2), 512, 0, stream>>>(A0, 4096, XpS, PS0, src0, dst0, P, dPp, 512,
                                               128, 2048);
  k_gat_reduce<<<2048, 256, 0, stream>>>(P, 2, (size_t)4096 * 512, dPp, (size_t)4096 * 4, bd0,
                                         X0, 512, 128, 4096 * 512);
  k_score<<<1024, 256, 0, stream>>>(X0, wp0, bp0, sc0, 512);
  k_topk_rank<<<16, 256, 4096 * 8, stream>>>(sc0, 4096, 2048, idx0, v0);
  k_fill0<<<16, 256, 0, stream>>>(maskv, 4096);
  k_scatter_ones<<<8, 256, 0, stream>>>(idx0, maskv, 2048);
  k_rowsum_mask<<<2048, 256, 0, stream>>>(A0, 4096, idx0, maskv, sv0);
  k_gatherT<<<dim3(32, 64), 256, 0, stream>>>(A0, 4096, idx0, T1, 2048);
  k_scaleT<<<dim3(2, 2048), 256, 0, stream>>>(T1, 2048, idx0, sv0, A1);
  k_gather_scale_rows<<<dim3(2, 2048), 256, 0, stream>>>(X0, 512, idx0, v0, X1in);

  // ---- down level 1: GAT(512 -> 4x256), bf16x6 split MFMA ----
  k_split3<<<1024, 256, 0, stream>>>(X1in, XSp, (size_t)2048 * 512, 2048 * 512);
  k_transpose_split<<<dim3(16, 8, 1), 256, 0, stream>>>(Wd1, 1024, 1024, Wd1T, 512,
                                                        (size_t)1024 * 512);
  k_gemm_x6_bt<<<dim3(8, 16), 256, 0, stream>>>(XSp, (size_t)2048 * 512, Wd1T,
                                                (size_t)1024 * 512, Xp1, 2048, 1024, 512);
  k_src_dst<<<2048, 256, 0, stream>>>(Xp1, asd1, add1, src1, dst1, 4, 256);
  k_transpose_split<<<dim3(4, 32, 4), 256, 0, stream>>>(Xp1, 1024, 256, XpS, 2048, PS1);
  k_gat_x6<<<dim3(8, 16, 2), 512, 0, stream>>>(A1, 2048, XpS, PS1, src1, dst1, P, dPp, 1024,
                                               256, 1024);
  k_gat_reduce<<<2048, 256, 0, stream>>>(P, 2, (size_t)2048 * 1024, dPp, (size_t)2048 * 4, bd1,
                                         X1, 1024, 256, 2048 * 1024);
  k_score<<<512, 256, 0, stream>>>(X1, wp1, bp1, sc1, 1024);
  k_topk_rank<<<8, 256, 2048 * 8, stream>>>(sc1, 2048, 1024, idx1, v1);
  k_gather_mat<<<dim3(4, 1024), 256, 0, stream>>>(A1, 2048, idx1, A2m, 1024);
  k_gather_scale_rows<<<dim3(4, 1024), 256, 0, stream>>>(X1, 1024, idx1, v1, X2in);

  // ---- bottom: GAT(1024 -> 2x512), bf16 MFMA ----
  k_f32_to_bf16<<<1024, 256, 0, stream>>>(X2in, X2inB, 1024 * 1024);
  k_transpose_bf16<<<dim3(16, 16), 256, 0, stream>>>(Wb, 1024, WbT, 1024, 1024);
  k_gemm_mfma_bt<<<dim3(8, 8), 256, 0, stream>>>(X2inB, WbT, nullptr, Xpb, 1024, 1024, 1024);
  k_src_dst<<<1024, 128, 0, stream>>>(Xpb, asb, adb, srcb, dstb, 2, 512);
  k_transpose_bf16h<<<dim3(8, 16, 2), 256, 0, stream>>>(Xpb, 1024, 512, XpT, 1024);
  k_gat_mfma<<<dim3(16, 4, 8), 256, 0, stream>>>(A2m, 1024, XpT, srcb, dstb, P, dPp, 1024, 512,
                                                 128);
  k_gat_reduce<<<1024, 256, 0, stream>>>(P, 8, (size_t)1024 * 1024, dPp, (size_t)1024 * 2, bb,
                                         Xb, 1024, 512, 1024 * 1024);

  // ---- up level 0: unpool -> GAT(1024 -> 4x128) over A1, bf16 MFMA ----
  k_f32_to_bf16<<<1024, 256, 0, stream>>>(Xb, XbB, 1024 * 1024);
  k_transpose_bf16<<<dim3(8, 16), 256, 0, stream>>>(Wu0, 512, Wu0T, 1024, 512);
  k_gemm_mfma_bt<<<dim3(4, 8), 256, 0, stream>>>(XbB, Wu0T, nullptr, Pu0, 1024, 512, 1024);
  k_fill0<<<1024, 256, 0, stream>>>(Xpu0, 2048 * 512);
  k_scatter_rows<<<dim3(2, 1024), 256, 0, stream>>>(Pu0, 512, idx1, Xpu0);
  k_src_dst<<<2048, 256, 0, stream>>>(Xpu0, asu0, adu0, su0, du0, 4, 128);
  k_transpose_bf16h<<<dim3(2, 32, 4), 256, 0, stream>>>(Xpu0, 512, 128, XpT, 2048);
  k_gat_mfma<<<dim3(8, 8, 8), 256, 0, stream>>>(A1, 2048, XpT, su0, du0, P, dPp, 512, 128, 256);
  k_gat_reduce<<<1024, 256, 0, stream>>>(P, 8, (size_t)2048 * 512, dPp, (size_t)2048 * 4, bu0,
                                         Xu0, 512, 128, 2048 * 512);
  k_f32_to_bf16<<<1024, 256, 0, stream>>>(Xu0, Xu0B, 2048 * 512);

  // ---- up level 1: unpool -> GAT(512 -> 4x64) over A0, bf16 MFMA ----
  k_transpose_bf16<<<dim3(4, 8), 256, 0, stream>>>(Wu1, 256, Wu1T, 512, 256);
  k_gemm_mfma_bt<<<dim3(2, 16), 256, 0, stream>>>(Xu0B, Wu1T, nullptr, Pu1, 2048, 256, 512);
  k_fill0<<<1024, 256, 0, stream>>>(Xpu1, 4096 * 256);
  k_scatter_rows<<<dim3(1, 2048), 256, 0, stream>>>(Pu1, 256, idx0, Xpu1);
  k_src_dst<<<4096, 256, 0, stream>>>(Xpu1, asu1, adu1, su1, du1, 4, 64);
  k_transpose_bf16h<<<dim3(1, 64, 4), 256, 0, stream>>>(Xpu1, 256, 64, XpT, 4096);
  k_gat_mfma<<<dim3(4, 16, 8), 256, 0, stream>>>(A0, 4096, XpT, su1, du1, P, dPp, 256, 64, 512);
  k_gat_reduce<<<1024, 256, 0, stream>>>(P, 8, (size_t)4096 * 256, dPp, (size_t)4096 * 4, bu1,
                                         Xu1, 256, 64, 4096 * 256);
  k_f32_to_bf16<<<1024, 256, 0, stream>>>(Xu1, Xu1B, 4096 * 256);
  k_transpose_bf16<<<dim3(4, 64), 256, 0, stream>>>(Xu1, 256, Xu1T, 4096, 256);

  // ---- upsampler: split-k GEMM (fused f32->bf16 A staging) + fused softmax ----
  k_gemm_aup<<<dim3(4, 64), 512, 0, stream>>>(Wup, Xu1T, Pz, 8192, 4096, 1024);
  k_softmax_fuse<<<8192, 256, 0, stream>>>(Pz, 4, (size_t)8192 * 256, bup, ZB);
  k_syrk_mfma<<<dim3(64, 64), 256, 0, stream>>>(ZB, 8192, 256, Aup);

  // ---- reconstructions ----
  k_syrk_mfma<<<dim3(32, 32), 256, 0, stream>>>(Xu1B, 4096, 256, rec1);
  k_syrk_mfma<<<dim3(16, 16), 256, 0, stream>>>(Xu0B, 2048, 512, rec0);
}

// Round 8
// 959.651 us; speedup vs baseline: 2.8157x; 1.1920x over previous
//
#include <hip/hip_runtime.h>
#include <math.h>

// ---------------------------------------------------------------------------
// Graph U-Net forward on MI355X.
// Ordering-critical math (down path) = bf16x6 split MFMA (~3e-8 rel err),
// single-buffered 2-blocks/CU tiles. Non-ordering layers = unified multi-head
// bf16 MFMA GAT (Adj read once, exp once, denom fused).
// ---------------------------------------------------------------------------

typedef short bf16x8 __attribute__((ext_vector_type(8)));
typedef float f32x4 __attribute__((ext_vector_type(4)));

static __device__ __forceinline__ float wave_sum64(float v) {
#pragma unroll
  for (int off = 32; off; off >>= 1) v += __shfl_down(v, off);
  return v;
}

static __device__ __forceinline__ unsigned short f2b(float x) {
  unsigned u = __float_as_uint(x);
  unsigned r = (u + 0x7fffu + ((u >> 16) & 1u)) >> 16;
  return (unsigned short)r;
}

static __device__ __forceinline__ float b2f(unsigned short h) {
  return __uint_as_float(((unsigned)h) << 16);
}

// A0 = A + I  (4096x4096), float4
__global__ void k_add_eye(const float* __restrict__ A, float* __restrict__ O) {
  size_t i = ((size_t)blockIdx.x * 256 + threadIdx.x) * 4;
  size_t r = i >> 12, c = i & 4095;
  float4 v = *reinterpret_cast<const float4*>(&A[i]);
  if (r >= c && r < c + 4) ((float*)&v)[r - c] += 1.f;
  *reinterpret_cast<float4*>(&O[i]) = v;
}

__global__ void k_fill0(float* __restrict__ p, int n) {
  int stride = gridDim.x * 256;
  for (int i = blockIdx.x * 256 + threadIdx.x; i < n; i += stride) p[i] = 0.f;
}

// row-major 3-plane bf16 split: D[p*PS + i] = split_p(S[i])
__global__ void k_split3(const float* __restrict__ S, unsigned short* __restrict__ D,
                         size_t PS, int n) {
  int stride = gridDim.x * 1024;
  for (int i = (blockIdx.x * 256 + threadIdx.x) * 4; i < n; i += stride) {
    float4 v = *reinterpret_cast<const float4*>(&S[i]);
    float xv[4] = {v.x, v.y, v.z, v.w};
    unsigned short o1[4], o2[4], o3[4];
#pragma unroll
    for (int e = 0; e < 4; ++e) {
      float x = xv[e];
      unsigned short a = f2b(x);
      float r1 = x - b2f(a);
      unsigned short b = f2b(r1);
      float r2 = r1 - b2f(b);
      o1[e] = a; o2[e] = b; o3[e] = f2b(r2);
    }
    *reinterpret_cast<uint2*>(&D[i]) = *reinterpret_cast<const uint2*>(o1);
    *reinterpret_cast<uint2*>(&D[PS + i]) = *reinterpret_cast<const uint2*>(o2);
    *reinterpret_cast<uint2*>(&D[2 * PS + i]) = *reinterpret_cast<const uint2*>(o3);
  }
}

// gather rows + scale + 3-plane split: D[p*PS + i*Dd + f] = split_p(Xs[idx[i]][f]*v[i])
__global__ void k_gather_scale_split3(const float* __restrict__ Xs, int Dd,
    const int* __restrict__ idx, const float* __restrict__ v,
    unsigned short* __restrict__ D, size_t PS) {
  int i = blockIdx.y;
  int f = (blockIdx.x * 256 + threadIdx.x) * 4;
  if (f >= Dd) return;
  float vi = v[i];
  float4 x4 = *reinterpret_cast<const float4*>(&Xs[(size_t)idx[i] * Dd + f]);
  float xv[4] = {x4.x * vi, x4.y * vi, x4.z * vi, x4.w * vi};
  unsigned short o1[4], o2[4], o3[4];
#pragma unroll
  for (int e = 0; e < 4; ++e) {
    float x = xv[e];
    unsigned short a = f2b(x);
    float r1 = x - b2f(a);
    unsigned short b = f2b(r1);
    float r2 = r1 - b2f(b);
    o1[e] = a; o2[e] = b; o3[e] = f2b(r2);
  }
  size_t e0 = (size_t)i * Dd + f;
  *reinterpret_cast<uint2*>(&D[e0]) = *reinterpret_cast<const uint2*>(o1);
  *reinterpret_cast<uint2*>(&D[PS + e0]) = *reinterpret_cast<const uint2*>(o2);
  *reinterpret_cast<uint2*>(&D[2 * PS + e0]) = *reinterpret_cast<const uint2*>(o3);
}

// gather rows + scale -> bf16
__global__ void k_gather_scale_b16(const float* __restrict__ Xs, int Dd,
    const int* __restrict__ idx, const float* __restrict__ v,
    unsigned short* __restrict__ D) {
  int i = blockIdx.y;
  int f = (blockIdx.x * 256 + threadIdx.x) * 4;
  if (f >= Dd) return;
  float vi = v[i];
  float4 x4 = *reinterpret_cast<const float4*>(&Xs[(size_t)idx[i] * Dd + f]);
  unsigned short o[4] = {f2b(x4.x * vi), f2b(x4.y * vi), f2b(x4.z * vi), f2b(x4.w * vi)};
  *reinterpret_cast<uint2*>(&D[(size_t)i * Dd + f]) = *reinterpret_cast<const uint2*>(o);
}

// D[c][r] = bf16(S[r*ldS + c]); f32 in
__global__ __launch_bounds__(256) void k_transpose_bf16(const float* __restrict__ S, int ldS,
    unsigned short* __restrict__ D, int R, int Cc) {
  __shared__ unsigned short T[64][72];
  int r0 = blockIdx.y << 6, c0 = blockIdx.x << 6;
  int tid = threadIdx.x;
  int tr = tid >> 4, tc4 = (tid & 15) << 2;
#pragma unroll
  for (int q = 0; q < 4; ++q) {
    int row = tr + q * 16;
    float4 v = *reinterpret_cast<const float4*>(&S[(size_t)(r0 + row) * ldS + c0 + tc4]);
    T[tc4 + 0][row] = f2b(v.x);
    T[tc4 + 1][row] = f2b(v.y);
    T[tc4 + 2][row] = f2b(v.z);
    T[tc4 + 3][row] = f2b(v.w);
  }
  __syncthreads();
#pragma unroll
  for (int q = 0; q < 4; ++q) {
    int row = tr + q * 16;
    *reinterpret_cast<uint2*>(&D[(size_t)(c0 + row) * R + r0 + tc4]) =
        *reinterpret_cast<const uint2*>(&T[row][tc4]);
  }
}

// D[c][r] = S[r*ldS + c]; bf16 in, bf16 out
__global__ __launch_bounds__(256) void k_transpose_bb(const unsigned short* __restrict__ S,
    int ldS, unsigned short* __restrict__ D, int R, int Cc) {
  __shared__ unsigned short T[64][72];
  int r0 = blockIdx.y << 6, c0 = blockIdx.x << 6;
  int tid = threadIdx.x;
  int tr = tid >> 4, tc4 = (tid & 15) << 2;
#pragma unroll
  for (int q = 0; q < 4; ++q) {
    int row = tr + q * 16;
    uint2 v = *reinterpret_cast<const uint2*>(&S[(size_t)(r0 + row) * ldS + c0 + tc4]);
    const unsigned short* p = (const unsigned short*)&v;
    T[tc4 + 0][row] = p[0]; T[tc4 + 1][row] = p[1];
    T[tc4 + 2][row] = p[2]; T[tc4 + 3][row] = p[3];
  }
  __syncthreads();
#pragma unroll
  for (int q = 0; q < 4; ++q) {
    int row = tr + q * 16;
    *reinterpret_cast<uint2*>(&D[(size_t)(c0 + row) * R + r0 + tc4]) =
        *reinterpret_cast<const uint2*>(&T[row][tc4]);
  }
}

// per-head transpose: D[(h*F + c)*R + r] = bf16(S[r*ldS + h*F + c]); z = head
__global__ __launch_bounds__(256) void k_transpose_bf16h(const float* __restrict__ S, int ldS,
    int F, unsigned short* __restrict__ D, int R) {
  __shared__ unsigned short T[64][72];
  int h = blockIdx.z;
  int r0 = blockIdx.y << 6, c0 = blockIdx.x << 6;
  int tid = threadIdx.x;
  int tr = tid >> 4, tc4 = (tid & 15) << 2;
#pragma unroll
  for (int q = 0; q < 4; ++q) {
    int row = tr + q * 16;
    float4 v = *reinterpret_cast<const float4*>(&S[(size_t)(r0 + row) * ldS + h * F + c0 + tc4]);
    T[tc4 + 0][row] = f2b(v.x);
    T[tc4 + 1][row] = f2b(v.y);
    T[tc4 + 2][row] = f2b(v.z);
    T[tc4 + 3][row] = f2b(v.w);
  }
  __syncthreads();
#pragma unroll
  for (int q = 0; q < 4; ++q) {
    int row = tr + q * 16;
    *reinterpret_cast<uint2*>(&D[((size_t)h * F + c0 + row) * R + r0 + tc4]) =
        *reinterpret_cast<const uint2*>(&T[row][tc4]);
  }
}

// 3-way bf16 split + transpose: D[p*PS + (h*F + c)*R + r] = split_p(S[r][h*F+c])
__global__ __launch_bounds__(256) void k_transpose_split(const float* __restrict__ S, int ldS,
    int F, unsigned short* __restrict__ D, int R, size_t PS) {
  __shared__ unsigned short T[3][64][72];
  int h = blockIdx.z;
  int c0 = blockIdx.x << 6, r0 = blockIdx.y << 6;
  int tid = threadIdx.x;
  int tr = tid >> 4, tc4 = (tid & 15) << 2;
#pragma unroll
  for (int q = 0; q < 4; ++q) {
    int row = tr + q * 16;
    float4 v = *reinterpret_cast<const float4*>(&S[(size_t)(r0 + row) * ldS + h * F + c0 + tc4]);
    float xv[4] = {v.x, v.y, v.z, v.w};
#pragma unroll
    for (int e = 0; e < 4; ++e) {
      float x = xv[e];
      unsigned short h1 = f2b(x);
      float r1 = x - b2f(h1);
      unsigned short h2 = f2b(r1);
      float r2 = r1 - b2f(h2);
      T[0][tc4 + e][row] = h1;
      T[1][tc4 + e][row] = h2;
      T[2][tc4 + e][row] = f2b(r2);
    }
  }
  __syncthreads();
#pragma unroll
  for (int p = 0; p < 3; ++p)
#pragma unroll
    for (int q = 0; q < 4; ++q) {
      int row = tr + q * 16;
      *reinterpret_cast<uint2*>(&D[p * PS + (size_t)(h * F + c0 + row) * R + r0 + tc4]) =
          *reinterpret_cast<const uint2*>(&T[p][row][tc4]);
    }
}

// ---- bf16x6 GEMM: C[M,N] = A @ BT^T from 3-plane splits. 128x128 block. ----
__global__ __launch_bounds__(256, 2) void k_gemm_x6_bt(const unsigned short* __restrict__ As,
    size_t APS, const unsigned short* __restrict__ BTs, size_t BPS, float* __restrict__ C,
    int M, int N, int K) {
  __shared__ __align__(16) unsigned short Ai[3][128 * 40];
  __shared__ __align__(16) unsigned short Bj[3][128 * 40];
  int tid = threadIdx.x;
  int m0 = blockIdx.y << 7, n0 = blockIdx.x << 7;
  int lane = tid & 63, w = tid >> 6;
  int lr = lane & 15, kb = lane >> 4;
  int wr = (w >> 1) << 6, wc = (w & 1) << 6;
  int sr = tid >> 1, sc = (tid & 1) << 4;
  f32x4 acc[4][4] = {};
  for (int k0 = 0; k0 < K; k0 += 32) {
    __syncthreads();
#pragma unroll
    for (int p = 0; p < 3; ++p) {
      const unsigned short* ga = &As[p * APS + (size_t)(m0 + sr) * K + k0 + sc];
      *reinterpret_cast<uint4*>(&Ai[p][sr * 40 + sc]) = *reinterpret_cast<const uint4*>(ga);
      *reinterpret_cast<uint4*>(&Ai[p][sr * 40 + sc + 8]) =
          *reinterpret_cast<const uint4*>(ga + 8);
      const unsigned short* gb = &BTs[p * BPS + (size_t)(n0 + sr) * K + k0 + sc];
      *reinterpret_cast<uint4*>(&Bj[p][sr * 40 + sc]) = *reinterpret_cast<const uint4*>(gb);
      *reinterpret_cast<uint4*>(&Bj[p][sr * 40 + sc + 8]) =
          *reinterpret_cast<const uint4*>(gb + 8);
    }
    __syncthreads();
    bf16x8 af[4][3], bf_[4][3];
#pragma unroll
    for (int m = 0; m < 4; ++m)
#pragma unroll
      for (int p = 0; p < 3; ++p)
        af[m][p] = *reinterpret_cast<const bf16x8*>(&Ai[p][(wr + m * 16 + lr) * 40 + kb * 8]);
#pragma unroll
    for (int n = 0; n < 4; ++n)
#pragma unroll
      for (int p = 0; p < 3; ++p)
        bf_[n][p] = *reinterpret_cast<const bf16x8*>(&Bj[p][(wc + n * 16 + lr) * 40 + kb * 8]);
#pragma unroll
    for (int m = 0; m < 4; ++m)
#pragma unroll
      for (int n = 0; n < 4; ++n) {
        acc[m][n] = __builtin_amdgcn_mfma_f32_16x16x32_bf16(af[m][0], bf_[n][0], acc[m][n], 0, 0, 0);
        acc[m][n] = __builtin_amdgcn_mfma_f32_16x16x32_bf16(af[m][0], bf_[n][1], acc[m][n], 0, 0, 0);
        acc[m][n] = __builtin_amdgcn_mfma_f32_16x16x32_bf16(af[m][1], bf_[n][0], acc[m][n], 0, 0, 0);
        acc[m][n] = __builtin_amdgcn_mfma_f32_16x16x32_bf16(af[m][0], bf_[n][2], acc[m][n], 0, 0, 0);
        acc[m][n] = __builtin_amdgcn_mfma_f32_16x16x32_bf16(af[m][2], bf_[n][0], acc[m][n], 0, 0, 0);
        acc[m][n] = __builtin_amdgcn_mfma_f32_16x16x32_bf16(af[m][1], bf_[n][1], acc[m][n], 0, 0, 0);
      }
  }
  int orow = m0 + wr + (lane >> 4) * 4;
  int ocol = n0 + wc + lr;
#pragma unroll
  for (int m = 0; m < 4; ++m)
#pragma unroll
    for (int n = 0; n < 4; ++n)
#pragma unroll
      for (int r = 0; r < 4; ++r)
        C[(size_t)(orow + m * 16 + r) * N + ocol + n * 16] = acc[m][n][r];
}

// ---- bf16x6 GAT aggregation v4: per-(head,fpart) blocks, single-buffered,
// 62 KB LDS -> 2 blocks/CU. grid: (H*FP, N/128, JC). 512 threads.
__global__ __launch_bounds__(512, 4) void k_gat_x6(const float* __restrict__ Adj, int N,
    const unsigned short* __restrict__ XpS, size_t PS,
    const float* __restrict__ src, const float* __restrict__ dst,
    float* __restrict__ P, float* __restrict__ dP, int HF, int Ffull, int FP, int jchunk) {
  __shared__ __align__(16) unsigned short wL[3][128 * 40];
  __shared__ __align__(16) unsigned short xL[3][128 * 40];
  __shared__ float dstL[128];
  __shared__ float srcL[32];
  int H = HF / Ffull;
  int h = blockIdx.x / FP;
  int fp = blockIdx.x % FP;
  int f0 = fp << 7;
  int i0 = blockIdx.y << 7;
  int jb0 = blockIdx.z * jchunk;
  int tid = threadIdx.x;
  int si = tid >> 2, sj8 = (tid & 3) << 3;
  int lane = tid & 63, w = tid >> 6;
  int lr = lane & 15, kb = lane >> 4;
  int fs = w << 4;
  if (tid < 128) dstL[tid] = dst[(i0 + tid) * H + h];
  float dsum = 0.f;
  f32x4 acc[8] = {};
  int ntiles = jchunk >> 5;
  const unsigned short* xbase = XpS + ((size_t)h * Ffull + f0) * N;
  for (int t = 0; t < ntiles; ++t) {
    int jb = jb0 + (t << 5);
    __syncthreads();  // prev MFMA done
    if (tid < 32) srcL[tid] = src[(jb + tid) * H + h];
    // x stage (no dependence on srcL)
    {
      int frow = tid >> 2;
#pragma unroll
      for (int p = 0; p < 3; ++p)
        *reinterpret_cast<uint4*>(&xL[p][frow * 40 + sj8]) =
            *reinterpret_cast<const uint4*>(&xbase[p * PS + (size_t)frow * N + jb + sj8]);
    }
    float4 av0 = *reinterpret_cast<const float4*>(&Adj[(size_t)(i0 + si) * N + jb + sj8]);
    float4 av1 = *reinterpret_cast<const float4*>(&Adj[(size_t)(i0 + si) * N + jb + sj8 + 4]);
    __syncthreads();  // srcL ready
    {
      int gi = i0 + si;
      float dq = dstL[si];
      const float* a0 = (const float*)&av0;
      const float* a1 = (const float*)&av1;
      unsigned short h1[8], h2[8], h3[8];
      float ds = 0.f;
#pragma unroll
      for (int e = 0; e < 8; ++e) {
        float a = e < 4 ? a0[e] : a1[e - 4];
        float wv = 0.f;
        if (a != 0.f || (jb + sj8 + e) == gi) {
          float tt = dq + srcL[sj8 + e];
          tt = tt >= 0.f ? tt : 0.2f * tt;
          wv = __expf(tt);
        }
        ds += wv;
        unsigned u1 = __float_as_uint(wv);
        h1[e] = (unsigned short)(u1 >> 16);
        float r1 = wv - __uint_as_float(u1 & 0xffff0000u);
        unsigned u2 = __float_as_uint(r1);
        h2[e] = (unsigned short)(u2 >> 16);
        float r2 = r1 - __uint_as_float(u2 & 0xffff0000u);
        h3[e] = (unsigned short)(__float_as_uint(r2) >> 16);
      }
      dsum += ds;
      *reinterpret_cast<uint4*>(&wL[0][si * 40 + sj8]) = *reinterpret_cast<const uint4*>(h1);
      *reinterpret_cast<uint4*>(&wL[1][si * 40 + sj8]) = *reinterpret_cast<const uint4*>(h2);
      *reinterpret_cast<uint4*>(&wL[2][si * 40 + sj8]) = *reinterpret_cast<const uint4*>(h3);
    }
    __syncthreads();  // tile staged
    bf16x8 bf_[3];
#pragma unroll
    for (int p = 0; p < 3; ++p)
      bf_[p] = *reinterpret_cast<const bf16x8*>(&xL[p][(fs + lr) * 40 + kb * 8]);
#pragma unroll
    for (int m = 0; m < 8; ++m) {
      bf16x8 af[3];
#pragma unroll
      for (int p = 0; p < 3; ++p)
        af[p] = *reinterpret_cast<const bf16x8*>(&wL[p][(m * 16 + lr) * 40 + kb * 8]);
      acc[m] = __builtin_amdgcn_mfma_f32_16x16x32_bf16(af[0], bf_[0], acc[m], 0, 0, 0);
      acc[m] = __builtin_amdgcn_mfma_f32_16x16x32_bf16(af[0], bf_[1], acc[m], 0, 0, 0);
      acc[m] = __builtin_amdgcn_mfma_f32_16x16x32_bf16(af[1], bf_[0], acc[m], 0, 0, 0);
      acc[m] = __builtin_amdgcn_mfma_f32_16x16x32_bf16(af[0], bf_[2], acc[m], 0, 0, 0);
      acc[m] = __builtin_amdgcn_mfma_f32_16x16x32_bf16(af[2], bf_[0], acc[m], 0, 0, 0);
      acc[m] = __builtin_amdgcn_mfma_f32_16x16x32_bf16(af[1], bf_[1], acc[m], 0, 0, 0);
    }
  }
  if (fp == 0) {
    float v = dsum;
    v += __shfl_xor(v, 1);
    v += __shfl_xor(v, 2);
    if ((tid & 3) == 0)
      dP[(size_t)blockIdx.z * N * H + (i0 + si) * H + h] = v;
  }
  float* Pc = P + (size_t)blockIdx.z * N * HF;
  int orow = i0 + (lane >> 4) * 4;
  int ocol = h * Ffull + f0 + fs + lr;
#pragma unroll
  for (int m = 0; m < 8; ++m)
#pragma unroll
    for (int r = 0; r < 4; ++r)
      Pc[(size_t)(orow + m * 16 + r) * HF + ocol] = acc[m][r];
}

// ---- unified multi-head bf16 GAT (non-ordering): block covers 128i x (NS*128)hf ----
// grid: (HF/(NS*128), N/128, JC). 512 threads, 8 waves each own NS*16 f-cols.
template <int NS, int HEADS>
__global__ __launch_bounds__(512) void k_gat_b16(const float* __restrict__ Adj, int N,
    const unsigned short* __restrict__ XpT,
    const float* __restrict__ src, const float* __restrict__ dst,
    float* __restrict__ P, float* __restrict__ dP, int HF, int F, int jchunk) {
  constexpr int HFB = NS * 128;
  __shared__ __align__(16) unsigned short wL[HEADS][128 * 40];
  __shared__ __align__(16) unsigned short xL[HFB * 40];
  __shared__ float dstL[HEADS][128];
  __shared__ float srcL[HEADS][32];
  int H = HF / F;
  int hf0 = blockIdx.x * HFB;
  int h0 = hf0 / F;
  int i0 = blockIdx.y << 7;
  int jb0 = blockIdx.z * jchunk;
  int tid = threadIdx.x;
  int si = tid >> 2, sj8 = (tid & 3) << 3;
  int lane = tid & 63, w = tid >> 6;
  int lr = lane & 15, kb = lane >> 4;
  int fs = w * (NS * 16);
  int hw = (hf0 + fs) / F - h0;
  if (tid < HEADS * 128)
    dstL[tid >> 7][tid & 127] = dst[(i0 + (tid & 127)) * H + h0 + (tid >> 7)];
  float dsum[HEADS] = {};
  f32x4 acc[8][NS] = {};
  int ntiles = jchunk >> 5;
  for (int t = 0; t < ntiles; ++t) {
    int jb = jb0 + (t << 5);
    __syncthreads();
    if (tid < HEADS * 32) srcL[tid >> 5][tid & 31] = src[(jb + (tid & 31)) * H + h0 + (tid >> 5)];
    // x stage
#pragma unroll
    for (int base = 0; base < HFB; base += 128) {
      int row = base + (tid >> 2);
      *reinterpret_cast<uint4*>(&xL[row * 40 + sj8]) =
          *reinterpret_cast<const uint4*>(&XpT[(size_t)(hf0 + row) * N + jb + sj8]);
    }
    float4 av0 = *reinterpret_cast<const float4*>(&Adj[(size_t)(i0 + si) * N + jb + sj8]);
    float4 av1 = *reinterpret_cast<const float4*>(&Adj[(size_t)(i0 + si) * N + jb + sj8 + 4]);
    __syncthreads();
    {
      int gi = i0 + si;
      const float* a0 = (const float*)&av0;
      const float* a1 = (const float*)&av1;
#pragma unroll
      for (int hh = 0; hh < HEADS; ++hh) {
        float dq = dstL[hh][si];
        unsigned short wb[8];
        float ds = 0.f;
#pragma unroll
        for (int e = 0; e < 8; ++e) {
          float a = e < 4 ? a0[e] : a1[e - 4];
          float wv = 0.f;
          if (a != 0.f || (jb + sj8 + e) == gi) {
            float tt = dq + srcL[hh][sj8 + e];
            tt = tt >= 0.f ? tt : 0.2f * tt;
            wv = __expf(tt);
          }
          ds += wv;
          wb[e] = f2b(wv);
        }
        dsum[hh] += ds;
        *reinterpret_cast<uint4*>(&wL[hh][si * 40 + sj8]) =
            *reinterpret_cast<const uint4*>(wb);
      }
    }
    __syncthreads();
    bf16x8 bf_[NS];
#pragma unroll
    for (int n = 0; n < NS; ++n)
      bf_[n] = *reinterpret_cast<const bf16x8*>(&xL[(fs + n * 16 + lr) * 40 + kb * 8]);
#pragma unroll
    for (int m = 0; m < 8; ++m) {
      bf16x8 a = *reinterpret_cast<const bf16x8*>(&wL[hw][(m * 16 + lr) * 40 + kb * 8]);
#pragma unroll
      for (int n = 0; n < NS; ++n)
        acc[m][n] = __builtin_amdgcn_mfma_f32_16x16x32_bf16(a, bf_[n], acc[m][n], 0, 0, 0);
    }
  }
#pragma unroll
  for (int hh = 0; hh < HEADS; ++hh) {
    float v = dsum[hh];
    v += __shfl_xor(v, 1);
    v += __shfl_xor(v, 2);
    if ((tid & 3) == 0)
      dP[(size_t)blockIdx.z * N * H + (i0 + si) * H + h0 + hh] = v;
  }
  float* Pc = P + (size_t)blockIdx.z * N * HF;
  int orow = i0 + (lane >> 4) * 4;
  int ocol0 = hf0 + fs + lr;
#pragma unroll
  for (int m = 0; m < 8; ++m)
#pragma unroll
    for (int n = 0; n < NS; ++n)
#pragma unroll
      for (int r = 0; r < 4; ++r)
        Pc[(size_t)(orow + m * 16 + r) * HF + ocol0 + n * 16] = acc[m][n][r];
}

// Out = relu((sum_c P[c]) / (sum_c dP[c]) + bias); optional f32/bf16 outputs
__global__ void k_gat_reduce(const float* __restrict__ P, int nch, size_t chstride,
    const float* __restrict__ dP, size_t dstride, const float* __restrict__ bias,
    float* __restrict__ Of, unsigned short* __restrict__ Ob, int HF, int F, int n_total) {
  int e = (blockIdx.x * 256 + threadIdx.x) * 4;
  if (e >= n_total) return;
  float4 s = *reinterpret_cast<const float4*>(&P[e]);
  for (int c = 1; c < nch; ++c) {
    float4 v = *reinterpret_cast<const float4*>(&P[c * chstride + e]);
    s.x += v.x; s.y += v.y; s.z += v.z; s.w += v.w;
  }
  int i = e / HF;
  int hf = e - i * HF;
  int h = hf / F;
  float den = 0.f;
  for (int c = 0; c < nch; ++c) den += dP[c * dstride + i * (HF / F) + h];
  float inv = 1.f / den;
  float4 bz = *reinterpret_cast<const float4*>(&bias[hf]);
  float4 o;
  o.x = fmaxf(fmaf(s.x, inv, bz.x), 0.f);
  o.y = fmaxf(fmaf(s.y, inv, bz.y), 0.f);
  o.z = fmaxf(fmaf(s.z, inv, bz.z), 0.f);
  o.w = fmaxf(fmaf(s.w, inv, bz.w), 0.f);
  if (Of) *reinterpret_cast<float4*>(&Of[e]) = o;
  if (Ob) {
    unsigned short ob[4] = {f2b(o.x), f2b(o.y), f2b(o.z), f2b(o.w)};
    *reinterpret_cast<uint2*>(&Ob[e]) = *reinterpret_cast<const uint2*>(ob);
  }
}

// ---- bf16 MFMA: C = relu(G @ G^T), 128x128 block, triangular + mirror ----
__global__ __launch_bounds__(256) void k_syrk_mfma(const unsigned short* __restrict__ G,
    int M, int Kd, float* __restrict__ C) {
  if (blockIdx.x < blockIdx.y) return;
  __shared__ __align__(16) unsigned short Ai[128 * 40];
  __shared__ __align__(16) unsigned short Bj[128 * 40];
  int tid = threadIdx.x;
  int i0 = blockIdx.y << 7, j0 = blockIdx.x << 7;
  int srow = tid >> 1, scol = (tid & 1) << 3;
  int lane = tid & 63, w = tid >> 6;
  int wr = (w >> 1) << 6, wc = (w & 1) << 6;
  int lr = lane & 15, kb = lane >> 4;
  f32x4 acc[4][4] = {};
  const unsigned short* gA = G + (size_t)i0 * Kd;
  const unsigned short* gB = G + (size_t)j0 * Kd;
  for (int k0 = 0; k0 < Kd; k0 += 32) {
    __syncthreads();
#pragma unroll
    for (int kk = 0; kk < 32; kk += 16) {
      *reinterpret_cast<uint4*>(&Ai[srow * 40 + scol + kk]) =
          *reinterpret_cast<const uint4*>(&gA[(size_t)srow * Kd + k0 + scol + kk]);
      *reinterpret_cast<uint4*>(&Bj[srow * 40 + scol + kk]) =
          *reinterpret_cast<const uint4*>(&gB[(size_t)srow * Kd + k0 + scol + kk]);
    }
    __syncthreads();
    bf16x8 a[4], b[4];
#pragma unroll
    for (int m = 0; m < 4; ++m)
      a[m] = *reinterpret_cast<const bf16x8*>(&Ai[(wr + m * 16 + lr) * 40 + kb * 8]);
#pragma unroll
    for (int n = 0; n < 4; ++n)
      b[n] = *reinterpret_cast<const bf16x8*>(&Bj[(wc + n * 16 + lr) * 40 + kb * 8]);
#pragma unroll
    for (int m = 0; m < 4; ++m)
#pragma unroll
      for (int n = 0; n < 4; ++n)
        acc[m][n] = __builtin_amdgcn_mfma_f32_16x16x32_bf16(a[m], b[n], acc[m][n], 0, 0, 0);
  }
  int orow = i0 + wr + (lane >> 4) * 4;
  int ocol = j0 + wc + (lane & 15);
  bool mirror = (j0 != i0);
#pragma unroll
  for (int m = 0; m < 4; ++m)
#pragma unroll
    for (int n = 0; n < 4; ++n) {
      float4 v;
      v.x = fmaxf(acc[m][n][0], 0.f);
      v.y = fmaxf(acc[m][n][1], 0.f);
      v.z = fmaxf(acc[m][n][2], 0.f);
      v.w = fmaxf(acc[m][n][3], 0.f);
#pragma unroll
      for (int r = 0; r < 4; ++r)
        C[(size_t)(orow + m * 16 + r) * M + ocol + n * 16] = ((const float*)&v)[r];
      if (mirror)
        *reinterpret_cast<float4*>(
            &C[(size_t)(j0 + wc + n * 16 + lr) * M + i0 + wr + m * 16 + (lane >> 4) * 4]) = v;
    }
}

// C[M,N] = A[M,K] @ BT[N,K]^T (+ bias[m] if non-null). bf16 in, f32 out.
__global__ __launch_bounds__(256) void k_gemm_mfma_bt(const unsigned short* __restrict__ Amat,
    const unsigned short* __restrict__ BT, const float* __restrict__ bias,
    float* __restrict__ C, int M, int N, int Kd) {
  __shared__ __align__(16) unsigned short Ai[128 * 40];
  __shared__ __align__(16) unsigned short Bj[128 * 40];
  int tid = threadIdx.x;
  int m0 = blockIdx.y << 7, n0 = blockIdx.x << 7;
  int srow = tid >> 1, scol = (tid & 1) << 3;
  int lane = tid & 63, w = tid >> 6;
  int wr = (w >> 1) << 6, wc = (w & 1) << 6;
  int lr = lane & 15, kb = lane >> 4;
  f32x4 acc[4][4] = {};
  const unsigned short* gA = Amat + (size_t)m0 * Kd;
  const unsigned short* gB = BT + (size_t)n0 * Kd;
  for (int k0 = 0; k0 < Kd; k0 += 32) {
    __syncthreads();
#pragma unroll
    for (int kk = 0; kk < 32; kk += 16) {
      *reinterpret_cast<uint4*>(&Ai[srow * 40 + scol + kk]) =
          *reinterpret_cast<const uint4*>(&gA[(size_t)srow * Kd + k0 + scol + kk]);
      *reinterpret_cast<uint4*>(&Bj[srow * 40 + scol + kk]) =
          *reinterpret_cast<const uint4*>(&gB[(size_t)srow * Kd + k0 + scol + kk]);
    }
    __syncthreads();
    bf16x8 a[4], b[4];
#pragma unroll
    for (int m = 0; m < 4; ++m)
      a[m] = *reinterpret_cast<const bf16x8*>(&Ai[(wr + m * 16 + lr) * 40 + kb * 8]);
#pragma unroll
    for (int n = 0; n < 4; ++n)
      b[n] = *reinterpret_cast<const bf16x8*>(&Bj[(wc + n * 16 + lr) * 40 + kb * 8]);
#pragma unroll
    for (int m = 0; m < 4; ++m)
#pragma unroll
      for (int n = 0; n < 4; ++n)
        acc[m][n] = __builtin_amdgcn_mfma_f32_16x16x32_bf16(a[m], b[n], acc[m][n], 0, 0, 0);
  }
  int orow = m0 + wr + (lane >> 4) * 4;
  int ocol = n0 + wc + (lane & 15);
#pragma unroll
  for (int m = 0; m < 4; ++m)
#pragma unroll
    for (int n = 0; n < 4; ++n)
#pragma unroll
      for (int r = 0; r < 4; ++r) {
        float rb = bias ? bias[orow + m * 16 + r] : 0.f;
        C[(size_t)(orow + m * 16 + r) * N + ocol + n * 16] = acc[m][n][r] + rb;
      }
}

// ---- upsampler GEMM: Pz[kc] = Wup(f32,staged->bf16) @ Xu1T^T, 128x256 tile, split-k ----
__global__ __launch_bounds__(512) void k_gemm_aup(const float* __restrict__ Wg,
    const unsigned short* __restrict__ BT, float* __restrict__ Pz, int Mtot, int Ktot,
    int kc_len) {
  __shared__ __align__(16) unsigned short Ai[128 * 40];
  __shared__ __align__(16) unsigned short Bj[256 * 40];
  int tid = threadIdx.x;
  int m0 = blockIdx.y << 7;
  int k0base = blockIdx.x * kc_len;
  int lane = tid & 63, w = tid >> 6;
  int wr = (w >> 2) << 6, wc = (w & 3) << 6;
  int lr = lane & 15, kb = lane >> 4;
  int ar = tid >> 2, ac8 = (tid & 3) << 3;
  int br = tid >> 1, bc16 = (tid & 1) << 4;
  f32x4 acc[4][4] = {};
  for (int kk = 0; kk < kc_len; kk += 32) {
    int k0 = k0base + kk;
    __syncthreads();
    {
      const float* arow = &Wg[(size_t)(m0 + ar) * Ktot + k0 + ac8];
      float4 v0 = *reinterpret_cast<const float4*>(arow);
      float4 v1 = *reinterpret_cast<const float4*>(arow + 4);
      unsigned short t8[8] = {f2b(v0.x), f2b(v0.y), f2b(v0.z), f2b(v0.w),
                              f2b(v1.x), f2b(v1.y), f2b(v1.z), f2b(v1.w)};
      *reinterpret_cast<uint4*>(&Ai[ar * 40 + ac8]) = *reinterpret_cast<const uint4*>(t8);
      const unsigned short* brow = &BT[(size_t)br * Ktot + k0 + bc16];
      *reinterpret_cast<uint4*>(&Bj[br * 40 + bc16]) = *reinterpret_cast<const uint4*>(brow);
      *reinterpret_cast<uint4*>(&Bj[br * 40 + bc16 + 8]) =
          *reinterpret_cast<const uint4*>(brow + 8);
    }
    __syncthreads();
    bf16x8 a[4], b[4];
#pragma unroll
    for (int m = 0; m < 4; ++m)
      a[m] = *reinterpret_cast<const bf16x8*>(&Ai[(wr + m * 16 + lr) * 40 + kb * 8]);
#pragma unroll
    for (int n = 0; n < 4; ++n)
      b[n] = *reinterpret_cast<const bf16x8*>(&Bj[(wc + n * 16 + lr) * 40 + kb * 8]);
#pragma unroll
    for (int m = 0; m < 4; ++m)
#pragma unroll
      for (int n = 0; n < 4; ++n)
        acc[m][n] = __builtin_amdgcn_mfma_f32_16x16x32_bf16(a[m], b[n], acc[m][n], 0, 0, 0);
  }
  float* outp = Pz + (size_t)blockIdx.x * Mtot * 256;
  int orow = m0 + wr + (lane >> 4) * 4;
  int ocol = wc + (lane & 15);
#pragma unroll
  for (int m = 0; m < 4; ++m)
#pragma unroll
    for (int n = 0; n < 4; ++n)
#pragma unroll
      for (int r = 0; r < 4; ++r)
        outp[(size_t)(orow + m * 16 + r) * 256 + ocol + n * 16] = acc[m][n][r];
}

// row softmax over 256 cols of (sum_c Pz[c] + bias[row]) -> bf16
__global__ __launch_bounds__(256) void k_softmax_fuse(const float* __restrict__ Pz, int nch,
    size_t chstride, const float* __restrict__ bias, unsigned short* __restrict__ ZB) {
  int row = blockIdx.x, tid = threadIdx.x;
  size_t e = (size_t)row * 256 + tid;
  float x = bias[row];
  for (int c = 0; c < nch; ++c) x += Pz[c * chstride + e];
  float m = x;
#pragma unroll
  for (int off = 32; off; off >>= 1) m = fmaxf(m, __shfl_down(m, off));
  __shared__ float red[4];
  __shared__ float bm, bs;
  if ((tid & 63) == 0) red[tid >> 6] = m;
  __syncthreads();
  if (tid == 0) bm = fmaxf(fmaxf(red[0], red[1]), fmaxf(red[2], red[3]));
  __syncthreads();
  float ev = expf(x - bm);
  float sm = wave_sum64(ev);
  __syncthreads();
  if ((tid & 63) == 0) red[tid >> 6] = sm;
  __syncthreads();
  if (tid == 0) bs = red[0] + red[1] + red[2] + red[3];
  __syncthreads();
  ZB[e] = f2b(ev / bs);
}

// src[n,h] = sum_f Xp[n,h,f]*a_src[h,f]; dst likewise.
__global__ void k_src_dst(const float* __restrict__ Xp, const float* __restrict__ a_src,
    const float* __restrict__ a_dst, float* __restrict__ src, float* __restrict__ dst,
    int H, int F) {
  int n = blockIdx.x;
  int h = threadIdx.x >> 6, lane = threadIdx.x & 63;
  const float* x = Xp + ((size_t)n * H + h) * F;
  const float* as = a_src + h * F;
  const float* ad = a_dst + h * F;
  float ps = 0.f, pd = 0.f;
  for (int f = lane; f < F; f += 64) {
    float xv = x[f];
    ps = fmaf(xv, as[f], ps);
    pd = fmaf(xv, ad[f], pd);
  }
  ps = wave_sum64(ps);
  pd = wave_sum64(pd);
  if (lane == 0) { src[n * H + h] = ps; dst[n * H + h] = pd; }
}

// s[row] = sigmoid(dot(X[row,:], w) + b)
__global__ __launch_bounds__(256) void k_score(const float* __restrict__ Xf,
    const float* __restrict__ wv, const float* __restrict__ bsc, float* __restrict__ s, int D) {
  int row = blockIdx.x * 4 + (threadIdx.x >> 6);
  int lane = threadIdx.x & 63;
  const float* x = Xf + (size_t)row * D;
  float p = 0.f;
  for (int f = lane; f < D; f += 64) p = fmaf(x[f], wv[f], p);
  p = wave_sum64(p);
  if (lane == 0) s[row] = 1.f / (1.f + expf(-(p + bsc[0])));
}

// top-k by exact rank counting; optionally builds 0/1 mask over selected nodes.
__global__ __launch_bounds__(256) void k_topk_rank(const float* __restrict__ s, int n, int k,
    int* __restrict__ idx, float* __restrict__ vals, float* __restrict__ mask) {
  extern __shared__ unsigned long long keys[];
  int tid = threadIdx.x;
  int i = blockIdx.x * 256 + tid;
  if (mask) mask[i] = 0.f;
  for (int j = tid; j < n; j += 256) {
    unsigned u = __float_as_uint(s[j]);
    unsigned ord = (u & 0x80000000u) ? ~u : (u | 0x80000000u);
    keys[j] = ((unsigned long long)ord << 32) | (unsigned)(~j);
  }
  __syncthreads();
  unsigned long long mykey = keys[i];
  int rank = 0;
#pragma unroll 4
  for (int j = 0; j < n; ++j) rank += (keys[j] > mykey);
  if (rank < k) {
    idx[rank] = i;
    vals[rank] = s[i];
    if (mask) mask[i] = 1.f;
  }
}

// sv[i] = rsqrt(dot(A0[idx[i],:], mask) + 1e-5)
__global__ __launch_bounds__(256) void k_rowsum_mask(const float* __restrict__ A0, int N,
    const int* __restrict__ idx, const float* __restrict__ m, float* __restrict__ sv) {
  int i = blockIdx.x, tid = threadIdx.x;
  const float* row = A0 + (size_t)idx[i] * N;
  float p = 0.f;
  for (int j = tid * 4; j < N; j += 1024) {
    float4 a = *reinterpret_cast<const float4*>(&row[j]);
    float4 b = *reinterpret_cast<const float4*>(&m[j]);
    p += a.x * b.x + a.y * b.y + a.z * b.z + a.w * b.w;
  }
  p = wave_sum64(p);
  __shared__ float red[4];
  if ((tid & 63) == 0) red[tid >> 6] = p;
  __syncthreads();
  if (tid == 0) sv[i] = rsqrtf(red[0] + red[1] + red[2] + red[3] + 1e-5f);
}

// T1[c][i] = A0[idx[i]][c]
__global__ __launch_bounds__(256) void k_gatherT(const float* __restrict__ A0, int N,
    const int* __restrict__ idx, float* __restrict__ T1, int k) {
  __shared__ float T[64][65];
  int i0 = blockIdx.x << 6, c0 = blockIdx.y << 6;
  int tid = threadIdx.x;
  int tr = tid >> 4, tc4 = (tid & 15) << 2;
#pragma unroll
  for (int q = 0; q < 4; ++q) {
    int row = tr + q * 16;
    float4 v = *reinterpret_cast<const float4*>(&A0[(size_t)idx[i0 + row] * N + c0 + tc4]);
    T[tc4 + 0][row] = v.x; T[tc4 + 1][row] = v.y; T[tc4 + 2][row] = v.z; T[tc4 + 3][row] = v.w;
  }
  __syncthreads();
#pragma unroll
  for (int q = 0; q < 4; ++q) {
    int row = tr + q * 16;
    float4 o;
    o.x = T[row][tc4]; o.y = T[row][tc4 + 1]; o.z = T[row][tc4 + 2]; o.w = T[row][tc4 + 3];
    *reinterpret_cast<float4*>(&T1[(size_t)(c0 + row) * k + i0 + tc4]) = o;
  }
}

// A1[j][i] = T1[idx[j]][i] * sv[j] * sv[i]
__global__ void k_scaleT(const float* __restrict__ T1, int k, const int* __restrict__ idx,
    const float* __restrict__ sv, float* __restrict__ A1) {
  int j = blockIdx.y;
  int i = (blockIdx.x * 256 + threadIdx.x) * 4;
  float sj = sv[j];
  const float* r = T1 + (size_t)idx[j] * k;
  float4 v = *reinterpret_cast<const float4*>(&r[i]);
  float4 s = *reinterpret_cast<const float4*>(&sv[i]);
  v.x *= sj * s.x; v.y *= sj * s.y; v.z *= sj * s.z; v.w *= sj * s.w;
  *reinterpret_cast<float4*>(&A1[(size_t)j * k + i]) = v;
}

__global__ void k_gather_mat(const float* __restrict__ Asrc, int lda,
    const int* __restrict__ idx, float* __restrict__ B, int k) {
  int j = blockIdx.x * 256 + threadIdx.x;
  int i = blockIdx.y;
  B[(size_t)i * k + j] = Asrc[(size_t)idx[i] * lda + idx[j]];
}

__global__ void k_scatter_rows(const float* __restrict__ P, int D, const int* __restrict__ idx,
                               float* __restrict__ Xo) {
  int f = blockIdx.x * 256 + threadIdx.x;
  int i = blockIdx.y;
  Xo[(size_t)idx[i] * D + f] = P[(size_t)i * D + f];
}

extern "C" void kernel_launch(void* const* d_in, const int* in_sizes, int n_in,
                              void* d_out, int out_size, void* d_ws, size_t ws_size,
                              hipStream_t stream) {
  const float* A    = (const float*)d_in[0];
  const float* X    = (const float*)d_in[1];
  const float* Wd0  = (const float*)d_in[2];
  const float* asd0 = (const float*)d_in[3];
  const float* add0 = (const float*)d_in[4];
  const float* bd0  = (const float*)d_in[5];
  const float* Wd1  = (const float*)d_in[6];
  const float* asd1 = (const float*)d_in[7];
  const float* add1 = (const float*)d_in[8];
  const float* bd1  = (const float*)d_in[9];
  const float* wp0  = (const float*)d_in[10];
  const float* bp0  = (const float*)d_in[11];
  const float* wp1  = (const float*)d_in[12];
  const float* bp1  = (const float*)d_in[13];
  const float* Wb   = (const float*)d_in[14];
  const float* asb  = (const float*)d_in[15];
  const float* adb  = (const float*)d_in[16];
  const float* bb   = (const float*)d_in[17];
  const float* Wu0  = (const float*)d_in[18];
  const float* asu0 = (const float*)d_in[19];
  const float* adu0 = (const float*)d_in[20];
  const float* bu0  = (const float*)d_in[21];
  const float* Wu1  = (const float*)d_in[22];
  const float* asu1 = (const float*)d_in[23];
  const float* adu1 = (const float*)d_in[24];
  const float* bu1  = (const float*)d_in[25];
  const float* Wup  = (const float*)d_in[26];
  const float* bup  = (const float*)d_in[27];
  (void)in_sizes; (void)n_in; (void)out_size; (void)ws_size;

  float* out  = (float*)d_out;
  float* Aup  = out;                    // [8192*8192]
  float* A0   = out + 67108864ULL;      // [4096*4096]
  float* A1   = A0 + 16777216ULL;       // [2048*2048]
  float* rec0 = A1 + 4194304ULL;        // [2048*2048]
  float* rec1 = rec0 + 4194304ULL;      // [4096*4096]

  // Scratch in the A_up output region (dead before A_up syrk writes).
  float* S = Aup;
  size_t off = 0;
  auto nxt = [&](size_t n) { float* p = S + off; off += (n + 1023) & ~(size_t)1023; return p; };
  float* Xp0  = nxt(4096 * 512);
  float* X0   = nxt(4096 * 512);
  float* src0 = nxt(4096 * 4);
  float* dst0 = nxt(4096 * 4);
  float* sc0  = nxt(4096);
  int*   idx0 = (int*)nxt(2048);
  float* v0   = nxt(2048);
  float* sv0  = nxt(2048);
  float* maskv = nxt(4096);
  float* Xp1  = nxt(2048 * 1024);
  float* X1   = nxt(2048 * 1024);
  float* src1 = nxt(2048 * 4);
  float* dst1 = nxt(2048 * 4);
  float* sc1  = nxt(2048);
  int*   idx1 = (int*)nxt(1024);
  float* v1   = nxt(1024);
  float* A2m  = nxt(1024 * 1024);
  float* Xpb  = nxt(1024 * 1024);
  float* srcb = nxt(1024 * 2);
  float* dstb = nxt(1024 * 2);
  float* Pu0  = nxt(1024 * 512);
  float* Xpu0 = nxt(2048 * 512);
  float* su0  = nxt(2048 * 4);
  float* du0  = nxt(2048 * 4);
  float* Pu1  = nxt(2048 * 256);
  float* Xpu1 = nxt(4096 * 256);
  float* su1  = nxt(4096 * 4);
  float* du1  = nxt(4096 * 4);
  float* dPp  = nxt(8 * 4096 * 4);                         // denom partials
  float* P    = nxt((size_t)8 * 4096 * 512);               // split-j partials
  float* T1   = nxt((size_t)4096 * 2048);                  // gather-transpose buffer
  unsigned short* XpS  = (unsigned short*)nxt(3200000);    // 3 planes [H][F][N] bf16
  unsigned short* XSp  = (unsigned short*)nxt(1572864);    // 3-plane row split (A side)
  unsigned short* Wd0T = (unsigned short*)nxt(196608);
  unsigned short* Wd1T = (unsigned short*)nxt(786432);
  unsigned short* XpT  = (unsigned short*)nxt(524288);     // [H][F][N] bf16 (single plane)
  unsigned short* X2inB = (unsigned short*)nxt(524288);
  unsigned short* XbB   = (unsigned short*)nxt(524288);
  unsigned short* WbT   = (unsigned short*)nxt(524288);
  unsigned short* Wu0T  = (unsigned short*)nxt(262144);
  unsigned short* Wu1T  = (unsigned short*)nxt(65536);

  // d_ws: final-stage-live buffers
  float* W = (float*)d_ws;
  unsigned short* Xu1B = (unsigned short*)(W + 1048576);        // 4096*256 bf16
  unsigned short* Xu0B = (unsigned short*)(W + 1048576 + 524288);  // 2048*512 bf16

  // rec1 output region as late scratch (dead before rec1 syrk writes)
  float* Pz = rec1;                                             // 4 x 8192*256 f32
  unsigned short* ZB = (unsigned short*)(rec1 + 4 * 2097152);   // 8192*256 bf16
  unsigned short* Xu1T = (unsigned short*)(rec1 + 4 * 2097152 + 1048576);  // 256*4096 bf16

  const size_t PS0 = (size_t)4 * 128 * 4096;  // plane stride GAT0 agg
  const size_t PS1 = (size_t)4 * 256 * 2048;  // plane stride GAT1 agg

  // ---- A0 = A + I ----
  k_add_eye<<<16384, 256, 0, stream>>>(A, A0);

  // ---- down level 0: GAT(256 -> 4x128), bf16x6 split MFMA ----
  k_split3<<<1024, 256, 0, stream>>>(X, XSp, (size_t)4096 * 256, 4096 * 256);
  k_transpose_split<<<dim3(8, 4, 1), 256, 0, stream>>>(Wd0, 512, 512, Wd0T, 256,
                                                       (size_t)512 * 256);
  k_gemm_x6_bt<<<dim3(4, 32), 256, 0, stream>>>(XSp, (size_t)4096 * 256, Wd0T,
                                                (size_t)512 * 256, Xp0, 4096, 512, 256);
  k_src_dst<<<4096, 256, 0, stream>>>(Xp0, asd0, add0, src0, dst0, 4, 128);
  k_transpose_split<<<dim3(2, 64, 4), 256, 0, stream>>>(Xp0, 512, 128, XpS, 4096, PS0);
  k_gat_x6<<<dim3(4, 32, 4), 512, 0, stream>>>(A0, 4096, XpS, PS0, src0, dst0, P, dPp, 512,
                                               128, 1, 1024);
  k_gat_reduce<<<2048, 256, 0, stream>>>(P, 4, (size_t)4096 * 512, dPp, (size_t)4096 * 4, bd0,
                                         X0, nullptr, 512, 128, 4096 * 512);
  k_score<<<1024, 256, 0, stream>>>(X0, wp0, bp0, sc0, 512);
  k_topk_rank<<<16, 256, 4096 * 8, stream>>>(sc0, 4096, 2048, idx0, v0, maskv);
  k_rowsum_mask<<<2048, 256, 0, stream>>>(A0, 4096, idx0, maskv, sv0);
  k_gatherT<<<dim3(32, 64), 256, 0, stream>>>(A0, 4096, idx0, T1, 2048);
  k_scaleT<<<dim3(2, 2048), 256, 0, stream>>>(T1, 2048, idx0, sv0, A1);

  // ---- down level 1: GAT(512 -> 4x256), bf16x6 split MFMA ----
  k_gather_scale_split3<<<dim3(1, 2048), 256, 0, stream>>>(X0, 512, idx0, v0, XSp,
                                                           (size_t)2048 * 512);
  k_transpose_split<<<dim3(16, 8, 1), 256, 0, stream>>>(Wd1, 1024, 1024, Wd1T, 512,
                                                        (size_t)1024 * 512);
  k_gemm_x6_bt<<<dim3(8, 16), 256, 0, stream>>>(XSp, (size_t)2048 * 512, Wd1T,
                                                (size_t)1024 * 512, Xp1, 2048, 1024, 512);
  k_src_dst<<<2048, 256, 0, stream>>>(Xp1, asd1, add1, src1, dst1, 4, 256);
  k_transpose_split<<<dim3(4, 32, 4), 256, 0, stream>>>(Xp1, 1024, 256, XpS, 2048, PS1);
  k_gat_x6<<<dim3(8, 16, 4), 512, 0, stream>>>(A1, 2048, XpS, PS1, src1, dst1, P, dPp, 1024,
                                               256, 2, 512);
  k_gat_reduce<<<2048, 256, 0, stream>>>(P, 4, (size_t)2048 * 1024, dPp, (size_t)2048 * 4, bd1,
                                         X1, nullptr, 1024, 256, 2048 * 1024);
  k_score<<<512, 256, 0, stream>>>(X1, wp1, bp1, sc1, 1024);
  k_topk_rank<<<8, 256, 2048 * 8, stream>>>(sc1, 2048, 1024, idx1, v1, nullptr);
  k_gather_mat<<<dim3(4, 1024), 256, 0, stream>>>(A1, 2048, idx1, A2m, 1024);
  k_gather_scale_b16<<<dim3(1, 1024), 256, 0, stream>>>(X1, 1024, idx1, v1, X2inB);

  // ---- bottom: GAT(1024 -> 2x512), unified bf16 MFMA ----
  k_transpose_bf16<<<dim3(16, 16), 256, 0, stream>>>(Wb, 1024, WbT, 1024, 1024);
  k_gemm_mfma_bt<<<dim3(8, 8), 256, 0, stream>>>(X2inB, WbT, nullptr, Xpb, 1024, 1024, 1024);
  k_src_dst<<<1024, 128, 0, stream>>>(Xpb, asb, adb, srcb, dstb, 2, 512);
  k_transpose_bf16h<<<dim3(8, 16, 2), 256, 0, stream>>>(Xpb, 1024, 512, XpT, 1024);
  k_gat_b16<4, 1><<<dim3(2, 8, 4), 512, 0, stream>>>(A2m, 1024, XpT, srcb, dstb, P, dPp, 1024,
                                                     512, 256);
  k_gat_reduce<<<1024, 256, 0, stream>>>(P, 4, (size_t)1024 * 1024, dPp, (size_t)1024 * 2, bb,
                                         nullptr, XbB, 1024, 512, 1024 * 1024);

  // ---- up level 0: unpool -> GAT(1024 -> 4x128) over A1, unified bf16 MFMA ----
  k_transpose_bf16<<<dim3(8, 16), 256, 0, stream>>>(Wu0, 512, Wu0T, 1024, 512);
  k_gemm_mfma_bt<<<dim3(4, 8), 256, 0, stream>>>(XbB, Wu0T, nullptr, Pu0, 1024, 512, 1024);
  k_fill0<<<1024, 256, 0, stream>>>(Xpu0, 2048 * 512);
  k_scatter_rows<<<dim3(2, 1024), 256, 0, stream>>>(Pu0, 512, idx1, Xpu0);
  k_src_dst<<<2048, 256, 0, stream>>>(Xpu0, asu0, adu0, su0, du0, 4, 128);
  k_transpose_bf16h<<<dim3(2, 32, 4), 256, 0, stream>>>(Xpu0, 512, 128, XpT, 2048);
  k_gat_b16<4, 4><<<dim3(1, 16, 8), 512, 0, stream>>>(A1, 2048, XpT, su0, du0, P, dPp, 512,
                                                      128, 256);
  k_gat_reduce<<<1024, 256, 0, stream>>>(P, 8, (size_t)2048 * 512, dPp, (size_t)2048 * 4, bu0,
                                         nullptr, Xu0B, 512, 128, 2048 * 512);

  // ---- up level 1: unpool -> GAT(512 -> 4x64) over A0, unified bf16 MFMA ----
  k_transpose_bf16<<<dim3(4, 8), 256, 0, stream>>>(Wu1, 256, Wu1T, 512, 256);
  k_gemm_mfma_bt<<<dim3(2, 16), 256, 0, stream>>>(Xu0B, Wu1T, nullptr, Pu1, 2048, 256, 512);
  k_fill0<<<1024, 256, 0, stream>>>(Xpu1, 4096 * 256);
  k_scatter_rows<<<dim3(1, 2048), 256, 0, stream>>>(Pu1, 256, idx0, Xpu1);
  k_src_dst<<<4096, 256, 0, stream>>>(Xpu1, asu1, adu1, su1, du1, 4, 64);
  k_transpose_bf16h<<<dim3(1, 64, 4), 256, 0, stream>>>(Xpu1, 256, 64, XpT, 4096);
  k_gat_b16<2, 4><<<dim3(1, 32, 8), 512, 0, stream>>>(A0, 4096, XpT, su1, du1, P, dPp, 256,
                                                      64, 512);
  k_gat_reduce<<<1024, 256, 0, stream>>>(P, 8, (size_t)4096 * 256, dPp, (size_t)4096 * 4, bu1,
                                         nullptr, Xu1B, 256, 64, 4096 * 256);
  k_transpose_bb<<<dim3(4, 64), 256, 0, stream>>>(Xu1B, 256, Xu1T, 4096, 256);

  // ---- upsampler: split-k GEMM (fused f32->bf16 A staging) + fused softmax ----
  k_gemm_aup<<<dim3(4, 64), 512, 0, stream>>>(Wup, Xu1T, Pz, 8192, 4096, 1024);
  k_softmax_fuse<<<8192, 256, 0, stream>>>(Pz, 4, (size_t)8192 * 256, bup, ZB);
  k_syrk_mfma<<<dim3(64, 64), 256, 0, stream>>>(ZB, 8192, 256, Aup);

  // ---- reconstructions ----
  k_syrk_mfma<<<dim3(32, 32), 256, 0, stream>>>(Xu1B, 4096, 256, rec1);
  k_syrk_mfma<<<dim3(16, 16), 256, 0, stream>>>(Xu0B, 2048, 512, rec0);
}